// Round 2
// baseline (4789.712 us; speedup 1.0000x reference)
//
#include <hip/hip_runtime.h>
#include <math.h>

#define B_ 4
#define L_ 2048
#define HD_ 1024
#define H_ 16
#define VD_ 64
#define M_ 128
#define M2_ 256
#define RIDGE_ 0.01f
#define SCALE_ 0.08838834764831845f   // 1/sqrt(128)

// ---------------- fp32 GEMM, C = A * B^T (both row-major, K contiguous) ----
// 128x128 tile, BK=8, 256 threads, 8x8 microtile.
__global__ __launch_bounds__(256) void gemm_nt_128(
    const float* __restrict__ A, const float* __restrict__ Bm, float* __restrict__ C,
    int Mdim, int Ndim, int Kdim,
    const float* __restrict__ bias, const float* __restrict__ mask)
{
  __shared__ __align__(16) float a_lds[8][132];
  __shared__ __align__(16) float b_lds[8][132];
  const int tid = threadIdx.x;
  const int tx = tid & 15, ty = tid >> 4;
  const int m0 = blockIdx.y * 128, n0 = blockIdx.x * 128;
  const int lr = tid >> 1;          // 0..127
  const int lc = (tid & 1) * 4;     // 0 or 4
  float acc[8][8];
#pragma unroll
  for (int i = 0; i < 8; ++i)
#pragma unroll
    for (int j = 0; j < 8; ++j) acc[i][j] = 0.f;

  const float* Ap = A + (long)(m0 + lr) * Kdim + lc;
  const float* Bp = Bm + (long)(n0 + lr) * Kdim + lc;

  for (int k0 = 0; k0 < Kdim; k0 += 8) {
    float4 av = *(const float4*)(Ap + k0);
    float4 bv = *(const float4*)(Bp + k0);
    __syncthreads();
    a_lds[lc + 0][lr] = av.x; a_lds[lc + 1][lr] = av.y;
    a_lds[lc + 2][lr] = av.z; a_lds[lc + 3][lr] = av.w;
    b_lds[lc + 0][lr] = bv.x; b_lds[lc + 1][lr] = bv.y;
    b_lds[lc + 2][lr] = bv.z; b_lds[lc + 3][lr] = bv.w;
    __syncthreads();
#pragma unroll
    for (int kk = 0; kk < 8; ++kk) {
      float4 a0 = *(const float4*)&a_lds[kk][8 * ty];
      float4 a1 = *(const float4*)&a_lds[kk][8 * ty + 4];
      float4 b0 = *(const float4*)&b_lds[kk][8 * tx];
      float4 b1 = *(const float4*)&b_lds[kk][8 * tx + 4];
      float a8[8] = {a0.x, a0.y, a0.z, a0.w, a1.x, a1.y, a1.z, a1.w};
      float b8[8] = {b0.x, b0.y, b0.z, b0.w, b1.x, b1.y, b1.z, b1.w};
#pragma unroll
      for (int i = 0; i < 8; ++i)
#pragma unroll
        for (int j = 0; j < 8; ++j) acc[i][j] = fmaf(a8[i], b8[j], acc[i][j]);
    }
  }
  float bb[8];
#pragma unroll
  for (int j = 0; j < 8; ++j) bb[j] = bias ? bias[n0 + 8 * tx + j] : 0.f;
#pragma unroll
  for (int i = 0; i < 8; ++i) {
    int r = m0 + 8 * ty + i;
    float mval = mask ? mask[r] : 1.f;
    float4 o0, o1;
    o0.x = (acc[i][0] + bb[0]) * mval; o0.y = (acc[i][1] + bb[1]) * mval;
    o0.z = (acc[i][2] + bb[2]) * mval; o0.w = (acc[i][3] + bb[3]) * mval;
    o1.x = (acc[i][4] + bb[4]) * mval; o1.y = (acc[i][5] + bb[5]) * mval;
    o1.z = (acc[i][6] + bb[6]) * mval; o1.w = (acc[i][7] + bb[7]) * mval;
    float* Cp = C + (long)r * Ndim + n0 + 8 * tx;
    *(float4*)Cp = o0;
    *(float4*)(Cp + 4) = o1;
  }
}

// ---------------- batched fp32 GEMM, C = A^T * B (contraction over rows l) --
// 64x64 tile, BK=16, 256 threads, 4x4 microtile. batch z -> (b = z>>4, h = z&15)
__global__ __launch_bounds__(256) void gemm_tn_64(
    const float* __restrict__ A, long sAb, long sAh, int lda,
    const float* __restrict__ Bm, long sBb, long sBh, int ldb,
    float* __restrict__ C, long sCb, long sCh, int ldc,
    int Kdim, const float* __restrict__ maskB)
{
  __shared__ __align__(16) float a_lds[16][68];
  __shared__ __align__(16) float b_lds[16][68];
  const int tid = threadIdx.x;
  const int tx = tid & 15, ty = tid >> 4;
  const int z = blockIdx.z;
  const int bb_ = z >> 4, hh = z & 15;
  const int m0 = blockIdx.y * 64, n0 = blockIdx.x * 64;
  const float* Ab = A + bb_ * sAb + hh * sAh;
  const float* Bb = Bm + bb_ * sBb + hh * sBh;
  float* Cb = C + bb_ * sCb + hh * sCh;
  const int li = tid >> 4;        // l row within tile 0..15
  const int lj = (tid & 15) * 4;  // column*4
  const float* maskRow = maskB ? (maskB + (long)bb_ * L_) : nullptr;
  float acc[4][4];
#pragma unroll
  for (int i = 0; i < 4; ++i)
#pragma unroll
    for (int j = 0; j < 4; ++j) acc[i][j] = 0.f;

  for (int k0 = 0; k0 < Kdim; k0 += 16) {
    float4 av = *(const float4*)(Ab + (long)(k0 + li) * lda + m0 + lj);
    float4 bv = *(const float4*)(Bb + (long)(k0 + li) * ldb + n0 + lj);
    if (maskRow) {
      float mv = maskRow[k0 + li];
      bv.x *= mv; bv.y *= mv; bv.z *= mv; bv.w *= mv;
    }
    __syncthreads();
    *(float4*)&a_lds[li][lj] = av;
    *(float4*)&b_lds[li][lj] = bv;
    __syncthreads();
#pragma unroll
    for (int kk = 0; kk < 16; ++kk) {
      float4 a4 = *(const float4*)&a_lds[kk][4 * ty];
      float4 b4 = *(const float4*)&b_lds[kk][4 * tx];
      float a_[4] = {a4.x, a4.y, a4.z, a4.w};
      float b_[4] = {b4.x, b4.y, b4.z, b4.w};
#pragma unroll
      for (int i = 0; i < 4; ++i)
#pragma unroll
        for (int j = 0; j < 4; ++j) acc[i][j] = fmaf(a_[i], b_[j], acc[i][j]);
    }
  }
#pragma unroll
  for (int i = 0; i < 4; ++i) {
    float4 o;
    o.x = acc[i][0]; o.y = acc[i][1]; o.z = acc[i][2]; o.w = acc[i][3];
    *(float4*)(Cb + (long)(m0 + 4 * ty + i) * ldc + n0 + 4 * tx) = o;
  }
}

// ---------------- RFF features of k, masked: PhiK (B,H,L,256) ----------------
__global__ __launch_bounds__(256) void rff_k_kernel(
    const float* __restrict__ kbuf, const float* __restrict__ mask,
    const float* __restrict__ rffW, const float* __restrict__ rffb,
    float* __restrict__ phik)
{
  __shared__ float w_lds[64 * 128];
  __shared__ float b_lds[128];
  __shared__ float k_lds[2][64];
  const int b = blockIdx.z, h = blockIdx.y, l0 = blockIdx.x * 32;
  const int tid = threadIdx.x;
  const float* wsrc = rffW + h * 8192;
  for (int f = tid * 4; f < 8192; f += 1024)
    *(float4*)&w_lds[f] = *(const float4*)&wsrc[f];
  if (tid < 128) b_lds[tid] = rffb[h * 128 + tid];
  __syncthreads();
  const int i2 = tid >> 7;   // 0..1
  const int m = tid & 127;
  for (int lp = 0; lp < 32; lp += 2) {
    if (tid < 128) {
      int ii = tid >> 6, d = tid & 63;
      k_lds[ii][d] = kbuf[(long)(b * L_ + l0 + lp + ii) * HD_ + h * VD_ + d];
    }
    __syncthreads();
    int l = l0 + lp + i2;
    float proj = b_lds[m];
#pragma unroll 16
    for (int d = 0; d < 64; ++d) proj = fmaf(k_lds[i2][d], w_lds[d * 128 + m], proj);
    float sv, cv;
    sincosf(proj, &sv, &cv);
    float mv = mask[b * L_ + l];
    long base = (long)((b * H_ + h) * L_ + l) * M2_;
    phik[base + m] = SCALE_ * cv * mv;
    phik[base + 128 + m] = SCALE_ * sv * mv;
    __syncthreads();
  }
}

// ---------------- per-(b,h) Cholesky (packed LDS) + triangular solves -------
__device__ __forceinline__ int tri_decode(int f) {
  int r = (int)((sqrtf(8.f * (float)f + 1.f) - 1.f) * 0.5f);
  while ((r + 1) * (r + 2) / 2 <= f) ++r;
  while (r * (r + 1) / 2 > f) --r;
  return r;
}

__global__ __launch_bounds__(512) void chol_solve_kernel(
    const float* __restrict__ G, const float* __restrict__ T,
    float* __restrict__ Lg, float* __restrict__ Wt)
{
  extern __shared__ float sm[];
  const int bh = blockIdx.x;
  const int tid = threadIdx.x;
  const float* Gb = G + (long)bh * 65536;
  float* Lp = sm;  // packed lower triangle, 32896 floats
  for (int f = tid; f < 32896; f += 512) {
    int i = tri_decode(f);
    int j = f - i * (i + 1) / 2;
    float v = Gb[i * 256 + j];
    if (i == j) v += RIDGE_;
    Lp[f] = v;
  }
  __syncthreads();
  for (int j = 0; j < 256; ++j) {
    const int jj = j * (j + 1) / 2 + j;
    float Ajj = Lp[jj];
    __syncthreads();
    float dv = sqrtf(Ajj);
    float dinv = 1.f / dv;
    if (tid == 0) Lp[jj] = dv;
    for (int i = j + 1 + tid; i < 256; i += 512)
      Lp[i * (i + 1) / 2 + j] *= dinv;
    __syncthreads();
    const int n = 255 - j;
    const int tot = n * (n + 1) / 2;
    for (int f = tid; f < tot; f += 512) {
      int r = tri_decode(f);
      int c = f - r * (r + 1) / 2;
      int i = j + 1 + r, kc = j + 1 + c;
      Lp[i * (i + 1) / 2 + kc] -= Lp[i * (i + 1) / 2 + j] * Lp[kc * (kc + 1) / 2 + j];
    }
    __syncthreads();
  }
  // dump packed L to global, then reuse LDS for the 256x64 RHS
  float* Lgb = Lg + (long)bh * 32896;
  for (int f = tid; f < 32896; f += 512) Lgb[f] = Lp[f];
  __syncthreads();
  float* Ts = sm;  // 256 rows x stride 65
  const float* Tb = T + (long)bh * 16384;
  for (int f = tid; f < 16384; f += 512) {
    int r = f >> 6, d = f & 63;
    Ts[r * 65 + d] = Tb[f];
  }
  __syncthreads();
  // forward: L y = T
  for (int j = 0; j < 256; ++j) {
    float dinv = 1.f / Lgb[j * (j + 1) / 2 + j];
    if (tid < 64) Ts[j * 65 + tid] *= dinv;
    __syncthreads();
    const int rows = 255 - j;
    for (int f = tid; f < rows * 64; f += 512) {
      int i = j + 1 + (f >> 6), d = f & 63;
      Ts[i * 65 + d] -= Lgb[i * (i + 1) / 2 + j] * Ts[j * 65 + d];
    }
    __syncthreads();
  }
  // backward: L^T w = y
  for (int j = 255; j >= 0; --j) {
    float dinv = 1.f / Lgb[j * (j + 1) / 2 + j];
    if (tid < 64) Ts[j * 65 + tid] *= dinv;
    __syncthreads();
    for (int f = tid; f < j * 64; f += 512) {
      int i = f >> 6, d = f & 63;
      Ts[i * 65 + d] -= Lgb[j * (j + 1) / 2 + i] * Ts[j * 65 + d];
    }
    __syncthreads();
  }
  __syncthreads();
  // write W transposed: Wt[d][m] = W[m][d]
  for (int f = tid; f < 16384; f += 512) {
    int d = f >> 8, mm = f & 255;
    Wt[(long)bh * 16384 + f] = Ts[mm * 65 + d];
  }
}

// ---------------- fused RFF(q) + out = PhiQ * W  → outheads (B,L,HD) --------
__global__ __launch_bounds__(256) void rffq_out_kernel(
    const float* __restrict__ q, const float* __restrict__ Wt,
    const float* __restrict__ rffW, const float* __restrict__ rffb,
    float* __restrict__ outheads)
{
  extern __shared__ float sm[];
  float* wt_lds = sm;                   // 64*260 = 16640
  float* w_lds  = sm + 16640;           // 8192
  float* rb_lds = sm + 16640 + 8192;    // 128
  float* q_lds  = rb_lds + 128;         // 256
  float* phi    = q_lds + 256;          // 1024
  const int b = blockIdx.z, h = blockIdx.y, l0 = blockIdx.x * 64;
  const int bh = b * H_ + h;
  const int tid = threadIdx.x;
  const float* Wtb = Wt + (long)bh * 16384;
  for (int f = tid; f < 16384; f += 256) {
    int d = f >> 8, mm = f & 255;
    wt_lds[d * 260 + mm] = Wtb[f];
  }
  const float* wsrc = rffW + h * 8192;
  for (int f = tid * 4; f < 8192; f += 1024)
    *(float4*)&w_lds[f] = *(const float4*)&wsrc[f];
  if (tid < 128) rb_lds[tid] = rffb[h * 128 + tid];
  __syncthreads();
  const int iw = tid >> 6;  // wave id 0..3 (one l per wave)
  const int d = tid & 63;
  for (int lp = 0; lp < 64; lp += 4) {
    q_lds[iw * 64 + d] = q[(long)(b * L_ + l0 + lp + iw) * HD_ + h * VD_ + d];
    __syncthreads();
#pragma unroll
    for (int p = 0; p < 2; ++p) {
      int ii = (tid >> 7) + 2 * p;
      int mm = tid & 127;
      float proj = rb_lds[mm];
#pragma unroll 16
      for (int dd = 0; dd < 64; ++dd)
        proj = fmaf(q_lds[ii * 64 + dd], w_lds[dd * 128 + mm], proj);
      float sv, cv;
      sincosf(proj, &sv, &cv);
      phi[ii * 256 + mm] = SCALE_ * cv;
      phi[ii * 256 + 128 + mm] = SCALE_ * sv;
    }
    __syncthreads();
    float accv = 0.f;
    const float* wrow = wt_lds + d * 260;
    const float* prow = phi + iw * 256;
#pragma unroll 16
    for (int mm = 0; mm < 256; mm += 4) {
      float4 w4 = *(const float4*)(wrow + mm);
      float4 p4 = *(const float4*)(prow + mm);
      accv = fmaf(w4.x, p4.x, accv);
      accv = fmaf(w4.y, p4.y, accv);
      accv = fmaf(w4.z, p4.z, accv);
      accv = fmaf(w4.w, p4.w, accv);
    }
    outheads[(long)(b * L_ + l0 + lp + iw) * HD_ + h * VD_ + d] = accv;
    __syncthreads();
  }
}

// sentinel when workspace is too small (distinctive absmax ~12345)
__global__ void ws_too_small_kernel(float* out) { out[0] = 12345.0f; }

extern "C" void kernel_launch(void* const* d_in, const int* in_sizes, int n_in,
                              void* d_out, int out_size, void* d_ws, size_t ws_size,
                              hipStream_t stream) {
  const float* x    = (const float*)d_in[0];
  const float* mask = (const float*)d_in[2];
  const float* Wq   = (const float*)d_in[3];
  const float* Wk   = (const float*)d_in[4];
  const float* Wv   = (const float*)d_in[5];
  const float* Wo   = (const float*)d_in[6];
  const float* bo   = (const float*)d_in[7];
  const float* rffW = (const float*)d_in[8];
  const float* rffb = (const float*)d_in[9];
  float* out = (float*)d_out;
  float* ws  = (float*)d_ws;

  // workspace layout (floats) — total 63,963,136 floats = 255,852,544 B < 256 MiB
  const size_t needed = 63963136UL * 4UL;
  if (ws_size < needed) {
    ws_too_small_kernel<<<1, 1, 0, stream>>>(out);
    return;
  }
  float* q    = ws;                 // 8388608
  float* k    = ws + 8388608;       // 8388608
  float* v    = ws + 16777216;      // 8388608
  float* phik = ws + 25165824;      // 33554432
  float* G    = ws + 58720256;      // 4194304
  float* T    = ws + 62914560;      // 1048576
  // Lg (2105344 floats) and Wt (1048576 floats) alias phik: phik is dead once
  // G and T are formed, and chol_solve_kernel (the only writer of Lg/Wt) runs
  // strictly after gemm_tn_64. Wt is then read by rffq_out_kernel. 
  float* Lg   = phik;               // 2105344 (aliases phik[0:2105344])
  float* Wt   = phik + 2105344;     // 1048576 (aliases phik[2105344:3153920])
  float* outheads = k;              // k is dead after rff_k

  hipFuncSetAttribute((const void*)chol_solve_kernel,
                      hipFuncAttributeMaxDynamicSharedMemorySize, 131584);
  hipFuncSetAttribute((const void*)rffq_out_kernel,
                      hipFuncAttributeMaxDynamicSharedMemorySize, 104960);

  dim3 blk(256);
  dim3 g1(1024 / 128, 8192 / 128);  // (8, 64)

  // q,k,v = x @ W^T
  gemm_nt_128<<<g1, blk, 0, stream>>>(x, Wq, q, 8192, 1024, 1024, nullptr, nullptr);
  gemm_nt_128<<<g1, blk, 0, stream>>>(x, Wk, k, 8192, 1024, 1024, nullptr, nullptr);
  gemm_nt_128<<<g1, blk, 0, stream>>>(x, Wv, v, 8192, 1024, 1024, nullptr, nullptr);

  // PhiK (masked)
  dim3 g2(64, 16, 4);
  rff_k_kernel<<<g2, blk, 0, stream>>>(k, mask, rffW, rffb, phik);

  // G = PhiK^T PhiK   (batched over 64 (b,h))
  dim3 g3a(4, 4, 64);
  gemm_tn_64<<<g3a, blk, 0, stream>>>(phik, 8388608L, 524288L, 256,
                                      phik, 8388608L, 524288L, 256,
                                      G, 1048576L, 65536L, 256,
                                      2048, nullptr);
  // T = PhiK^T (V * mask)
  dim3 g3b(1, 4, 64);
  gemm_tn_64<<<g3b, blk, 0, stream>>>(phik, 8388608L, 524288L, 256,
                                      v, 2097152L, 64L, 1024,
                                      T, 262144L, 16384L, 64,
                                      2048, mask);

  // Cholesky + solves → Wt (64, 64x256)  [Lg/Wt alias dead phik]
  chol_solve_kernel<<<dim3(64), dim3(512), 131584, stream>>>(G, T, Lg, Wt);

  // outheads = PhiQ @ W (RFF of q fused in)
  dim3 g5(32, 16, 4);
  rffq_out_kernel<<<g5, blk, 104960, stream>>>(q, Wt, rffW, rffb, outheads);

  // final: (outheads @ Wo^T + bo) * mask
  gemm_nt_128<<<g1, blk, 0, stream>>>(outheads, Wo, out, 8192, 1024, 1024, bo, mask);
}

// Round 3
// 2621.551 us; speedup vs baseline: 1.8271x; 1.8271x over previous
//
#include <hip/hip_runtime.h>
#include <math.h>

#define B_ 4
#define L_ 2048
#define HD_ 1024
#define H_ 16
#define VD_ 64
#define M_ 128
#define M2_ 256
#define RIDGE_ 0.01f
#define SCALE_ 0.08838834764831845f   // 1/sqrt(128)

// ---------------- fp32 GEMM, C = A * B^T (both row-major, K contiguous) ----
__global__ __launch_bounds__(256) void gemm_nt_128(
    const float* __restrict__ A, const float* __restrict__ Bm, float* __restrict__ C,
    int Mdim, int Ndim, int Kdim,
    const float* __restrict__ bias, const float* __restrict__ mask)
{
  __shared__ __align__(16) float a_lds[8][132];
  __shared__ __align__(16) float b_lds[8][132];
  const int tid = threadIdx.x;
  const int tx = tid & 15, ty = tid >> 4;
  const int m0 = blockIdx.y * 128, n0 = blockIdx.x * 128;
  const int lr = tid >> 1;
  const int lc = (tid & 1) * 4;
  float acc[8][8];
#pragma unroll
  for (int i = 0; i < 8; ++i)
#pragma unroll
    for (int j = 0; j < 8; ++j) acc[i][j] = 0.f;

  const float* Ap = A + (long)(m0 + lr) * Kdim + lc;
  const float* Bp = Bm + (long)(n0 + lr) * Kdim + lc;

  for (int k0 = 0; k0 < Kdim; k0 += 8) {
    float4 av = *(const float4*)(Ap + k0);
    float4 bv = *(const float4*)(Bp + k0);
    __syncthreads();
    a_lds[lc + 0][lr] = av.x; a_lds[lc + 1][lr] = av.y;
    a_lds[lc + 2][lr] = av.z; a_lds[lc + 3][lr] = av.w;
    b_lds[lc + 0][lr] = bv.x; b_lds[lc + 1][lr] = bv.y;
    b_lds[lc + 2][lr] = bv.z; b_lds[lc + 3][lr] = bv.w;
    __syncthreads();
#pragma unroll
    for (int kk = 0; kk < 8; ++kk) {
      float4 a0 = *(const float4*)&a_lds[kk][8 * ty];
      float4 a1 = *(const float4*)&a_lds[kk][8 * ty + 4];
      float4 b0 = *(const float4*)&b_lds[kk][8 * tx];
      float4 b1 = *(const float4*)&b_lds[kk][8 * tx + 4];
      float a8[8] = {a0.x, a0.y, a0.z, a0.w, a1.x, a1.y, a1.z, a1.w};
      float b8[8] = {b0.x, b0.y, b0.z, b0.w, b1.x, b1.y, b1.z, b1.w};
#pragma unroll
      for (int i = 0; i < 8; ++i)
#pragma unroll
        for (int j = 0; j < 8; ++j) acc[i][j] = fmaf(a8[i], b8[j], acc[i][j]);
    }
  }
  float bb[8];
#pragma unroll
  for (int j = 0; j < 8; ++j) bb[j] = bias ? bias[n0 + 8 * tx + j] : 0.f;
#pragma unroll
  for (int i = 0; i < 8; ++i) {
    int r = m0 + 8 * ty + i;
    float mval = mask ? mask[r] : 1.f;
    float4 o0, o1;
    o0.x = (acc[i][0] + bb[0]) * mval; o0.y = (acc[i][1] + bb[1]) * mval;
    o0.z = (acc[i][2] + bb[2]) * mval; o0.w = (acc[i][3] + bb[3]) * mval;
    o1.x = (acc[i][4] + bb[4]) * mval; o1.y = (acc[i][5] + bb[5]) * mval;
    o1.z = (acc[i][6] + bb[6]) * mval; o1.w = (acc[i][7] + bb[7]) * mval;
    float* Cp = C + (long)r * Ndim + n0 + 8 * tx;
    *(float4*)Cp = o0;
    *(float4*)(Cp + 4) = o1;
  }
}

// ---------------- batched fp32 GEMM, C = A^T * B ---------------------------
__global__ __launch_bounds__(256) void gemm_tn_64(
    const float* __restrict__ A, long sAb, long sAh, int lda,
    const float* __restrict__ Bm, long sBb, long sBh, int ldb,
    float* __restrict__ C, long sCb, long sCh, int ldc,
    int Kdim, const float* __restrict__ maskB)
{
  __shared__ __align__(16) float a_lds[16][68];
  __shared__ __align__(16) float b_lds[16][68];
  const int tid = threadIdx.x;
  const int tx = tid & 15, ty = tid >> 4;
  const int z = blockIdx.z;
  const int bb_ = z >> 4, hh = z & 15;
  const int m0 = blockIdx.y * 64, n0 = blockIdx.x * 64;
  const float* Ab = A + bb_ * sAb + hh * sAh;
  const float* Bb = Bm + bb_ * sBb + hh * sBh;
  float* Cb = C + bb_ * sCb + hh * sCh;
  const int li = tid >> 4;
  const int lj = (tid & 15) * 4;
  const float* maskRow = maskB ? (maskB + (long)bb_ * L_) : nullptr;
  float acc[4][4];
#pragma unroll
  for (int i = 0; i < 4; ++i)
#pragma unroll
    for (int j = 0; j < 4; ++j) acc[i][j] = 0.f;

  for (int k0 = 0; k0 < Kdim; k0 += 16) {
    float4 av = *(const float4*)(Ab + (long)(k0 + li) * lda + m0 + lj);
    float4 bv = *(const float4*)(Bb + (long)(k0 + li) * ldb + n0 + lj);
    if (maskRow) {
      float mv = maskRow[k0 + li];
      bv.x *= mv; bv.y *= mv; bv.z *= mv; bv.w *= mv;
    }
    __syncthreads();
    *(float4*)&a_lds[li][lj] = av;
    *(float4*)&b_lds[li][lj] = bv;
    __syncthreads();
#pragma unroll
    for (int kk = 0; kk < 16; ++kk) {
      float4 a4 = *(const float4*)&a_lds[kk][4 * ty];
      float4 b4 = *(const float4*)&b_lds[kk][4 * tx];
      float a_[4] = {a4.x, a4.y, a4.z, a4.w};
      float b_[4] = {b4.x, b4.y, b4.z, b4.w};
#pragma unroll
      for (int i = 0; i < 4; ++i)
#pragma unroll
        for (int j = 0; j < 4; ++j) acc[i][j] = fmaf(a_[i], b_[j], acc[i][j]);
    }
  }
#pragma unroll
  for (int i = 0; i < 4; ++i) {
    float4 o;
    o.x = acc[i][0]; o.y = acc[i][1]; o.z = acc[i][2]; o.w = acc[i][3];
    *(float4*)(Cb + (long)(m0 + 4 * ty + i) * ldc + n0 + 4 * tx) = o;
  }
}

// ---------------- RFF features of k, masked: PhiK (B,H,L,256) ---------------
__global__ __launch_bounds__(256) void rff_k_kernel(
    const float* __restrict__ kbuf, const float* __restrict__ mask,
    const float* __restrict__ rffW, const float* __restrict__ rffb,
    float* __restrict__ phik)
{
  __shared__ float w_lds[64 * 128];
  __shared__ float b_lds[128];
  __shared__ float k_lds[2][64];
  const int b = blockIdx.z, h = blockIdx.y, l0 = blockIdx.x * 32;
  const int tid = threadIdx.x;
  const float* wsrc = rffW + h * 8192;
  for (int f = tid * 4; f < 8192; f += 1024)
    *(float4*)&w_lds[f] = *(const float4*)&wsrc[f];
  if (tid < 128) b_lds[tid] = rffb[h * 128 + tid];
  __syncthreads();
  const int i2 = tid >> 7;
  const int m = tid & 127;
  for (int lp = 0; lp < 32; lp += 2) {
    if (tid < 128) {
      int ii = tid >> 6, d = tid & 63;
      k_lds[ii][d] = kbuf[(long)(b * L_ + l0 + lp + ii) * HD_ + h * VD_ + d];
    }
    __syncthreads();
    int l = l0 + lp + i2;
    float proj = b_lds[m];
#pragma unroll 16
    for (int d = 0; d < 64; ++d) proj = fmaf(k_lds[i2][d], w_lds[d * 128 + m], proj);
    float sv, cv;
    sincosf(proj, &sv, &cv);
    float mv = mask[b * L_ + l];
    long base = (long)((b * H_ + h) * L_ + l) * M2_;
    phik[base + m] = SCALE_ * cv * mv;
    phik[base + 128 + m] = SCALE_ * sv * mv;
    __syncthreads();
  }
}

// ---------------- blocked Cholesky factor (NB=16) + invD --------------------
// One block per (b,h). LDS: 136 blocks of 16x17 = 147,968 B.
// Output Lg[bh]: 136 blocks of 16x16 (unpadded, row-major); diagonal slots
// hold invD = D^{-1} (full 16x16 with zero upper).
__global__ __launch_bounds__(512) void chol_factor_kernel(
    const float* __restrict__ G, float* __restrict__ Lg)
{
  extern __shared__ float Lb[];  // 136*272
  const int bh = blockIdx.x;
  const int tid = threadIdx.x;
  const float* Gb = G + (long)bh * 65536;

  // load lower blocks of G (+ridge on diag)
  for (int f = tid; f < 136 * 256; f += 512) {
    int bi = f >> 8, e = f & 255;
    int i = e >> 4, j = e & 15;
    int I = 0; while ((I + 1) * (I + 2) / 2 <= bi) ++I;
    int J = bi - I * (I + 1) / 2;
    float v = Gb[(I * 16 + i) * 256 + J * 16 + j];
    if (I == J && i == j) v += RIDGE_;
    Lb[bi * 272 + i * 17 + j] = v;
  }
  __syncthreads();

  for (int p = 0; p < 16; ++p) {
    const int diagbase = (p * (p + 1) / 2 + p) * 272;
    // --- Step A: wave 0 factors diag block in registers, computes invD ---
    if (tid < 64) {
      const int i = tid & 15;
      float r[16];
#pragma unroll
      for (int k = 0; k < 16; ++k) r[k] = Lb[diagbase + i * 17 + k];
#pragma unroll
      for (int j = 0; j < 16; ++j) {
        float dj = __shfl(r[j], j);
        float dinv = 1.0f / sqrtf(dj);
        r[j] *= dinv;               // L[i][j] for i>=j (others garbage, unread)
        float Lij = r[j];
#pragma unroll
        for (int k = j + 1; k < 16; ++k) {
          float Lkj = __shfl(r[j], k);
          r[k] = fmaf(-Lij, Lkj, r[k]);
        }
      }
      // invD: lane c=i computes column c by forward substitution
      float x[16];
#pragma unroll
      for (int j = 0; j < 16; ++j) {
        float s = (i == j) ? 1.0f : 0.0f;
#pragma unroll
        for (int k = 0; k < j; ++k) {
          float Ljk = __shfl(r[k], j);
          s = fmaf(-Ljk, x[k], s);
        }
        float Ljj = __shfl(r[j], j);
        x[j] = s / Ljj;
      }
      if (tid < 16) {
#pragma unroll
        for (int j = 0; j < 16; ++j) Lb[diagbase + j * 17 + tid] = x[j];
      }
    }
    __syncthreads();

    // --- Step B: panel solve L(I,p) = A(I,p) * invD^T (GEMM) ---
    const int nIb = 15 - p;
    const int tot = nIb * 256;
    float outv[8];
#pragma unroll
    for (int s = 0; s < 8; ++s) {
      int f = tid + s * 512;
      if (f < tot) {
        int Ib = f >> 8;
        int I = p + 1 + Ib;
        int e = f & 255;
        int i = e >> 4, j = e & 15;
        const float* Ablk = &Lb[(I * (I + 1) / 2 + p) * 272 + i * 17];
        const float* invD = &Lb[diagbase + j * 17];
        float s2 = 0.f;
#pragma unroll
        for (int k = 0; k < 16; ++k) s2 = fmaf(Ablk[k], invD[k], s2);
        outv[s] = s2;
      }
    }
    __syncthreads();
#pragma unroll
    for (int s = 0; s < 8; ++s) {
      int f = tid + s * 512;
      if (f < tot) {
        int Ib = f >> 8;
        int I = p + 1 + Ib;
        int e = f & 255;
        int i = e >> 4, j = e & 15;
        Lb[(I * (I + 1) / 2 + p) * 272 + i * 17 + j] = outv[s];
      }
    }
    __syncthreads();

    // --- Step C: trailing update A(I,J) -= L(I,p) L(J,p)^T ---
    const int npairs = nIb * (nIb + 1) / 2;
    const int g = tid >> 4, t = tid & 15;
    const int tx = t & 3, ty = t >> 2;
    for (int pi0 = 0; pi0 < npairs; pi0 += 32) {
      int pi = pi0 + g;
      if (pi < npairs) {
        int a = 0; while ((a + 1) * (a + 2) / 2 <= pi) ++a;
        int b2 = pi - a * (a + 1) / 2;
        int I = p + 1 + a, J = p + 1 + b2;
        float* Cblk = &Lb[(I * (I + 1) / 2 + J) * 272];
        const float* Ablk = &Lb[(I * (I + 1) / 2 + p) * 272];
        const float* Bblk = &Lb[(J * (J + 1) / 2 + p) * 272];
        float c4[4][4];
#pragma unroll
        for (int ii = 0; ii < 4; ++ii)
#pragma unroll
          for (int jj = 0; jj < 4; ++jj)
            c4[ii][jj] = Cblk[(4 * ty + ii) * 17 + 4 * tx + jj];
#pragma unroll
        for (int kk = 0; kk < 16; ++kk) {
          float av[4], bv[4];
#pragma unroll
          for (int ii = 0; ii < 4; ++ii) av[ii] = Ablk[(4 * ty + ii) * 17 + kk];
#pragma unroll
          for (int jj = 0; jj < 4; ++jj) bv[jj] = Bblk[(4 * tx + jj) * 17 + kk];
#pragma unroll
          for (int ii = 0; ii < 4; ++ii)
#pragma unroll
            for (int jj = 0; jj < 4; ++jj)
              c4[ii][jj] = fmaf(-av[ii], bv[jj], c4[ii][jj]);
        }
#pragma unroll
        for (int ii = 0; ii < 4; ++ii)
#pragma unroll
          for (int jj = 0; jj < 4; ++jj)
            Cblk[(4 * ty + ii) * 17 + 4 * tx + jj] = c4[ii][jj];
      }
    }
    __syncthreads();
  }

  // write out: 136 blocks of 16x16 unpadded
  float* Lgb = Lg + (long)bh * 34816;
  for (int f = tid * 4; f < 136 * 256; f += 2048) {
    int bi = f >> 8, e = f & 255;
    int i = e >> 4, j = e & 15;  // j multiple of 4
    float4 v;
    v.x = Lb[bi * 272 + i * 17 + j];
    v.y = Lb[bi * 272 + i * 17 + j + 1];
    v.z = Lb[bi * 272 + i * 17 + j + 2];
    v.w = Lb[bi * 272 + i * 17 + j + 3];
    *(float4*)&Lgb[f] = v;
  }
}

// ---------------- blocked triangular solves, 16 RHS columns per block -------
// grid (4 chunks, 64 bh) x 256 threads. Writes Wt[bh][d][m].
__global__ __launch_bounds__(256) void tri_solve_kernel(
    const float* __restrict__ Lg, const float* __restrict__ T,
    float* __restrict__ Wt)
{
  __shared__ float Y[256 * 17];
  __shared__ float tmp[16 * 17];
  const int bh = blockIdx.y;
  const int d0 = blockIdx.x * 16;
  const int tid = threadIdx.x;
  const int i = tid >> 4, d = tid & 15;
  const float* Lb = Lg + (long)bh * 34816;
  const float* Tb = T + (long)bh * 16384;

  for (int r = i; r < 256; r += 16) Y[r * 17 + d] = Tb[r * 64 + d0 + d];
  __syncthreads();

  // forward: L y = T
  for (int J = 0; J < 16; ++J) {
    float acc = Y[(J * 16 + i) * 17 + d];
    for (int c = 0; c < J; ++c) {
      const float* Lblk = &Lb[(J * (J + 1) / 2 + c) * 256 + i * 16];
#pragma unroll
      for (int k = 0; k < 16; k += 4) {
        float4 l4 = *(const float4*)&Lblk[k];
        acc = fmaf(-l4.x, Y[(c * 16 + k + 0) * 17 + d], acc);
        acc = fmaf(-l4.y, Y[(c * 16 + k + 1) * 17 + d], acc);
        acc = fmaf(-l4.z, Y[(c * 16 + k + 2) * 17 + d], acc);
        acc = fmaf(-l4.w, Y[(c * 16 + k + 3) * 17 + d], acc);
      }
    }
    tmp[i * 17 + d] = acc;
    __syncthreads();
    const float* invD = &Lb[(J * (J + 1) / 2 + J) * 256 + i * 16];
    float y = 0.f;
#pragma unroll
    for (int k = 0; k < 16; ++k) y = fmaf(invD[k], tmp[k * 17 + d], y);
    Y[(J * 16 + i) * 17 + d] = y;
    __syncthreads();
  }

  // backward: L^T w = y
  for (int J = 15; J >= 0; --J) {
    float acc = Y[(J * 16 + i) * 17 + d];
    for (int I = J + 1; I < 16; ++I) {
      const float* Lblk = &Lb[(I * (I + 1) / 2 + J) * 256];
#pragma unroll
      for (int k = 0; k < 16; ++k)
        acc = fmaf(-Lblk[k * 16 + i], Y[(I * 16 + k) * 17 + d], acc);
    }
    tmp[i * 17 + d] = acc;
    __syncthreads();
    const float* invD = &Lb[(J * (J + 1) / 2 + J) * 256];
    float w = 0.f;
#pragma unroll
    for (int k = 0; k < 16; ++k) w = fmaf(invD[k * 16 + i], tmp[k * 17 + d], w);
    Y[(J * 16 + i) * 17 + d] = w;
    __syncthreads();
  }

  // write Wt[bh][d0+dc][m] = Y[m][dc]
  for (int f = tid; f < 16 * 256; f += 256) {
    int dc = f >> 8, m = f & 255;
    Wt[(long)bh * 16384 + (long)(d0 + dc) * 256 + m] = Y[m * 17 + dc];
  }
}

// ---------------- fused RFF(q) + out = PhiQ * W  → outheads (B,L,HD) --------
__global__ __launch_bounds__(256) void rffq_out_kernel(
    const float* __restrict__ q, const float* __restrict__ Wt,
    const float* __restrict__ rffW, const float* __restrict__ rffb,
    float* __restrict__ outheads)
{
  extern __shared__ float sm[];
  float* wt_lds = sm;                   // 64*260 = 16640
  float* w_lds  = sm + 16640;           // 8192
  float* rb_lds = sm + 16640 + 8192;    // 128
  float* q_lds  = rb_lds + 128;         // 256
  float* phi    = q_lds + 256;          // 1024
  const int b = blockIdx.z, h = blockIdx.y, l0 = blockIdx.x * 64;
  const int bh = b * H_ + h;
  const int tid = threadIdx.x;
  const float* Wtb = Wt + (long)bh * 16384;
  for (int f = tid; f < 16384; f += 256) {
    int d = f >> 8, mm = f & 255;
    wt_lds[d * 260 + mm] = Wtb[f];
  }
  const float* wsrc = rffW + h * 8192;
  for (int f = tid * 4; f < 8192; f += 1024)
    *(float4*)&w_lds[f] = *(const float4*)&wsrc[f];
  if (tid < 128) rb_lds[tid] = rffb[h * 128 + tid];
  __syncthreads();
  const int iw = tid >> 6;
  const int d = tid & 63;
  for (int lp = 0; lp < 64; lp += 4) {
    q_lds[iw * 64 + d] = q[(long)(b * L_ + l0 + lp + iw) * HD_ + h * VD_ + d];
    __syncthreads();
#pragma unroll
    for (int p = 0; p < 2; ++p) {
      int ii = (tid >> 7) + 2 * p;
      int mm = tid & 127;
      float proj = rb_lds[mm];
#pragma unroll 16
      for (int dd = 0; dd < 64; ++dd)
        proj = fmaf(q_lds[ii * 64 + dd], w_lds[dd * 128 + mm], proj);
      float sv, cv;
      sincosf(proj, &sv, &cv);
      phi[ii * 256 + mm] = SCALE_ * cv;
      phi[ii * 256 + 128 + mm] = SCALE_ * sv;
    }
    __syncthreads();
    float accv = 0.f;
    const float* wrow = wt_lds + d * 260;
    const float* prow = phi + iw * 256;
#pragma unroll 16
    for (int mm = 0; mm < 256; mm += 4) {
      float4 w4 = *(const float4*)(wrow + mm);
      float4 p4 = *(const float4*)(prow + mm);
      accv = fmaf(w4.x, p4.x, accv);
      accv = fmaf(w4.y, p4.y, accv);
      accv = fmaf(w4.z, p4.z, accv);
      accv = fmaf(w4.w, p4.w, accv);
    }
    outheads[(long)(b * L_ + l0 + lp + iw) * HD_ + h * VD_ + d] = accv;
    __syncthreads();
  }
}

__global__ void ws_too_small_kernel(float* out) { out[0] = 12345.0f; }

extern "C" void kernel_launch(void* const* d_in, const int* in_sizes, int n_in,
                              void* d_out, int out_size, void* d_ws, size_t ws_size,
                              hipStream_t stream) {
  const float* x    = (const float*)d_in[0];
  const float* mask = (const float*)d_in[2];
  const float* Wq   = (const float*)d_in[3];
  const float* Wk   = (const float*)d_in[4];
  const float* Wv   = (const float*)d_in[5];
  const float* Wo   = (const float*)d_in[6];
  const float* bo   = (const float*)d_in[7];
  const float* rffW = (const float*)d_in[8];
  const float* rffb = (const float*)d_in[9];
  float* out = (float*)d_out;
  float* ws  = (float*)d_ws;

  const size_t needed = 63963136UL * 4UL;  // 255.85 MB < 256 MiB
  if (ws_size < needed) {
    ws_too_small_kernel<<<1, 1, 0, stream>>>(out);
    return;
  }
  float* q    = ws;                 // 8388608
  float* k    = ws + 8388608;       // 8388608
  float* v    = ws + 16777216;      // 8388608
  float* phik = ws + 25165824;      // 33554432
  float* G    = ws + 58720256;      // 4194304
  float* T    = ws + 62914560;      // 1048576
  // Lg (blocked L+invD, 64*34816=2228224 floats) and Wt (1048576) alias the
  // dead phik region (chol runs strictly after G/T formation).
  float* Lg   = phik;
  float* Wt   = phik + 2228224;
  float* outheads = k;              // k dead after rff_k

  hipFuncSetAttribute((const void*)chol_factor_kernel,
                      hipFuncAttributeMaxDynamicSharedMemorySize, 147968);
  hipFuncSetAttribute((const void*)rffq_out_kernel,
                      hipFuncAttributeMaxDynamicSharedMemorySize, 104960);

  dim3 blk(256);
  dim3 g1(1024 / 128, 8192 / 128);

  gemm_nt_128<<<g1, blk, 0, stream>>>(x, Wq, q, 8192, 1024, 1024, nullptr, nullptr);
  gemm_nt_128<<<g1, blk, 0, stream>>>(x, Wk, k, 8192, 1024, 1024, nullptr, nullptr);
  gemm_nt_128<<<g1, blk, 0, stream>>>(x, Wv, v, 8192, 1024, 1024, nullptr, nullptr);

  dim3 g2(64, 16, 4);
  rff_k_kernel<<<g2, blk, 0, stream>>>(k, mask, rffW, rffb, phik);

  dim3 g3a(4, 4, 64);
  gemm_tn_64<<<g3a, blk, 0, stream>>>(phik, 8388608L, 524288L, 256,
                                      phik, 8388608L, 524288L, 256,
                                      G, 1048576L, 65536L, 256,
                                      2048, nullptr);
  dim3 g3b(1, 4, 64);
  gemm_tn_64<<<g3b, blk, 0, stream>>>(phik, 8388608L, 524288L, 256,
                                      v, 2097152L, 64L, 1024,
                                      T, 262144L, 16384L, 64,
                                      2048, mask);

  // blocked Cholesky factor + blocked triangular solves
  chol_factor_kernel<<<dim3(64), dim3(512), 147968, stream>>>(G, Lg);
  tri_solve_kernel<<<dim3(4, 64), dim3(256), 0, stream>>>(Lg, T, Wt);

  dim3 g5(32, 16, 4);
  rffq_out_kernel<<<g5, blk, 104960, stream>>>(q, Wt, rffW, rffb, outheads);

  gemm_nt_128<<<g1, blk, 0, stream>>>(outheads, Wo, out, 8192, 1024, 1024, bo, mask);
}

// Round 4
// 1813.060 us; speedup vs baseline: 2.6418x; 1.4459x over previous
//
#include <hip/hip_runtime.h>
#include <math.h>

#define B_ 4
#define L_ 2048
#define HD_ 1024
#define H_ 16
#define VD_ 64
#define M_ 128
#define M2_ 256
#define RIDGE_ 0.01f
#define SCALE_ 0.08838834764831845f   // 1/sqrt(128)

// ---------------- fp32 GEMM, C = A * B^T (both row-major, K contiguous) ----
__global__ __launch_bounds__(256) void gemm_nt_128(
    const float* __restrict__ A, const float* __restrict__ Bm, float* __restrict__ C,
    int Mdim, int Ndim, int Kdim,
    const float* __restrict__ bias, const float* __restrict__ mask)
{
  __shared__ __align__(16) float a_lds[8][132];
  __shared__ __align__(16) float b_lds[8][132];
  const int tid = threadIdx.x;
  const int tx = tid & 15, ty = tid >> 4;
  const int m0 = blockIdx.y * 128, n0 = blockIdx.x * 128;
  const int lr = tid >> 1;
  const int lc = (tid & 1) * 4;
  float acc[8][8];
#pragma unroll
  for (int i = 0; i < 8; ++i)
#pragma unroll
    for (int j = 0; j < 8; ++j) acc[i][j] = 0.f;

  const float* Ap = A + (long)(m0 + lr) * Kdim + lc;
  const float* Bp = Bm + (long)(n0 + lr) * Kdim + lc;

  for (int k0 = 0; k0 < Kdim; k0 += 8) {
    float4 av = *(const float4*)(Ap + k0);
    float4 bv = *(const float4*)(Bp + k0);
    __syncthreads();
    a_lds[lc + 0][lr] = av.x; a_lds[lc + 1][lr] = av.y;
    a_lds[lc + 2][lr] = av.z; a_lds[lc + 3][lr] = av.w;
    b_lds[lc + 0][lr] = bv.x; b_lds[lc + 1][lr] = bv.y;
    b_lds[lc + 2][lr] = bv.z; b_lds[lc + 3][lr] = bv.w;
    __syncthreads();
#pragma unroll
    for (int kk = 0; kk < 8; ++kk) {
      float4 a0 = *(const float4*)&a_lds[kk][8 * ty];
      float4 a1 = *(const float4*)&a_lds[kk][8 * ty + 4];
      float4 b0 = *(const float4*)&b_lds[kk][8 * tx];
      float4 b1 = *(const float4*)&b_lds[kk][8 * tx + 4];
      float a8[8] = {a0.x, a0.y, a0.z, a0.w, a1.x, a1.y, a1.z, a1.w};
      float b8[8] = {b0.x, b0.y, b0.z, b0.w, b1.x, b1.y, b1.z, b1.w};
#pragma unroll
      for (int i = 0; i < 8; ++i)
#pragma unroll
        for (int j = 0; j < 8; ++j) acc[i][j] = fmaf(a8[i], b8[j], acc[i][j]);
    }
  }
  float bb[8];
#pragma unroll
  for (int j = 0; j < 8; ++j) bb[j] = bias ? bias[n0 + 8 * tx + j] : 0.f;
#pragma unroll
  for (int i = 0; i < 8; ++i) {
    int r = m0 + 8 * ty + i;
    float mval = mask ? mask[r] : 1.f;
    float4 o0, o1;
    o0.x = (acc[i][0] + bb[0]) * mval; o0.y = (acc[i][1] + bb[1]) * mval;
    o0.z = (acc[i][2] + bb[2]) * mval; o0.w = (acc[i][3] + bb[3]) * mval;
    o1.x = (acc[i][4] + bb[4]) * mval; o1.y = (acc[i][5] + bb[5]) * mval;
    o1.z = (acc[i][6] + bb[6]) * mval; o1.w = (acc[i][7] + bb[7]) * mval;
    float* Cp = C + (long)r * Ndim + n0 + 8 * tx;
    *(float4*)Cp = o0;
    *(float4*)(Cp + 4) = o1;
  }
}

// ---------------- batched fp32 GEMM, C = A^T * B ---------------------------
__global__ __launch_bounds__(256) void gemm_tn_64(
    const float* __restrict__ A, long sAb, long sAh, int lda,
    const float* __restrict__ Bm, long sBb, long sBh, int ldb,
    float* __restrict__ C, long sCb, long sCh, int ldc,
    int Kdim, const float* __restrict__ maskB)
{
  __shared__ __align__(16) float a_lds[16][68];
  __shared__ __align__(16) float b_lds[16][68];
  const int tid = threadIdx.x;
  const int tx = tid & 15, ty = tid >> 4;
  const int z = blockIdx.z;
  const int bb_ = z >> 4, hh = z & 15;
  const int m0 = blockIdx.y * 64, n0 = blockIdx.x * 64;
  const float* Ab = A + bb_ * sAb + hh * sAh;
  const float* Bb = Bm + bb_ * sBb + hh * sBh;
  float* Cb = C + bb_ * sCb + hh * sCh;
  const int li = tid >> 4;
  const int lj = (tid & 15) * 4;
  const float* maskRow = maskB ? (maskB + (long)bb_ * L_) : nullptr;
  float acc[4][4];
#pragma unroll
  for (int i = 0; i < 4; ++i)
#pragma unroll
    for (int j = 0; j < 4; ++j) acc[i][j] = 0.f;

  for (int k0 = 0; k0 < Kdim; k0 += 16) {
    float4 av = *(const float4*)(Ab + (long)(k0 + li) * lda + m0 + lj);
    float4 bv = *(const float4*)(Bb + (long)(k0 + li) * ldb + n0 + lj);
    if (maskRow) {
      float mv = maskRow[k0 + li];
      bv.x *= mv; bv.y *= mv; bv.z *= mv; bv.w *= mv;
    }
    __syncthreads();
    *(float4*)&a_lds[li][lj] = av;
    *(float4*)&b_lds[li][lj] = bv;
    __syncthreads();
#pragma unroll
    for (int kk = 0; kk < 16; ++kk) {
      float4 a4 = *(const float4*)&a_lds[kk][4 * ty];
      float4 b4 = *(const float4*)&b_lds[kk][4 * tx];
      float a_[4] = {a4.x, a4.y, a4.z, a4.w};
      float b_[4] = {b4.x, b4.y, b4.z, b4.w};
#pragma unroll
      for (int i = 0; i < 4; ++i)
#pragma unroll
        for (int j = 0; j < 4; ++j) acc[i][j] = fmaf(a_[i], b_[j], acc[i][j]);
    }
  }
#pragma unroll
  for (int i = 0; i < 4; ++i) {
    float4 o;
    o.x = acc[i][0]; o.y = acc[i][1]; o.z = acc[i][2]; o.w = acc[i][3];
    *(float4*)(Cb + (long)(m0 + 4 * ty + i) * ldc + n0 + 4 * tx) = o;
  }
}

// ---------------- RFF features (shared q/k): phi (B,H,L,256) ----------------
// 64-row tile per block; 48.5KB LDS -> 3 blocks/CU. Each thread: 4x8 microtile
// of the 64x128 projection GEMM, sincos, coalesced float4 stores.
__global__ __launch_bounds__(256) void rff_kernel(
    const float* __restrict__ src, const float* __restrict__ mask,
    const float* __restrict__ rffW, const float* __restrict__ rffb,
    float* __restrict__ phi)
{
  __shared__ __align__(16) float w_lds[64][132];
  __shared__ __align__(16) float x_lds[64][68];
  __shared__ float b_lds[128];
  const int l0 = blockIdx.x * 64;
  const int h = blockIdx.y, b = blockIdx.z;
  const int tid = threadIdx.x;

  const float* wsrc = rffW + h * 8192;
  for (int f = tid * 4; f < 8192; f += 1024) {
    int d = f >> 7, m = f & 127;
    *(float4*)&w_lds[d][m] = *(const float4*)&wsrc[f];
  }
  if (tid < 128) b_lds[tid] = rffb[h * 128 + tid];
  {
    int r = tid >> 2, c0 = (tid & 3) * 16;
    const float* srow = src + (long)(b * L_ + l0 + r) * HD_ + h * VD_ + c0;
    *(float4*)&x_lds[r][c0 + 0]  = *(const float4*)(srow + 0);
    *(float4*)&x_lds[r][c0 + 4]  = *(const float4*)(srow + 4);
    *(float4*)&x_lds[r][c0 + 8]  = *(const float4*)(srow + 8);
    *(float4*)&x_lds[r][c0 + 12] = *(const float4*)(srow + 12);
  }
  __syncthreads();

  const int ty = tid >> 4, tx = tid & 15;  // rows 4ty..4ty+3, m = 4tx+64j+c
  float acc[4][8];
  {
    float4 b0 = *(const float4*)&b_lds[4 * tx];
    float4 b1 = *(const float4*)&b_lds[4 * tx + 64];
#pragma unroll
    for (int i = 0; i < 4; ++i) {
      acc[i][0] = b0.x; acc[i][1] = b0.y; acc[i][2] = b0.z; acc[i][3] = b0.w;
      acc[i][4] = b1.x; acc[i][5] = b1.y; acc[i][6] = b1.z; acc[i][7] = b1.w;
    }
  }
#pragma unroll 8
  for (int kk = 0; kk < 64; ++kk) {
    float4 w0 = *(const float4*)&w_lds[kk][4 * tx];
    float4 w1 = *(const float4*)&w_lds[kk][4 * tx + 64];
    float xv[4];
#pragma unroll
    for (int i = 0; i < 4; ++i) xv[i] = x_lds[4 * ty + i][kk];
#pragma unroll
    for (int i = 0; i < 4; ++i) {
      acc[i][0] = fmaf(xv[i], w0.x, acc[i][0]);
      acc[i][1] = fmaf(xv[i], w0.y, acc[i][1]);
      acc[i][2] = fmaf(xv[i], w0.z, acc[i][2]);
      acc[i][3] = fmaf(xv[i], w0.w, acc[i][3]);
      acc[i][4] = fmaf(xv[i], w1.x, acc[i][4]);
      acc[i][5] = fmaf(xv[i], w1.y, acc[i][5]);
      acc[i][6] = fmaf(xv[i], w1.z, acc[i][6]);
      acc[i][7] = fmaf(xv[i], w1.w, acc[i][7]);
    }
  }
#pragma unroll
  for (int i = 0; i < 4; ++i) {
    int l = l0 + 4 * ty + i;
    float f = SCALE_ * (mask ? mask[b * L_ + l] : 1.0f);
    float4 c0, c1, s0, s1;
    float sv, cv;
    sincosf(acc[i][0], &sv, &cv); c0.x = cv * f; s0.x = sv * f;
    sincosf(acc[i][1], &sv, &cv); c0.y = cv * f; s0.y = sv * f;
    sincosf(acc[i][2], &sv, &cv); c0.z = cv * f; s0.z = sv * f;
    sincosf(acc[i][3], &sv, &cv); c0.w = cv * f; s0.w = sv * f;
    sincosf(acc[i][4], &sv, &cv); c1.x = cv * f; s1.x = sv * f;
    sincosf(acc[i][5], &sv, &cv); c1.y = cv * f; s1.y = sv * f;
    sincosf(acc[i][6], &sv, &cv); c1.z = cv * f; s1.z = sv * f;
    sincosf(acc[i][7], &sv, &cv); c1.w = cv * f; s1.w = sv * f;
    long base = (long)((b * H_ + h) * L_ + l) * M2_;
    *(float4*)&phi[base + 4 * tx]        = c0;
    *(float4*)&phi[base + 4 * tx + 64]   = c1;
    *(float4*)&phi[base + 4 * tx + 128]  = s0;
    *(float4*)&phi[base + 4 * tx + 192]  = s1;
  }
}

// ---------------- blocked Cholesky factor (NB=16) + invD --------------------
__global__ __launch_bounds__(512) void chol_factor_kernel(
    const float* __restrict__ G, float* __restrict__ Lg)
{
  extern __shared__ float Lb[];  // 136*272
  const int bh = blockIdx.x;
  const int tid = threadIdx.x;
  const float* Gb = G + (long)bh * 65536;

  for (int f = tid; f < 136 * 256; f += 512) {
    int bi = f >> 8, e = f & 255;
    int i = e >> 4, j = e & 15;
    int I = 0; while ((I + 1) * (I + 2) / 2 <= bi) ++I;
    int J = bi - I * (I + 1) / 2;
    float v = Gb[(I * 16 + i) * 256 + J * 16 + j];
    if (I == J && i == j) v += RIDGE_;
    Lb[bi * 272 + i * 17 + j] = v;
  }
  __syncthreads();

  for (int p = 0; p < 16; ++p) {
    const int diagbase = (p * (p + 1) / 2 + p) * 272;
    if (tid < 64) {
      const int i = tid & 15;
      float r[16];
#pragma unroll
      for (int k = 0; k < 16; ++k) r[k] = Lb[diagbase + i * 17 + k];
#pragma unroll
      for (int j = 0; j < 16; ++j) {
        float dj = __shfl(r[j], j);
        float dinv = 1.0f / sqrtf(dj);
        r[j] *= dinv;
        float Lij = r[j];
#pragma unroll
        for (int k = j + 1; k < 16; ++k) {
          float Lkj = __shfl(r[j], k);
          r[k] = fmaf(-Lij, Lkj, r[k]);
        }
      }
      float x[16];
#pragma unroll
      for (int j = 0; j < 16; ++j) {
        float s = (i == j) ? 1.0f : 0.0f;
#pragma unroll
        for (int k = 0; k < j; ++k) {
          float Ljk = __shfl(r[k], j);
          s = fmaf(-Ljk, x[k], s);
        }
        float Ljj = __shfl(r[j], j);
        x[j] = s / Ljj;
      }
      if (tid < 16) {
#pragma unroll
        for (int j = 0; j < 16; ++j) Lb[diagbase + j * 17 + tid] = x[j];
      }
    }
    __syncthreads();

    const int nIb = 15 - p;
    const int tot = nIb * 256;
    float outv[8];
#pragma unroll
    for (int s = 0; s < 8; ++s) {
      int f = tid + s * 512;
      if (f < tot) {
        int Ib = f >> 8;
        int I = p + 1 + Ib;
        int e = f & 255;
        int i = e >> 4, j = e & 15;
        const float* Ablk = &Lb[(I * (I + 1) / 2 + p) * 272 + i * 17];
        const float* invD = &Lb[diagbase + j * 17];
        float s2 = 0.f;
#pragma unroll
        for (int k = 0; k < 16; ++k) s2 = fmaf(Ablk[k], invD[k], s2);
        outv[s] = s2;
      }
    }
    __syncthreads();
#pragma unroll
    for (int s = 0; s < 8; ++s) {
      int f = tid + s * 512;
      if (f < tot) {
        int Ib = f >> 8;
        int I = p + 1 + Ib;
        int e = f & 255;
        int i = e >> 4, j = e & 15;
        Lb[(I * (I + 1) / 2 + p) * 272 + i * 17 + j] = outv[s];
      }
    }
    __syncthreads();

    const int npairs = nIb * (nIb + 1) / 2;
    const int g = tid >> 4, t = tid & 15;
    const int tx = t & 3, ty = t >> 2;
    for (int pi0 = 0; pi0 < npairs; pi0 += 32) {
      int pi = pi0 + g;
      if (pi < npairs) {
        int a = 0; while ((a + 1) * (a + 2) / 2 <= pi) ++a;
        int b2 = pi - a * (a + 1) / 2;
        int I = p + 1 + a, J = p + 1 + b2;
        float* Cblk = &Lb[(I * (I + 1) / 2 + J) * 272];
        const float* Ablk = &Lb[(I * (I + 1) / 2 + p) * 272];
        const float* Bblk = &Lb[(J * (J + 1) / 2 + p) * 272];
        float c4[4][4];
#pragma unroll
        for (int ii = 0; ii < 4; ++ii)
#pragma unroll
          for (int jj = 0; jj < 4; ++jj)
            c4[ii][jj] = Cblk[(4 * ty + ii) * 17 + 4 * tx + jj];
#pragma unroll
        for (int kk = 0; kk < 16; ++kk) {
          float av[4], bv[4];
#pragma unroll
          for (int ii = 0; ii < 4; ++ii) av[ii] = Ablk[(4 * ty + ii) * 17 + kk];
#pragma unroll
          for (int jj = 0; jj < 4; ++jj) bv[jj] = Bblk[(4 * tx + jj) * 17 + kk];
#pragma unroll
          for (int ii = 0; ii < 4; ++ii)
#pragma unroll
            for (int jj = 0; jj < 4; ++jj)
              c4[ii][jj] = fmaf(-av[ii], bv[jj], c4[ii][jj]);
        }
#pragma unroll
        for (int ii = 0; ii < 4; ++ii)
#pragma unroll
          for (int jj = 0; jj < 4; ++jj)
            Cblk[(4 * ty + ii) * 17 + 4 * tx + jj] = c4[ii][jj];
      }
    }
    __syncthreads();
  }

  float* Lgb = Lg + (long)bh * 34816;
  for (int f = tid * 4; f < 136 * 256; f += 2048) {
    int bi = f >> 8, e = f & 255;
    int i = e >> 4, j = e & 15;
    float4 v;
    v.x = Lb[bi * 272 + i * 17 + j];
    v.y = Lb[bi * 272 + i * 17 + j + 1];
    v.z = Lb[bi * 272 + i * 17 + j + 2];
    v.w = Lb[bi * 272 + i * 17 + j + 3];
    *(float4*)&Lgb[f] = v;
  }
}

// ---------------- blocked triangular solves, 16 RHS columns per block -------
__global__ __launch_bounds__(256) void tri_solve_kernel(
    const float* __restrict__ Lg, const float* __restrict__ T,
    float* __restrict__ Wt)
{
  __shared__ float Y[256 * 17];
  __shared__ float tmp[16 * 17];
  const int bh = blockIdx.y;
  const int d0 = blockIdx.x * 16;
  const int tid = threadIdx.x;
  const int i = tid >> 4, d = tid & 15;
  const float* Lb = Lg + (long)bh * 34816;
  const float* Tb = T + (long)bh * 16384;

  for (int r = i; r < 256; r += 16) Y[r * 17 + d] = Tb[r * 64 + d0 + d];
  __syncthreads();

  for (int J = 0; J < 16; ++J) {
    float acc = Y[(J * 16 + i) * 17 + d];
    for (int c = 0; c < J; ++c) {
      const float* Lblk = &Lb[(J * (J + 1) / 2 + c) * 256 + i * 16];
#pragma unroll
      for (int k = 0; k < 16; k += 4) {
        float4 l4 = *(const float4*)&Lblk[k];
        acc = fmaf(-l4.x, Y[(c * 16 + k + 0) * 17 + d], acc);
        acc = fmaf(-l4.y, Y[(c * 16 + k + 1) * 17 + d], acc);
        acc = fmaf(-l4.z, Y[(c * 16 + k + 2) * 17 + d], acc);
        acc = fmaf(-l4.w, Y[(c * 16 + k + 3) * 17 + d], acc);
      }
    }
    tmp[i * 17 + d] = acc;
    __syncthreads();
    const float* invD = &Lb[(J * (J + 1) / 2 + J) * 256 + i * 16];
    float y = 0.f;
#pragma unroll
    for (int k = 0; k < 16; ++k) y = fmaf(invD[k], tmp[k * 17 + d], y);
    Y[(J * 16 + i) * 17 + d] = y;
    __syncthreads();
  }

  for (int J = 15; J >= 0; --J) {
    float acc = Y[(J * 16 + i) * 17 + d];
    for (int I = J + 1; I < 16; ++I) {
      const float* Lblk = &Lb[(I * (I + 1) / 2 + J) * 256];
#pragma unroll
      for (int k = 0; k < 16; ++k)
        acc = fmaf(-Lblk[k * 16 + i], Y[(I * 16 + k) * 17 + d], acc);
    }
    tmp[i * 17 + d] = acc;
    __syncthreads();
    const float* invD = &Lb[(J * (J + 1) / 2 + J) * 256];
    float w = 0.f;
#pragma unroll
    for (int k = 0; k < 16; ++k) w = fmaf(invD[k * 16 + i], tmp[k * 17 + d], w);
    Y[(J * 16 + i) * 17 + d] = w;
    __syncthreads();
  }

  for (int f = tid; f < 16 * 256; f += 256) {
    int dc = f >> 8, m = f & 255;
    Wt[(long)bh * 16384 + (long)(d0 + dc) * 256 + m] = Y[m * 17 + dc];
  }
}

// ---------------- batched GEMM: outheads = PhiQ @ Wt^T ----------------------
// grid (16 l-tiles, 64 bh), 256 thr; tile 128(l) x 64(d), K=256 (m).
__global__ __launch_bounds__(256) void gemm_nt_out(
    const float* __restrict__ phiQ, const float* __restrict__ Wt,
    float* __restrict__ outheads)
{
  __shared__ __align__(16) float a_lds[16][132];
  __shared__ __align__(16) float b_lds[16][68];
  const int tid = threadIdx.x;
  const int bh = blockIdx.y;
  const int b = bh >> 4, h = bh & 15;
  const int l0 = blockIdx.x * 128;
  const float* Ab = phiQ + (long)bh * (L_ * M2_) + (long)l0 * M2_;
  const float* Bb = Wt + (long)bh * 16384;

  const int alr = tid >> 1, alc = (tid & 1) * 8;
  const int bdr = tid >> 2, bmc = (tid & 3) * 4;
  const int ty = tid >> 4, tx = tid & 15;  // rows 8ty.., cols 4tx..
  float acc[8][4];
#pragma unroll
  for (int i = 0; i < 8; ++i)
#pragma unroll
    for (int j = 0; j < 4; ++j) acc[i][j] = 0.f;

  for (int k0 = 0; k0 < 256; k0 += 16) {
    float4 a0 = *(const float4*)(Ab + (long)alr * M2_ + k0 + alc);
    float4 a1 = *(const float4*)(Ab + (long)alr * M2_ + k0 + alc + 4);
    float4 bv = *(const float4*)(Bb + (long)bdr * M2_ + k0 + bmc);
    __syncthreads();
    a_lds[alc + 0][alr] = a0.x; a_lds[alc + 1][alr] = a0.y;
    a_lds[alc + 2][alr] = a0.z; a_lds[alc + 3][alr] = a0.w;
    a_lds[alc + 4][alr] = a1.x; a_lds[alc + 5][alr] = a1.y;
    a_lds[alc + 6][alr] = a1.z; a_lds[alc + 7][alr] = a1.w;
    b_lds[bmc + 0][bdr] = bv.x; b_lds[bmc + 1][bdr] = bv.y;
    b_lds[bmc + 2][bdr] = bv.z; b_lds[bmc + 3][bdr] = bv.w;
    __syncthreads();
#pragma unroll
    for (int kk = 0; kk < 16; ++kk) {
      float4 av0 = *(const float4*)&a_lds[kk][8 * ty];
      float4 av1 = *(const float4*)&a_lds[kk][8 * ty + 4];
      float4 bv4 = *(const float4*)&b_lds[kk][4 * tx];
      float a8[8] = {av0.x, av0.y, av0.z, av0.w, av1.x, av1.y, av1.z, av1.w};
      float b4[4] = {bv4.x, bv4.y, bv4.z, bv4.w};
#pragma unroll
      for (int i = 0; i < 8; ++i)
#pragma unroll
        for (int j = 0; j < 4; ++j) acc[i][j] = fmaf(a8[i], b4[j], acc[i][j]);
    }
  }
#pragma unroll
  for (int i = 0; i < 8; ++i) {
    float4 o;
    o.x = acc[i][0]; o.y = acc[i][1]; o.z = acc[i][2]; o.w = acc[i][3];
    *(float4*)&outheads[(long)(b * L_ + l0 + 8 * ty + i) * HD_ + h * VD_ + 4 * tx] = o;
  }
}

__global__ void ws_too_small_kernel(float* out) { out[0] = 12345.0f; }

extern "C" void kernel_launch(void* const* d_in, const int* in_sizes, int n_in,
                              void* d_out, int out_size, void* d_ws, size_t ws_size,
                              hipStream_t stream) {
  const float* x    = (const float*)d_in[0];
  const float* mask = (const float*)d_in[2];
  const float* Wq   = (const float*)d_in[3];
  const float* Wk   = (const float*)d_in[4];
  const float* Wv   = (const float*)d_in[5];
  const float* Wo   = (const float*)d_in[6];
  const float* bo   = (const float*)d_in[7];
  const float* rffW = (const float*)d_in[8];
  const float* rffb = (const float*)d_in[9];
  float* out = (float*)d_out;
  float* ws  = (float*)d_ws;

  const size_t needed = 63963136UL * 4UL;  // 255.85 MB < 256 MiB
  if (ws_size < needed) {
    ws_too_small_kernel<<<1, 1, 0, stream>>>(out);
    return;
  }
  float* q    = ws;                 // 8388608
  float* k    = ws + 8388608;       // 8388608
  float* v    = ws + 16777216;      // 8388608
  float* phik = ws + 25165824;      // 33554432
  float* G    = ws + 58720256;      // 4194304
  float* T    = ws + 62914560;      // 1048576
  // Lg (64*34816=2228224 floats) + Wt (1048576) alias the dead v region
  // (v is only read by the T-forming gemm_tn, which precedes chol/tri_solve).
  float* Lg   = v;
  float* Wt   = v + 2228224;
  // PhiQ reuses the full phik buffer (dead after G/T formation).
  float* phiq = phik;
  float* outheads = k;              // k dead after rff(k)

  hipFuncSetAttribute((const void*)chol_factor_kernel,
                      hipFuncAttributeMaxDynamicSharedMemorySize, 147968);

  dim3 blk(256);
  dim3 g1(1024 / 128, 8192 / 128);

  gemm_nt_128<<<g1, blk, 0, stream>>>(x, Wq, q, 8192, 1024, 1024, nullptr, nullptr);
  gemm_nt_128<<<g1, blk, 0, stream>>>(x, Wk, k, 8192, 1024, 1024, nullptr, nullptr);
  gemm_nt_128<<<g1, blk, 0, stream>>>(x, Wv, v, 8192, 1024, 1024, nullptr, nullptr);

  dim3 g2(32, 16, 4);   // L/64, H, B
  rff_kernel<<<g2, blk, 0, stream>>>(k, mask, rffW, rffb, phik);

  dim3 g3a(4, 4, 64);
  gemm_tn_64<<<g3a, blk, 0, stream>>>(phik, 8388608L, 524288L, 256,
                                      phik, 8388608L, 524288L, 256,
                                      G, 1048576L, 65536L, 256,
                                      2048, nullptr);
  dim3 g3b(1, 4, 64);
  gemm_tn_64<<<g3b, blk, 0, stream>>>(phik, 8388608L, 524288L, 256,
                                      v, 2097152L, 64L, 1024,
                                      T, 262144L, 16384L, 64,
                                      2048, mask);

  chol_factor_kernel<<<dim3(64), dim3(512), 147968, stream>>>(G, Lg);
  tri_solve_kernel<<<dim3(4, 64), dim3(256), 0, stream>>>(Lg, T, Wt);

  // PhiQ (unmasked) into phiq, then outheads = PhiQ @ Wt^T
  rff_kernel<<<g2, blk, 0, stream>>>(q, nullptr, rffW, rffb, phiq);
  gemm_nt_out<<<dim3(16, 64), blk, 0, stream>>>(phiq, Wt, outheads);

  gemm_nt_128<<<g1, blk, 0, stream>>>(outheads, Wo, out, 8192, 1024, 1024, bo, mask);
}

// Round 5
// 1293.686 us; speedup vs baseline: 3.7024x; 1.4015x over previous
//
#include <hip/hip_runtime.h>
#include <math.h>

#define B_ 4
#define L_ 2048
#define HD_ 1024
#define H_ 16
#define VD_ 64
#define M_ 128
#define M2_ 256
#define RIDGE_ 0.01f
#define SCALE_ 0.08838834764831845f   // 1/sqrt(128)

typedef unsigned short u16;
typedef __attribute__((ext_vector_type(8))) short short8;
typedef __attribute__((ext_vector_type(4))) float floatx4;

__device__ __forceinline__ u16 f2bf(float x) {
  unsigned u = __float_as_uint(x);
  unsigned r = u + 0x7fff + ((u >> 16) & 1);
  return (u16)(r >> 16);
}
__device__ __forceinline__ float bf2f(u16 h) {
  return __uint_as_float(((unsigned)h) << 16);
}
__device__ __forceinline__ void gload_lds16(const u16* g, u16* l) {
  __builtin_amdgcn_global_load_lds(
      (const __attribute__((address_space(1))) unsigned int*)g,
      (__attribute__((address_space(3))) unsigned int*)l, 16, 0, 0);
}

// ---------------- fp32 -> bf16 hi/lo split ---------------------------------
__global__ __launch_bounds__(256) void cvt_split_kernel(
    const float* __restrict__ src, u16* __restrict__ hi, u16* __restrict__ lo, int n4)
{
  int i = blockIdx.x * 256 + threadIdx.x;
  if (i < n4) {
    float4 f = ((const float4*)src)[i];
    u16 h0 = f2bf(f.x), h1 = f2bf(f.y), h2 = f2bf(f.z), h3 = f2bf(f.w);
    ushort4 hv = {h0, h1, h2, h3};
    ushort4 lv = {f2bf(f.x - bf2f(h0)), f2bf(f.y - bf2f(h1)),
                  f2bf(f.z - bf2f(h2)), f2bf(f.w - bf2f(h3))};
    ((ushort4*)hi)[i] = hv;
    ((ushort4*)lo)[i] = lv;
  }
}

// ---------------- fp32 -> bf16 (plain) -------------------------------------
__global__ __launch_bounds__(256) void cvt_bf16_kernel(
    const float* __restrict__ src, u16* __restrict__ hi, int n4)
{
  int i = blockIdx.x * 256 + threadIdx.x;
  if (i < n4) {
    float4 f = ((const float4*)src)[i];
    ushort4 hv = {f2bf(f.x), f2bf(f.y), f2bf(f.z), f2bf(f.w)};
    ((ushort4*)hi)[i] = hv;
  }
}

// ---------------- bf16 MFMA GEMM: C = sum_p A_p * B_p^T --------------------
// A_p: M x K bf16 row-major (ld ldA); B_p: N x K bf16 (ld ldB); C fp32 (ld Ndim).
// 128x128 tile, BK=32, 256 thr (4 waves, 2x2 of 64x64), 16x16x32 bf16 MFMA.
// LDS layout fragment-ordered: off(q,m) = (q*128+m)*8 u16 — contiguous 16B per
// (m,quad) so global_load_lds(width=16) staging matches lane order.
__global__ __launch_bounds__(256) void mfma_nt(
    const u16* __restrict__ A0, const u16* __restrict__ A1, const u16* __restrict__ A2,
    const u16* __restrict__ B0, const u16* __restrict__ B1, const u16* __restrict__ B2,
    float* __restrict__ C, int Ndim, int Kdim, int ldA, int ldB, int npass,
    const float* __restrict__ bias, const float* __restrict__ mask)
{
  __shared__ __align__(16) u16 a_sm[4096];  // 4 quads * 128 rows * 8
  __shared__ __align__(16) u16 b_sm[4096];
  const int tid = threadIdx.x;
  const int wave = tid >> 6, lane = tid & 63;
  const int m0 = blockIdx.y * 128, n0 = blockIdx.x * 128;
  const int wrow = (wave >> 1) * 64, wcol = (wave & 1) * 64;
  const int fm = lane & 15, q = lane >> 4;

  floatx4 acc[4][4];
#pragma unroll
  for (int i = 0; i < 4; ++i)
#pragma unroll
    for (int j = 0; j < 4; ++j) acc[i][j] = (floatx4){0.f, 0.f, 0.f, 0.f};

  for (int p = 0; p < npass; ++p) {
    const u16* Ap = (p == 0) ? A0 : ((p == 1) ? A1 : A2);
    const u16* Bp = (p == 0) ? B0 : ((p == 1) ? B1 : B2);
    // wave stages quad q=wave for rows lane and 64+lane of A and B tiles
    const u16* Ag0 = Ap + (long)(m0 + lane) * ldA + wave * 8;
    const u16* Ag1 = Ap + (long)(m0 + 64 + lane) * ldA + wave * 8;
    const u16* Bg0 = Bp + (long)(n0 + lane) * ldB + wave * 8;
    const u16* Bg1 = Bp + (long)(n0 + 64 + lane) * ldB + wave * 8;
    u16* la0 = &a_sm[(wave * 128 + 0) * 8];
    u16* la1 = &a_sm[(wave * 128 + 64) * 8];
    u16* lb0 = &b_sm[(wave * 128 + 0) * 8];
    u16* lb1 = &b_sm[(wave * 128 + 64) * 8];

    for (int k0 = 0; k0 < Kdim; k0 += 32) {
      __syncthreads();
      gload_lds16(Ag0 + k0, la0);
      gload_lds16(Ag1 + k0, la1);
      gload_lds16(Bg0 + k0, lb0);
      gload_lds16(Bg1 + k0, lb1);
      __syncthreads();
      short8 af[4], bf[4];
#pragma unroll
      for (int i = 0; i < 4; ++i)
        af[i] = *(const short8*)&a_sm[(q * 128 + wrow + i * 16 + fm) * 8];
#pragma unroll
      for (int j = 0; j < 4; ++j)
        bf[j] = *(const short8*)&b_sm[(q * 128 + wcol + j * 16 + fm) * 8];
#pragma unroll
      for (int i = 0; i < 4; ++i)
#pragma unroll
        for (int j = 0; j < 4; ++j)
          acc[i][j] = __builtin_amdgcn_mfma_f32_16x16x32_bf16(af[i], bf[j], acc[i][j], 0, 0, 0);
    }
  }

  // epilogue: C/D layout col=lane&15, row=(lane>>4)*4+reg
  const int colb = n0 + wcol + fm;
  const int rbase = m0 + wrow + (lane >> 4) * 4;
#pragma unroll
  for (int j = 0; j < 4; ++j) {
    int cg = colb + j * 16;
    float bb = bias ? bias[cg] : 0.f;
#pragma unroll
    for (int i = 0; i < 4; ++i) {
#pragma unroll
      for (int r = 0; r < 4; ++r) {
        int row = rbase + i * 16 + r;
        float val = acc[i][j][r];
        if (bias) val = (val + bb) * mask[row];
        C[(long)row * Ndim + cg] = val;
      }
    }
  }
}

// ---------------- batched fp32 GEMM, C = A^T * B ---------------------------
__global__ __launch_bounds__(256) void gemm_tn_64(
    const float* __restrict__ A, long sAb, long sAh, int lda,
    const float* __restrict__ Bm, long sBb, long sBh, int ldb,
    float* __restrict__ C, long sCb, long sCh, int ldc,
    int Kdim, const float* __restrict__ maskB)
{
  __shared__ __align__(16) float a_lds[16][68];
  __shared__ __align__(16) float b_lds[16][68];
  const int tid = threadIdx.x;
  const int tx = tid & 15, ty = tid >> 4;
  const int z = blockIdx.z;
  const int bb_ = z >> 4, hh = z & 15;
  const int m0 = blockIdx.y * 64, n0 = blockIdx.x * 64;
  const float* Ab = A + bb_ * sAb + hh * sAh;
  const float* Bb = Bm + bb_ * sBb + hh * sBh;
  float* Cb = C + bb_ * sCb + hh * sCh;
  const int li = tid >> 4;
  const int lj = (tid & 15) * 4;
  const float* maskRow = maskB ? (maskB + (long)bb_ * L_) : nullptr;
  float acc[4][4];
#pragma unroll
  for (int i = 0; i < 4; ++i)
#pragma unroll
    for (int j = 0; j < 4; ++j) acc[i][j] = 0.f;

  for (int k0 = 0; k0 < Kdim; k0 += 16) {
    float4 av = *(const float4*)(Ab + (long)(k0 + li) * lda + m0 + lj);
    float4 bv = *(const float4*)(Bb + (long)(k0 + li) * ldb + n0 + lj);
    if (maskRow) {
      float mv = maskRow[k0 + li];
      bv.x *= mv; bv.y *= mv; bv.z *= mv; bv.w *= mv;
    }
    __syncthreads();
    *(float4*)&a_lds[li][lj] = av;
    *(float4*)&b_lds[li][lj] = bv;
    __syncthreads();
#pragma unroll
    for (int kk = 0; kk < 16; ++kk) {
      float4 a4 = *(const float4*)&a_lds[kk][4 * ty];
      float4 b4 = *(const float4*)&b_lds[kk][4 * tx];
      float a_[4] = {a4.x, a4.y, a4.z, a4.w};
      float b_[4] = {b4.x, b4.y, b4.z, b4.w};
#pragma unroll
      for (int i = 0; i < 4; ++i)
#pragma unroll
        for (int j = 0; j < 4; ++j) acc[i][j] = fmaf(a_[i], b_[j], acc[i][j]);
    }
  }
#pragma unroll
  for (int i = 0; i < 4; ++i) {
    float4 o;
    o.x = acc[i][0]; o.y = acc[i][1]; o.z = acc[i][2]; o.w = acc[i][3];
    *(float4*)(Cb + (long)(m0 + 4 * ty + i) * ldc + n0 + 4 * tx) = o;
  }
}

// ---------------- RFF features: phi (B,H,L,256) -----------------------------
__global__ __launch_bounds__(256) void rff_kernel(
    const float* __restrict__ src, int ldS, const float* __restrict__ mask,
    const float* __restrict__ rffW, const float* __restrict__ rffb,
    float* __restrict__ phi)
{
  __shared__ __align__(16) float w_lds[64][132];
  __shared__ __align__(16) float x_lds[64][68];
  __shared__ float b_lds[128];
  const int l0 = blockIdx.x * 64;
  const int h = blockIdx.y, b = blockIdx.z;
  const int tid = threadIdx.x;

  const float* wsrc = rffW + h * 8192;
  for (int f = tid * 4; f < 8192; f += 1024) {
    int d = f >> 7, m = f & 127;
    *(float4*)&w_lds[d][m] = *(const float4*)&wsrc[f];
  }
  if (tid < 128) b_lds[tid] = rffb[h * 128 + tid];
  {
    int r = tid >> 2, c0 = (tid & 3) * 16;
    const float* srow = src + (long)(b * L_ + l0 + r) * ldS + h * VD_ + c0;
    *(float4*)&x_lds[r][c0 + 0]  = *(const float4*)(srow + 0);
    *(float4*)&x_lds[r][c0 + 4]  = *(const float4*)(srow + 4);
    *(float4*)&x_lds[r][c0 + 8]  = *(const float4*)(srow + 8);
    *(float4*)&x_lds[r][c0 + 12] = *(const float4*)(srow + 12);
  }
  __syncthreads();

  const int ty = tid >> 4, tx = tid & 15;
  float acc[4][8];
  {
    float4 b0 = *(const float4*)&b_lds[4 * tx];
    float4 b1 = *(const float4*)&b_lds[4 * tx + 64];
#pragma unroll
    for (int i = 0; i < 4; ++i) {
      acc[i][0] = b0.x; acc[i][1] = b0.y; acc[i][2] = b0.z; acc[i][3] = b0.w;
      acc[i][4] = b1.x; acc[i][5] = b1.y; acc[i][6] = b1.z; acc[i][7] = b1.w;
    }
  }
#pragma unroll 8
  for (int kk = 0; kk < 64; ++kk) {
    float4 w0 = *(const float4*)&w_lds[kk][4 * tx];
    float4 w1 = *(const float4*)&w_lds[kk][4 * tx + 64];
    float xv[4];
#pragma unroll
    for (int i = 0; i < 4; ++i) xv[i] = x_lds[4 * ty + i][kk];
#pragma unroll
    for (int i = 0; i < 4; ++i) {
      acc[i][0] = fmaf(xv[i], w0.x, acc[i][0]);
      acc[i][1] = fmaf(xv[i], w0.y, acc[i][1]);
      acc[i][2] = fmaf(xv[i], w0.z, acc[i][2]);
      acc[i][3] = fmaf(xv[i], w0.w, acc[i][3]);
      acc[i][4] = fmaf(xv[i], w1.x, acc[i][4]);
      acc[i][5] = fmaf(xv[i], w1.y, acc[i][5]);
      acc[i][6] = fmaf(xv[i], w1.z, acc[i][6]);
      acc[i][7] = fmaf(xv[i], w1.w, acc[i][7]);
    }
  }
#pragma unroll
  for (int i = 0; i < 4; ++i) {
    int l = l0 + 4 * ty + i;
    float f = SCALE_ * (mask ? mask[b * L_ + l] : 1.0f);
    float4 c0, c1, s0, s1;
    float sv, cv;
    sincosf(acc[i][0], &sv, &cv); c0.x = cv * f; s0.x = sv * f;
    sincosf(acc[i][1], &sv, &cv); c0.y = cv * f; s0.y = sv * f;
    sincosf(acc[i][2], &sv, &cv); c0.z = cv * f; s0.z = sv * f;
    sincosf(acc[i][3], &sv, &cv); c0.w = cv * f; s0.w = sv * f;
    sincosf(acc[i][4], &sv, &cv); c1.x = cv * f; s1.x = sv * f;
    sincosf(acc[i][5], &sv, &cv); c1.y = cv * f; s1.y = sv * f;
    sincosf(acc[i][6], &sv, &cv); c1.z = cv * f; s1.z = sv * f;
    sincosf(acc[i][7], &sv, &cv); c1.w = cv * f; s1.w = sv * f;
    long base = (long)((b * H_ + h) * L_ + l) * M2_;
    *(float4*)&phi[base + 4 * tx]        = c0;
    *(float4*)&phi[base + 4 * tx + 64]   = c1;
    *(float4*)&phi[base + 4 * tx + 128]  = s0;
    *(float4*)&phi[base + 4 * tx + 192]  = s1;
  }
}

// ---------------- blocked Cholesky factor (NB=16) + invD --------------------
__global__ __launch_bounds__(512) void chol_factor_kernel(
    const float* __restrict__ G, float* __restrict__ Lg)
{
  extern __shared__ float Lb[];  // 136*272
  const int bh = blockIdx.x;
  const int tid = threadIdx.x;
  const float* Gb = G + (long)bh * 65536;

  for (int f = tid; f < 136 * 256; f += 512) {
    int bi = f >> 8, e = f & 255;
    int i = e >> 4, j = e & 15;
    int I = 0; while ((I + 1) * (I + 2) / 2 <= bi) ++I;
    int J = bi - I * (I + 1) / 2;
    float v = Gb[(I * 16 + i) * 256 + J * 16 + j];
    if (I == J && i == j) v += RIDGE_;
    Lb[bi * 272 + i * 17 + j] = v;
  }
  __syncthreads();

  for (int p = 0; p < 16; ++p) {
    const int diagbase = (p * (p + 1) / 2 + p) * 272;
    if (tid < 64) {
      const int i = tid & 15;
      float r[16];
#pragma unroll
      for (int k = 0; k < 16; ++k) r[k] = Lb[diagbase + i * 17 + k];
#pragma unroll
      for (int j = 0; j < 16; ++j) {
        float dj = __shfl(r[j], j);
        float dinv = 1.0f / sqrtf(dj);
        r[j] *= dinv;
        float Lij = r[j];
#pragma unroll
        for (int k = j + 1; k < 16; ++k) {
          float Lkj = __shfl(r[j], k);
          r[k] = fmaf(-Lij, Lkj, r[k]);
        }
      }
      float x[16];
#pragma unroll
      for (int j = 0; j < 16; ++j) {
        float s = (i == j) ? 1.0f : 0.0f;
#pragma unroll
        for (int k = 0; k < j; ++k) {
          float Ljk = __shfl(r[k], j);
          s = fmaf(-Ljk, x[k], s);
        }
        float Ljj = __shfl(r[j], j);
        x[j] = s / Ljj;
      }
      if (tid < 16) {
#pragma unroll
        for (int j = 0; j < 16; ++j) Lb[diagbase + j * 17 + tid] = x[j];
      }
    }
    __syncthreads();

    const int nIb = 15 - p;
    const int tot = nIb * 256;
    float outv[8];
#pragma unroll
    for (int s = 0; s < 8; ++s) {
      int f = tid + s * 512;
      if (f < tot) {
        int Ib = f >> 8;
        int I = p + 1 + Ib;
        int e = f & 255;
        int i = e >> 4, j = e & 15;
        const float* Ablk = &Lb[(I * (I + 1) / 2 + p) * 272 + i * 17];
        const float* invD = &Lb[diagbase + j * 17];
        float s2 = 0.f;
#pragma unroll
        for (int k = 0; k < 16; ++k) s2 = fmaf(Ablk[k], invD[k], s2);
        outv[s] = s2;
      }
    }
    __syncthreads();
#pragma unroll
    for (int s = 0; s < 8; ++s) {
      int f = tid + s * 512;
      if (f < tot) {
        int Ib = f >> 8;
        int I = p + 1 + Ib;
        int e = f & 255;
        int i = e >> 4, j = e & 15;
        Lb[(I * (I + 1) / 2 + p) * 272 + i * 17 + j] = outv[s];
      }
    }
    __syncthreads();

    const int npairs = nIb * (nIb + 1) / 2;
    const int g = tid >> 4, t = tid & 15;
    const int tx = t & 3, ty = t >> 2;
    for (int pi0 = 0; pi0 < npairs; pi0 += 32) {
      int pi = pi0 + g;
      if (pi < npairs) {
        int a = 0; while ((a + 1) * (a + 2) / 2 <= pi) ++a;
        int b2 = pi - a * (a + 1) / 2;
        int I = p + 1 + a, J = p + 1 + b2;
        float* Cblk = &Lb[(I * (I + 1) / 2 + J) * 272];
        const float* Ablk = &Lb[(I * (I + 1) / 2 + p) * 272];
        const float* Bblk = &Lb[(J * (J + 1) / 2 + p) * 272];
        float c4[4][4];
#pragma unroll
        for (int ii = 0; ii < 4; ++ii)
#pragma unroll
          for (int jj = 0; jj < 4; ++jj)
            c4[ii][jj] = Cblk[(4 * ty + ii) * 17 + 4 * tx + jj];
#pragma unroll
        for (int kk = 0; kk < 16; ++kk) {
          float av[4], bv[4];
#pragma unroll
          for (int ii = 0; ii < 4; ++ii) av[ii] = Ablk[(4 * ty + ii) * 17 + kk];
#pragma unroll
          for (int jj = 0; jj < 4; ++jj) bv[jj] = Bblk[(4 * tx + jj) * 17 + kk];
#pragma unroll
          for (int ii = 0; ii < 4; ++ii)
#pragma unroll
            for (int jj = 0; jj < 4; ++jj)
              c4[ii][jj] = fmaf(-av[ii], bv[jj], c4[ii][jj]);
        }
#pragma unroll
        for (int ii = 0; ii < 4; ++ii)
#pragma unroll
          for (int jj = 0; jj < 4; ++jj)
            Cblk[(4 * ty + ii) * 17 + 4 * tx + jj] = c4[ii][jj];
      }
    }
    __syncthreads();
  }

  float* Lgb = Lg + (long)bh * 34816;
  for (int f = tid * 4; f < 136 * 256; f += 2048) {
    int bi = f >> 8, e = f & 255;
    int i = e >> 4, j = e & 15;
    float4 v;
    v.x = Lb[bi * 272 + i * 17 + j];
    v.y = Lb[bi * 272 + i * 17 + j + 1];
    v.z = Lb[bi * 272 + i * 17 + j + 2];
    v.w = Lb[bi * 272 + i * 17 + j + 3];
    *(float4*)&Lgb[f] = v;
  }
}

// ---------------- blocked triangular solves ---------------------------------
__global__ __launch_bounds__(256) void tri_solve_kernel(
    const float* __restrict__ Lg, const float* __restrict__ T,
    float* __restrict__ Wt)
{
  __shared__ float Y[256 * 17];
  __shared__ float tmp[16 * 17];
  const int bh = blockIdx.y;
  const int d0 = blockIdx.x * 16;
  const int tid = threadIdx.x;
  const int i = tid >> 4, d = tid & 15;
  const float* Lb = Lg + (long)bh * 34816;
  const float* Tb = T + (long)bh * 16384;

  for (int r = i; r < 256; r += 16) Y[r * 17 + d] = Tb[r * 64 + d0 + d];
  __syncthreads();

  for (int J = 0; J < 16; ++J) {
    float acc = Y[(J * 16 + i) * 17 + d];
    for (int c = 0; c < J; ++c) {
      const float* Lblk = &Lb[(J * (J + 1) / 2 + c) * 256 + i * 16];
#pragma unroll
      for (int k = 0; k < 16; k += 4) {
        float4 l4 = *(const float4*)&Lblk[k];
        acc = fmaf(-l4.x, Y[(c * 16 + k + 0) * 17 + d], acc);
        acc = fmaf(-l4.y, Y[(c * 16 + k + 1) * 17 + d], acc);
        acc = fmaf(-l4.z, Y[(c * 16 + k + 2) * 17 + d], acc);
        acc = fmaf(-l4.w, Y[(c * 16 + k + 3) * 17 + d], acc);
      }
    }
    tmp[i * 17 + d] = acc;
    __syncthreads();
    const float* invD = &Lb[(J * (J + 1) / 2 + J) * 256 + i * 16];
    float y = 0.f;
#pragma unroll
    for (int k = 0; k < 16; ++k) y = fmaf(invD[k], tmp[k * 17 + d], y);
    Y[(J * 16 + i) * 17 + d] = y;
    __syncthreads();
  }

  for (int J = 15; J >= 0; --J) {
    float acc = Y[(J * 16 + i) * 17 + d];
    for (int I = J + 1; I < 16; ++I) {
      const float* Lblk = &Lb[(I * (I + 1) / 2 + J) * 256];
#pragma unroll
      for (int k = 0; k < 16; ++k)
        acc = fmaf(-Lblk[k * 16 + i], Y[(I * 16 + k) * 17 + d], acc);
    }
    tmp[i * 17 + d] = acc;
    __syncthreads();
    const float* invD = &Lb[(J * (J + 1) / 2 + J) * 256];
    float w = 0.f;
#pragma unroll
    for (int k = 0; k < 16; ++k) w = fmaf(invD[k * 16 + i], tmp[k * 17 + d], w);
    Y[(J * 16 + i) * 17 + d] = w;
    __syncthreads();
  }

  for (int f = tid; f < 16 * 256; f += 256) {
    int dc = f >> 8, m = f & 255;
    Wt[(long)bh * 16384 + (long)(d0 + dc) * 256 + m] = Y[m * 17 + dc];
  }
}

// ---------------- batched GEMM: outheads = PhiQ @ Wt^T ----------------------
__global__ __launch_bounds__(256) void gemm_nt_out(
    const float* __restrict__ phiQ, const float* __restrict__ Wt,
    float* __restrict__ outheads)
{
  __shared__ __align__(16) float a_lds[16][132];
  __shared__ __align__(16) float b_lds[16][68];
  const int tid = threadIdx.x;
  const int bh = blockIdx.y;
  const int b = bh >> 4, h = bh & 15;
  const int l0 = blockIdx.x * 128;
  const float* Ab = phiQ + (long)bh * (L_ * M2_) + (long)l0 * M2_;
  const float* Bb = Wt + (long)bh * 16384;

  const int alr = tid >> 1, alc = (tid & 1) * 8;
  const int bdr = tid >> 2, bmc = (tid & 3) * 4;
  const int ty = tid >> 4, tx = tid & 15;
  float acc[8][4];
#pragma unroll
  for (int i = 0; i < 8; ++i)
#pragma unroll
    for (int j = 0; j < 4; ++j) acc[i][j] = 0.f;

  for (int k0 = 0; k0 < 256; k0 += 16) {
    float4 a0 = *(const float4*)(Ab + (long)alr * M2_ + k0 + alc);
    float4 a1 = *(const float4*)(Ab + (long)alr * M2_ + k0 + alc + 4);
    float4 bv = *(const float4*)(Bb + (long)bdr * M2_ + k0 + bmc);
    __syncthreads();
    a_lds[alc + 0][alr] = a0.x; a_lds[alc + 1][alr] = a0.y;
    a_lds[alc + 2][alr] = a0.z; a_lds[alc + 3][alr] = a0.w;
    a_lds[alc + 4][alr] = a1.x; a_lds[alc + 5][alr] = a1.y;
    a_lds[alc + 6][alr] = a1.z; a_lds[alc + 7][alr] = a1.w;
    b_lds[bmc + 0][bdr] = bv.x; b_lds[bmc + 1][bdr] = bv.y;
    b_lds[bmc + 2][bdr] = bv.z; b_lds[bmc + 3][bdr] = bv.w;
    __syncthreads();
#pragma unroll
    for (int kk = 0; kk < 16; ++kk) {
      float4 av0 = *(const float4*)&a_lds[kk][8 * ty];
      float4 av1 = *(const float4*)&a_lds[kk][8 * ty + 4];
      float4 bv4 = *(const float4*)&b_lds[kk][4 * tx];
      float a8[8] = {av0.x, av0.y, av0.z, av0.w, av1.x, av1.y, av1.z, av1.w};
      float b4[4] = {bv4.x, bv4.y, bv4.z, bv4.w};
#pragma unroll
      for (int i = 0; i < 8; ++i)
#pragma unroll
        for (int j = 0; j < 4; ++j) acc[i][j] = fmaf(a8[i], b4[j], acc[i][j]);
    }
  }
#pragma unroll
  for (int i = 0; i < 8; ++i) {
    float4 o;
    o.x = acc[i][0]; o.y = acc[i][1]; o.z = acc[i][2]; o.w = acc[i][3];
    *(float4*)&outheads[(long)(b * L_ + l0 + 8 * ty + i) * HD_ + h * VD_ + 4 * tx] = o;
  }
}

__global__ void ws_too_small_kernel(float* out) { out[0] = 12345.0f; }

extern "C" void kernel_launch(void* const* d_in, const int* in_sizes, int n_in,
                              void* d_out, int out_size, void* d_ws, size_t ws_size,
                              hipStream_t stream) {
  const float* x    = (const float*)d_in[0];
  const float* mask = (const float*)d_in[2];
  const float* Wq   = (const float*)d_in[3];
  const float* Wk   = (const float*)d_in[4];
  const float* Wv   = (const float*)d_in[5];
  const float* Wo   = (const float*)d_in[6];
  const float* bo   = (const float*)d_in[7];
  const float* rffW = (const float*)d_in[8];
  const float* rffb = (const float*)d_in[9];
  float* out = (float*)d_out;
  float* ws  = (float*)d_ws;

  const size_t needed = 66191360UL * 4UL;  // 264.77 MB <= 268.44 MB
  if (ws_size < needed) {
    ws_too_small_kernel<<<1, 1, 0, stream>>>(out);
    return;
  }
  // layout (floats)
  float* qkv  = ws;                  // 25,165,824  (8192 x 3072)
  float* phik = ws + 25165824;       // 33,554,432  (64 bh x 2048 x 256)
  float* G    = ws + 58720256;       //  4,194,304
  float* T    = ws + 62914560;       //  1,048,576
  float* Lg   = ws + 63963136;       //  2,228,224 (spare tail)
  // aliases:
  u16* x_hi = (u16*)phik;                       // 8,388,608 u16
  u16* x_lo = (u16*)(phik + 4194304);
  u16* w_hi = (u16*)(phik + 8388608);           // 3,145,728 u16 (Wq|Wk|Wv)
  u16* w_lo = (u16*)(phik + 9961472);
  float* Wt   = G;                   // G dead after chol; tri writes Wt here
  float* phiq = phik;                // phik dead after G/T gemms
  float* outheads = qkv;             // qkv dead after rff(q)
  u16* oh_bf16 = (u16*)(qkv + 8388608);
  u16* wo_hi   = (u16*)(qkv + 12582912);

  hipFuncSetAttribute((const void*)chol_factor_kernel,
                      hipFuncAttributeMaxDynamicSharedMemorySize, 147968);

  dim3 blk(256);

  // --- split-convert x, Wq, Wk, Wv to bf16 hi/lo ---
  cvt_split_kernel<<<8192, blk, 0, stream>>>(x, x_hi, x_lo, 2097152);
  cvt_split_kernel<<<1024, blk, 0, stream>>>(Wq, w_hi,           w_lo,           262144);
  cvt_split_kernel<<<1024, blk, 0, stream>>>(Wk, w_hi + 1048576, w_lo + 1048576, 262144);
  cvt_split_kernel<<<1024, blk, 0, stream>>>(Wv, w_hi + 2097152, w_lo + 2097152, 262144);

  // --- qkv = x @ [Wq;Wk;Wv]^T  (bf16x3: hi*hi + lo*hi + hi*lo) ---
  mfma_nt<<<dim3(24, 64), blk, 0, stream>>>(
      x_hi, x_lo, x_hi, w_hi, w_hi, w_lo,
      qkv, 3072, 1024, 1024, 1024, 3, nullptr, nullptr);

  // --- PhiK (masked), reading k slice of qkv ---
  dim3 g2(32, 16, 4);
  rff_kernel<<<g2, blk, 0, stream>>>(qkv + 1024, 3072, mask, rffW, rffb, phik);

  // --- G = PhiK^T PhiK ; T = PhiK^T (V*mask) ---
  dim3 g3a(4, 4, 64);
  gemm_tn_64<<<g3a, blk, 0, stream>>>(phik, 8388608L, 524288L, 256,
                                      phik, 8388608L, 524288L, 256,
                                      G, 1048576L, 65536L, 256,
                                      2048, nullptr);
  dim3 g3b(1, 4, 64);
  gemm_tn_64<<<g3b, blk, 0, stream>>>(phik, 8388608L, 524288L, 256,
                                      qkv + 2048, 6291456L, 64L, 3072,
                                      T, 262144L, 16384L, 64,
                                      2048, mask);

  // --- Cholesky + solves ---
  chol_factor_kernel<<<dim3(64), dim3(512), 147968, stream>>>(G, Lg);
  tri_solve_kernel<<<dim3(4, 64), dim3(256), 0, stream>>>(Lg, T, Wt);

  // --- PhiQ + outheads = PhiQ @ Wt^T ---
  rff_kernel<<<g2, blk, 0, stream>>>(qkv, 3072, nullptr, rffW, rffb, phiq);
  gemm_nt_out<<<dim3(16, 64), blk, 0, stream>>>(phiq, Wt, outheads);

  // --- final: (outheads @ Wo^T + bo) * mask  (plain bf16 MFMA) ---
  cvt_bf16_kernel<<<8192, blk, 0, stream>>>(outheads, oh_bf16, 2097152);
  cvt_bf16_kernel<<<1024, blk, 0, stream>>>(Wo, wo_hi, 262144);
  mfma_nt<<<dim3(8, 64), blk, 0, stream>>>(
      oh_bf16, nullptr, nullptr, wo_hi, nullptr, nullptr,
      out, 1024, 1024, 1024, 1024, 1, bo, mask);
}

// Round 6
// 1029.750 us; speedup vs baseline: 4.6513x; 1.2563x over previous
//
#include <hip/hip_runtime.h>
#include <math.h>

#define B_ 4
#define L_ 2048
#define HD_ 1024
#define H_ 16
#define VD_ 64
#define M_ 128
#define M2_ 256
#define RIDGE_ 0.01f
#define SCALE_ 0.08838834764831845f   // 1/sqrt(128)

typedef unsigned short u16;
typedef __attribute__((ext_vector_type(8))) short short8;
typedef __attribute__((ext_vector_type(4))) float floatx4;

__device__ __forceinline__ u16 f2bf(float x) {
  unsigned u = __float_as_uint(x);
  unsigned r = u + 0x7fff + ((u >> 16) & 1);
  return (u16)(r >> 16);
}
__device__ __forceinline__ float bf2f(u16 h) {
  return __uint_as_float(((unsigned)h) << 16);
}
__device__ __forceinline__ void gload_lds16(const u16* g, u16* l) {
  __builtin_amdgcn_global_load_lds(
      (const __attribute__((address_space(1))) unsigned int*)g,
      (__attribute__((address_space(3))) unsigned int*)l, 16, 0, 0);
}
__device__ __forceinline__ void split4(float4 f, ushort4* h, float4* r) {
  h->x = f2bf(f.x); h->y = f2bf(f.y); h->z = f2bf(f.z); h->w = f2bf(f.w);
  r->x = f.x - bf2f(h->x); r->y = f.y - bf2f(h->y);
  r->z = f.z - bf2f(h->z); r->w = f.w - bf2f(h->w);
}

// ---------------- fp32 -> bf16 hi/lo split ---------------------------------
__global__ __launch_bounds__(256) void cvt_split_kernel(
    const float* __restrict__ src, u16* __restrict__ hi, u16* __restrict__ lo, int n4)
{
  int i = blockIdx.x * 256 + threadIdx.x;
  if (i < n4) {
    float4 f = ((const float4*)src)[i];
    ushort4 hv; float4 r;
    split4(f, &hv, &r);
    ushort4 lv = {f2bf(r.x), f2bf(r.y), f2bf(r.z), f2bf(r.w)};
    ((ushort4*)hi)[i] = hv;
    ((ushort4*)lo)[i] = lv;
  }
}

__global__ __launch_bounds__(256) void cvt_bf16_kernel(
    const float* __restrict__ src, u16* __restrict__ hi, int n4)
{
  int i = blockIdx.x * 256 + threadIdx.x;
  if (i < n4) {
    float4 f = ((const float4*)src)[i];
    ushort4 hv = {f2bf(f.x), f2bf(f.y), f2bf(f.z), f2bf(f.w)};
    ((ushort4*)hi)[i] = hv;
  }
}

// ---------------- bf16 MFMA GEMM (single-pass), C = A * B^T ----------------
// (kept from R4, npass=1 use for the Wo projection)
__global__ __launch_bounds__(256) void mfma_nt(
    const u16* __restrict__ A0, const u16* __restrict__ B0,
    float* __restrict__ C, int Ndim, int Kdim, int ldA, int ldB,
    const float* __restrict__ bias, const float* __restrict__ mask)
{
  __shared__ __align__(16) u16 a_sm[4096];
  __shared__ __align__(16) u16 b_sm[4096];
  const int tid = threadIdx.x;
  const int wave = tid >> 6, lane = tid & 63;
  const int m0 = blockIdx.y * 128, n0 = blockIdx.x * 128;
  const int wrow = (wave >> 1) * 64, wcol = (wave & 1) * 64;
  const int fm = lane & 15, q = lane >> 4;

  floatx4 acc[4][4];
#pragma unroll
  for (int i = 0; i < 4; ++i)
#pragma unroll
    for (int j = 0; j < 4; ++j) acc[i][j] = (floatx4){0.f, 0.f, 0.f, 0.f};

  const u16* Ag0 = A0 + (long)(m0 + lane) * ldA + wave * 8;
  const u16* Ag1 = A0 + (long)(m0 + 64 + lane) * ldA + wave * 8;
  const u16* Bg0 = B0 + (long)(n0 + lane) * ldB + wave * 8;
  const u16* Bg1 = B0 + (long)(n0 + 64 + lane) * ldB + wave * 8;
  u16* la0 = &a_sm[(wave * 128 + 0) * 8];
  u16* la1 = &a_sm[(wave * 128 + 64) * 8];
  u16* lb0 = &b_sm[(wave * 128 + 0) * 8];
  u16* lb1 = &b_sm[(wave * 128 + 64) * 8];

  for (int k0 = 0; k0 < Kdim; k0 += 32) {
    __syncthreads();
    gload_lds16(Ag0 + k0, la0);
    gload_lds16(Ag1 + k0, la1);
    gload_lds16(Bg0 + k0, lb0);
    gload_lds16(Bg1 + k0, lb1);
    __syncthreads();
    short8 af[4], bf[4];
#pragma unroll
    for (int i = 0; i < 4; ++i)
      af[i] = *(const short8*)&a_sm[(q * 128 + wrow + i * 16 + fm) * 8];
#pragma unroll
    for (int j = 0; j < 4; ++j)
      bf[j] = *(const short8*)&b_sm[(q * 128 + wcol + j * 16 + fm) * 8];
#pragma unroll
    for (int i = 0; i < 4; ++i)
#pragma unroll
      for (int j = 0; j < 4; ++j)
        acc[i][j] = __builtin_amdgcn_mfma_f32_16x16x32_bf16(af[i], bf[j], acc[i][j], 0, 0, 0);
  }

  const int colb = n0 + wcol + fm;
  const int rbase = m0 + wrow + (lane >> 4) * 4;
#pragma unroll
  for (int j = 0; j < 4; ++j) {
    int cg = colb + j * 16;
    float bb = bias ? bias[cg] : 0.f;
#pragma unroll
    for (int i = 0; i < 4; ++i) {
#pragma unroll
      for (int r = 0; r < 4; ++r) {
        int row = rbase + i * 16 + r;
        float val = acc[i][j][r];
        if (bias) val = (val + bb) * mask[row];
        C[(long)row * Ndim + cg] = val;
      }
    }
  }
}

// ---------------- fused bf16x3 MFMA GEMM: C = Ah*Bh^T + Al*Bh^T + Ah*Bl^T ---
// QKV: A = x (8192x1024), B = [Wq;Wk;Wv] (3072x1024), C split into q/k/v.
__global__ __launch_bounds__(256) void mfma_nt3(
    const u16* __restrict__ Ah, const u16* __restrict__ Al,
    const u16* __restrict__ Bh, const u16* __restrict__ Bl,
    float* __restrict__ Cq, float* __restrict__ Ck, float* __restrict__ Cv)
{
  __shared__ __align__(16) u16 ah_sm[4096], al_sm[4096];
  __shared__ __align__(16) u16 bh_sm[4096], bl_sm[4096];
  const int tid = threadIdx.x;
  const int wave = tid >> 6, lane = tid & 63;
  const int m0 = blockIdx.y * 128, n0 = blockIdx.x * 128;
  const int wrow = (wave >> 1) * 64, wcol = (wave & 1) * 64;
  const int fm = lane & 15, q = lane >> 4;

  floatx4 acc[4][4];
#pragma unroll
  for (int i = 0; i < 4; ++i)
#pragma unroll
    for (int j = 0; j < 4; ++j) acc[i][j] = (floatx4){0.f, 0.f, 0.f, 0.f};

  const long a0o = (long)(m0 + lane) * 1024 + wave * 8;
  const long a1o = (long)(m0 + 64 + lane) * 1024 + wave * 8;
  const long b0o = (long)(n0 + lane) * 1024 + wave * 8;
  const long b1o = (long)(n0 + 64 + lane) * 1024 + wave * 8;
  u16* lah0 = &ah_sm[(wave * 128 + 0) * 8];
  u16* lah1 = &ah_sm[(wave * 128 + 64) * 8];
  u16* lal0 = &al_sm[(wave * 128 + 0) * 8];
  u16* lal1 = &al_sm[(wave * 128 + 64) * 8];
  u16* lbh0 = &bh_sm[(wave * 128 + 0) * 8];
  u16* lbh1 = &bh_sm[(wave * 128 + 64) * 8];
  u16* lbl0 = &bl_sm[(wave * 128 + 0) * 8];
  u16* lbl1 = &bl_sm[(wave * 128 + 64) * 8];

  for (int k0 = 0; k0 < 1024; k0 += 32) {
    __syncthreads();
    gload_lds16(Ah + a0o + k0, lah0);
    gload_lds16(Ah + a1o + k0, lah1);
    gload_lds16(Al + a0o + k0, lal0);
    gload_lds16(Al + a1o + k0, lal1);
    gload_lds16(Bh + b0o + k0, lbh0);
    gload_lds16(Bh + b1o + k0, lbh1);
    gload_lds16(Bl + b0o + k0, lbl0);
    gload_lds16(Bl + b1o + k0, lbl1);
    __syncthreads();
    short8 afh[4], afl[4], bfh[4], bfl[4];
#pragma unroll
    for (int i = 0; i < 4; ++i) {
      afh[i] = *(const short8*)&ah_sm[(q * 128 + wrow + i * 16 + fm) * 8];
      afl[i] = *(const short8*)&al_sm[(q * 128 + wrow + i * 16 + fm) * 8];
    }
#pragma unroll
    for (int j = 0; j < 4; ++j) {
      bfh[j] = *(const short8*)&bh_sm[(q * 128 + wcol + j * 16 + fm) * 8];
      bfl[j] = *(const short8*)&bl_sm[(q * 128 + wcol + j * 16 + fm) * 8];
    }
#pragma unroll
    for (int i = 0; i < 4; ++i)
#pragma unroll
      for (int j = 0; j < 4; ++j) {
        acc[i][j] = __builtin_amdgcn_mfma_f32_16x16x32_bf16(afh[i], bfh[j], acc[i][j], 0, 0, 0);
        acc[i][j] = __builtin_amdgcn_mfma_f32_16x16x32_bf16(afl[i], bfh[j], acc[i][j], 0, 0, 0);
        acc[i][j] = __builtin_amdgcn_mfma_f32_16x16x32_bf16(afh[i], bfl[j], acc[i][j], 0, 0, 0);
      }
  }

  // select output buffer by column block (n0 uniform per block)
  float* Cp; int cb;
  if (n0 < 1024)      { Cp = Cq; cb = n0; }
  else if (n0 < 2048) { Cp = Ck; cb = n0 - 1024; }
  else                { Cp = Cv; cb = n0 - 2048; }
  const int colb = cb + wcol + fm;
  const int rbase = m0 + wrow + (lane >> 4) * 4;
#pragma unroll
  for (int j = 0; j < 4; ++j) {
    int cg = colb + j * 16;
#pragma unroll
    for (int i = 0; i < 4; ++i)
#pragma unroll
      for (int r = 0; r < 4; ++r)
        Cp[(long)(rbase + i * 16 + r) * 1024 + cg] = acc[i][j][r];
  }
}

// ---------------- RFF(k): transposed bf16 hi/lo into pkT --------------------
// pkT layout (32 local bh, 320 rows, 2048 l); phi rows 0..255 (masked).
__global__ __launch_bounds__(256) void rff_k_t(
    const float* __restrict__ src, const float* __restrict__ mask,
    const float* __restrict__ rffW, const float* __restrict__ rffb,
    u16* __restrict__ pkh, u16* __restrict__ pkl, int b0)
{
  __shared__ __align__(16) float w_lds[64][132];
  __shared__ __align__(16) float x_lds[64][68];
  __shared__ float b_lds[128];
  const int l0 = blockIdx.x * 64;
  const int h = blockIdx.y, b = b0 + blockIdx.z;
  const int zloc = blockIdx.z * 16 + h;
  const int tid = threadIdx.x;

  const float* wsrc = rffW + h * 8192;
  for (int f = tid * 4; f < 8192; f += 1024) {
    int d = f >> 7, m = f & 127;
    *(float4*)&w_lds[d][m] = *(const float4*)&wsrc[f];
  }
  if (tid < 128) b_lds[tid] = rffb[h * 128 + tid];
  {
    int r = tid >> 2, c0 = (tid & 3) * 16;
    const float* srow = src + (long)(b * L_ + l0 + r) * 1024 + h * VD_ + c0;
    *(float4*)&x_lds[r][c0 + 0]  = *(const float4*)(srow + 0);
    *(float4*)&x_lds[r][c0 + 4]  = *(const float4*)(srow + 4);
    *(float4*)&x_lds[r][c0 + 8]  = *(const float4*)(srow + 8);
    *(float4*)&x_lds[r][c0 + 12] = *(const float4*)(srow + 12);
  }
  __syncthreads();

  const int ty = tid >> 4, tx = tid & 15;
  float acc[4][8];
  {
    float4 bb0 = *(const float4*)&b_lds[4 * tx];
    float4 bb1 = *(const float4*)&b_lds[4 * tx + 64];
#pragma unroll
    for (int i = 0; i < 4; ++i) {
      acc[i][0] = bb0.x; acc[i][1] = bb0.y; acc[i][2] = bb0.z; acc[i][3] = bb0.w;
      acc[i][4] = bb1.x; acc[i][5] = bb1.y; acc[i][6] = bb1.z; acc[i][7] = bb1.w;
    }
  }
#pragma unroll 8
  for (int kk = 0; kk < 64; ++kk) {
    float4 w0 = *(const float4*)&w_lds[kk][4 * tx];
    float4 w1 = *(const float4*)&w_lds[kk][4 * tx + 64];
    float xv[4];
#pragma unroll
    for (int i = 0; i < 4; ++i) xv[i] = x_lds[4 * ty + i][kk];
#pragma unroll
    for (int i = 0; i < 4; ++i) {
      acc[i][0] = fmaf(xv[i], w0.x, acc[i][0]);
      acc[i][1] = fmaf(xv[i], w0.y, acc[i][1]);
      acc[i][2] = fmaf(xv[i], w0.z, acc[i][2]);
      acc[i][3] = fmaf(xv[i], w0.w, acc[i][3]);
      acc[i][4] = fmaf(xv[i], w1.x, acc[i][4]);
      acc[i][5] = fmaf(xv[i], w1.y, acc[i][5]);
      acc[i][6] = fmaf(xv[i], w1.z, acc[i][6]);
      acc[i][7] = fmaf(xv[i], w1.w, acc[i][7]);
    }
  }
  float fi[4];
#pragma unroll
  for (int i = 0; i < 4; ++i) fi[i] = SCALE_ * mask[b * L_ + l0 + 4 * ty + i];
  float cvv[4][8], svv[4][8];
#pragma unroll
  for (int i = 0; i < 4; ++i)
#pragma unroll
    for (int jj = 0; jj < 8; ++jj) {
      float sv, cv;
      sincosf(acc[i][jj], &sv, &cv);
      cvv[i][jj] = cv * fi[i];
      svv[i][jj] = sv * fi[i];
    }
  const long lbase = l0 + 4 * ty;
  const long zbase = (long)zloc * 655360;
#pragma unroll
  for (int jj = 0; jj < 8; ++jj) {
    int mcol = (jj < 4) ? (4 * tx + jj) : (64 + 4 * tx + (jj - 4));
    ushort4 h4, l4;
    h4.x = f2bf(cvv[0][jj]); l4.x = f2bf(cvv[0][jj] - bf2f(h4.x));
    h4.y = f2bf(cvv[1][jj]); l4.y = f2bf(cvv[1][jj] - bf2f(h4.y));
    h4.z = f2bf(cvv[2][jj]); l4.z = f2bf(cvv[2][jj] - bf2f(h4.z));
    h4.w = f2bf(cvv[3][jj]); l4.w = f2bf(cvv[3][jj] - bf2f(h4.w));
    long base = zbase + (long)mcol * 2048 + lbase;
    *(ushort4*)&pkh[base] = h4;
    *(ushort4*)&pkl[base] = l4;
    ushort4 hs, ls;
    hs.x = f2bf(svv[0][jj]); ls.x = f2bf(svv[0][jj] - bf2f(hs.x));
    hs.y = f2bf(svv[1][jj]); ls.y = f2bf(svv[1][jj] - bf2f(hs.y));
    hs.z = f2bf(svv[2][jj]); ls.z = f2bf(svv[2][jj] - bf2f(hs.z));
    hs.w = f2bf(svv[3][jj]); ls.w = f2bf(svv[3][jj] - bf2f(hs.w));
    long base2 = zbase + (long)(mcol + 128) * 2048 + lbase;
    *(ushort4*)&pkh[base2] = hs;
    *(ushort4*)&pkl[base2] = ls;
  }
}

// ---------------- RFF(q): natural-layout bf16 hi/lo phiq (bh,l,256) ---------
__global__ __launch_bounds__(256) void rff_q_n(
    const float* __restrict__ src,
    const float* __restrict__ rffW, const float* __restrict__ rffb,
    u16* __restrict__ ph, u16* __restrict__ pl)
{
  __shared__ __align__(16) float w_lds[64][132];
  __shared__ __align__(16) float x_lds[64][68];
  __shared__ float b_lds[128];
  const int l0 = blockIdx.x * 64;
  const int h = blockIdx.y, b = blockIdx.z;
  const int tid = threadIdx.x;

  const float* wsrc = rffW + h * 8192;
  for (int f = tid * 4; f < 8192; f += 1024) {
    int d = f >> 7, m = f & 127;
    *(float4*)&w_lds[d][m] = *(const float4*)&wsrc[f];
  }
  if (tid < 128) b_lds[tid] = rffb[h * 128 + tid];
  {
    int r = tid >> 2, c0 = (tid & 3) * 16;
    const float* srow = src + (long)(b * L_ + l0 + r) * 1024 + h * VD_ + c0;
    *(float4*)&x_lds[r][c0 + 0]  = *(const float4*)(srow + 0);
    *(float4*)&x_lds[r][c0 + 4]  = *(const float4*)(srow + 4);
    *(float4*)&x_lds[r][c0 + 8]  = *(const float4*)(srow + 8);
    *(float4*)&x_lds[r][c0 + 12] = *(const float4*)(srow + 12);
  }
  __syncthreads();

  const int ty = tid >> 4, tx = tid & 15;
  float acc[4][8];
  {
    float4 bb0 = *(const float4*)&b_lds[4 * tx];
    float4 bb1 = *(const float4*)&b_lds[4 * tx + 64];
#pragma unroll
    for (int i = 0; i < 4; ++i) {
      acc[i][0] = bb0.x; acc[i][1] = bb0.y; acc[i][2] = bb0.z; acc[i][3] = bb0.w;
      acc[i][4] = bb1.x; acc[i][5] = bb1.y; acc[i][6] = bb1.z; acc[i][7] = bb1.w;
    }
  }
#pragma unroll 8
  for (int kk = 0; kk < 64; ++kk) {
    float4 w0 = *(const float4*)&w_lds[kk][4 * tx];
    float4 w1 = *(const float4*)&w_lds[kk][4 * tx + 64];
    float xv[4];
#pragma unroll
    for (int i = 0; i < 4; ++i) xv[i] = x_lds[4 * ty + i][kk];
#pragma unroll
    for (int i = 0; i < 4; ++i) {
      acc[i][0] = fmaf(xv[i], w0.x, acc[i][0]);
      acc[i][1] = fmaf(xv[i], w0.y, acc[i][1]);
      acc[i][2] = fmaf(xv[i], w0.z, acc[i][2]);
      acc[i][3] = fmaf(xv[i], w0.w, acc[i][3]);
      acc[i][4] = fmaf(xv[i], w1.x, acc[i][4]);
      acc[i][5] = fmaf(xv[i], w1.y, acc[i][5]);
      acc[i][6] = fmaf(xv[i], w1.z, acc[i][6]);
      acc[i][7] = fmaf(xv[i], w1.w, acc[i][7]);
    }
  }
#pragma unroll
  for (int i = 0; i < 4; ++i) {
    int l = l0 + 4 * ty + i;
    float4 c0, c1, s0, s1;
    float sv, cv;
    sincosf(acc[i][0], &sv, &cv); c0.x = cv * SCALE_; s0.x = sv * SCALE_;
    sincosf(acc[i][1], &sv, &cv); c0.y = cv * SCALE_; s0.y = sv * SCALE_;
    sincosf(acc[i][2], &sv, &cv); c0.z = cv * SCALE_; s0.z = sv * SCALE_;
    sincosf(acc[i][3], &sv, &cv); c0.w = cv * SCALE_; s0.w = sv * SCALE_;
    sincosf(acc[i][4], &sv, &cv); c1.x = cv * SCALE_; s1.x = sv * SCALE_;
    sincosf(acc[i][5], &sv, &cv); c1.y = cv * SCALE_; s1.y = sv * SCALE_;
    sincosf(acc[i][6], &sv, &cv); c1.z = cv * SCALE_; s1.z = sv * SCALE_;
    sincosf(acc[i][7], &sv, &cv); c1.w = cv * SCALE_; s1.w = sv * SCALE_;
    long base = ((long)(b * H_ + h) * L_ + l) * M2_;
    ushort4 hv; float4 r4;
    split4(c0, &hv, &r4);
    *(ushort4*)&ph[base + 4 * tx] = hv;
    *(ushort4*)&pl[base + 4 * tx] = (ushort4){f2bf(r4.x), f2bf(r4.y), f2bf(r4.z), f2bf(r4.w)};
    split4(c1, &hv, &r4);
    *(ushort4*)&ph[base + 64 + 4 * tx] = hv;
    *(ushort4*)&pl[base + 64 + 4 * tx] = (ushort4){f2bf(r4.x), f2bf(r4.y), f2bf(r4.z), f2bf(r4.w)};
    split4(s0, &hv, &r4);
    *(ushort4*)&ph[base + 128 + 4 * tx] = hv;
    *(ushort4*)&pl[base + 128 + 4 * tx] = (ushort4){f2bf(r4.x), f2bf(r4.y), f2bf(r4.z), f2bf(r4.w)};
    split4(s1, &hv, &r4);
    *(ushort4*)&ph[base + 192 + 4 * tx] = hv;
    *(ushort4*)&pl[base + 192 + 4 * tx] = (ushort4){f2bf(r4.x), f2bf(r4.y), f2bf(r4.z), f2bf(r4.w)};
  }
}

// ---------------- masked V transpose into pkT rows 256..319 -----------------
__global__ __launch_bounds__(256) void vt_kernel(
    const float* __restrict__ v, const float* __restrict__ mask,
    u16* __restrict__ pkh, u16* __restrict__ pkl, int b0)
{
  __shared__ float t[128][65];
  const int z = blockIdx.y;
  const int b = b0 + (z >> 4), h = z & 15;
  const int l0 = blockIdx.x * 128;
  const int tid = threadIdx.x;
  const int d = tid & 63, lg = tid >> 6;
  for (int i = 0; i < 128; i += 4) {
    int ll = i + lg;
    float mv = mask[b * L_ + l0 + ll];
    t[ll][d] = v[(long)(b * L_ + l0 + ll) * 1024 + h * 64 + d] * mv;
  }
  __syncthreads();
  const int d2 = tid >> 2, lofs = (tid & 3) * 32;
  long base = (long)z * 655360 + (long)(256 + d2) * 2048 + l0 + lofs;
  for (int j = 0; j < 32; j += 4) {
    float f0 = t[lofs + j + 0][d2], f1 = t[lofs + j + 1][d2];
    float f2 = t[lofs + j + 2][d2], f3 = t[lofs + j + 3][d2];
    ushort4 hv, lv;
    hv.x = f2bf(f0); lv.x = f2bf(f0 - bf2f(hv.x));
    hv.y = f2bf(f1); lv.y = f2bf(f1 - bf2f(hv.y));
    hv.z = f2bf(f2); lv.z = f2bf(f2 - bf2f(hv.z));
    hv.w = f2bf(f3); lv.w = f2bf(f3 - bf2f(hv.w));
    *(ushort4*)&pkh[base + j] = hv;
    *(ushort4*)&pkl[base + j] = lv;
  }
}

// ---------------- batched bf16x3 MFMA: [G|T] = Phi^T * [Phi|V] --------------
// A = pkT rows 0..255 (m), B = pkT rows n0..n0+63; K=2048; tile 128x64.
__global__ __launch_bounds__(256) void mfma_gt(
    const u16* __restrict__ pkh, const u16* __restrict__ pkl,
    float* __restrict__ G, float* __restrict__ T, int bh0)
{
  __shared__ __align__(16) u16 ah_sm[4096], al_sm[4096];
  __shared__ __align__(16) u16 bh_sm[2048], bl_sm[2048];
  const int tid = threadIdx.x;
  const int wave = tid >> 6, lane = tid & 63;
  const int z = blockIdx.z;
  const int m0 = blockIdx.y * 128, n0 = blockIdx.x * 64;
  const int wrow = (wave >> 1) * 64, wcol = (wave & 1) * 32;
  const int fm = lane & 15, q = lane >> 4;
  const long batch = (long)z * 655360;
  const u16* Ah = pkh + batch;
  const u16* Al = pkl + batch;

  floatx4 acc[4][2];
#pragma unroll
  for (int i = 0; i < 4; ++i)
#pragma unroll
    for (int j = 0; j < 2; ++j) acc[i][j] = (floatx4){0.f, 0.f, 0.f, 0.f};

  const long a0o = (long)(m0 + lane) * 2048 + wave * 8;
  const long a1o = (long)(m0 + 64 + lane) * 2048 + wave * 8;
  const long b0o = (long)(n0 + lane) * 2048 + wave * 8;
  u16* lah0 = &ah_sm[(wave * 128 + 0) * 8];
  u16* lah1 = &ah_sm[(wave * 128 + 64) * 8];
  u16* lal0 = &al_sm[(wave * 128 + 0) * 8];
  u16* lal1 = &al_sm[(wave * 128 + 64) * 8];
  u16* lbh = &bh_sm[(wave * 64) * 8];
  u16* lbl = &bl_sm[(wave * 64) * 8];

  for (int k0 = 0; k0 < 2048; k0 += 32) {
    __syncthreads();
    gload_lds16(Ah + a0o + k0, lah0);
    gload_lds16(Ah + a1o + k0, lah1);
    gload_lds16(Al + a0o + k0, lal0);
    gload_lds16(Al + a1o + k0, lal1);
    gload_lds16(Ah + b0o + k0, lbh);
    gload_lds16(Al + b0o + k0, lbl);
    __syncthreads();
    short8 afh[4], afl[4], bfh[2], bfl[2];
#pragma unroll
    for (int i = 0; i < 4; ++i) {
      afh[i] = *(const short8*)&ah_sm[(q * 128 + wrow + i * 16 + fm) * 8];
      afl[i] = *(const short8*)&al_sm[(q * 128 + wrow + i * 16 + fm) * 8];
    }
#pragma unroll
    for (int j = 0; j < 2; ++j) {
      bfh[j] = *(const short8*)&bh_sm[(q * 64 + wcol + j * 16 + fm) * 8];
      bfl[j] = *(const short8*)&bl_sm[(q * 64 + wcol + j * 16 + fm) * 8];
    }
#pragma unroll
    for (int i = 0; i < 4; ++i)
#pragma unroll
      for (int j = 0; j < 2; ++j) {
        acc[i][j] = __builtin_amdgcn_mfma_f32_16x16x32_bf16(afh[i], bfh[j], acc[i][j], 0, 0, 0);
        acc[i][j] = __builtin_amdgcn_mfma_f32_16x16x32_bf16(afl[i], bfh[j], acc[i][j], 0, 0, 0);
        acc[i][j] = __builtin_amdgcn_mfma_f32_16x16x32_bf16(afh[i], bfl[j], acc[i][j], 0, 0, 0);
      }
  }

  const int bh = bh0 + z;
  const int rbase = m0 + wrow + (lane >> 4) * 4;
#pragma unroll
  for (int j = 0; j < 2; ++j) {
    int col = n0 + wcol + j * 16 + fm;
#pragma unroll
    for (int i = 0; i < 4; ++i)
#pragma unroll
      for (int r = 0; r < 4; ++r) {
        int row = rbase + i * 16 + r;
        float val = acc[i][j][r];
        if (n0 < 256) G[(long)bh * 65536 + (long)row * 256 + col] = val;
        else T[(long)bh * 16384 + (long)row * 64 + (col - 256)] = val;
      }
  }
}

// ---------------- batched bf16x3 MFMA: oh = PhiQ @ Wt^T (bf16 out) ----------
__global__ __launch_bounds__(256) void mfma_out_k(
    const u16* __restrict__ ph, const u16* __restrict__ pl,
    const u16* __restrict__ wth, const u16* __restrict__ wtl,
    u16* __restrict__ oh)
{
  __shared__ __align__(16) u16 ah_sm[4096], al_sm[4096];
  __shared__ __align__(16) u16 bh_sm[2048], bl_sm[2048];
  const int tid = threadIdx.x;
  const int wave = tid >> 6, lane = tid & 63;
  const int bh = blockIdx.y;
  const int b = bh >> 4, h = bh & 15;
  const int l0 = blockIdx.x * 128;
  const int wrow = (wave >> 1) * 64, wcol = (wave & 1) * 32;
  const int fm = lane & 15, q = lane >> 4;
  const u16* Ah = ph + (long)bh * 524288 + (long)l0 * 256;
  const u16* Al = pl + (long)bh * 524288 + (long)l0 * 256;
  const u16* Bh = wth + (long)bh * 16384;
  const u16* Bl = wtl + (long)bh * 16384;

  floatx4 acc[4][2];
#pragma unroll
  for (int i = 0; i < 4; ++i)
#pragma unroll
    for (int j = 0; j < 2; ++j) acc[i][j] = (floatx4){0.f, 0.f, 0.f, 0.f};

  const long a0o = (long)lane * 256 + wave * 8;
  const long a1o = (long)(64 + lane) * 256 + wave * 8;
  const long b0o = (long)lane * 256 + wave * 8;
  u16* lah0 = &ah_sm[(wave * 128 + 0) * 8];
  u16* lah1 = &ah_sm[(wave * 128 + 64) * 8];
  u16* lal0 = &al_sm[(wave * 128 + 0) * 8];
  u16* lal1 = &al_sm[(wave * 128 + 64) * 8];
  u16* lbh = &bh_sm[(wave * 64) * 8];
  u16* lbl = &bl_sm[(wave * 64) * 8];

  for (int k0 = 0; k0 < 256; k0 += 32) {
    __syncthreads();
    gload_lds16(Ah + a0o + k0, lah0);
    gload_lds16(Ah + a1o + k0, lah1);
    gload_lds16(Al + a0o + k0, lal0);
    gload_lds16(Al + a1o + k0, lal1);
    gload_lds16(Bh + b0o + k0, lbh);
    gload_lds16(Bl + b0o + k0, lbl);
    __syncthreads();
    short8 afh[4], afl[4], bfh[2], bfl[2];
#pragma unroll
    for (int i = 0; i < 4; ++i) {
      afh[i] = *(const short8*)&ah_sm[(q * 128 + wrow + i * 16 + fm) * 8];
      afl[i] = *(const short8*)&al_sm[(q * 128 + wrow + i * 16 + fm) * 8];
    }
#pragma unroll
    for (int j = 0; j < 2; ++j) {
      bfh[j] = *(const short8*)&bh_sm[(q * 64 + wcol + j * 16 + fm) * 8];
      bfl[j] = *(const short8*)&bl_sm[(q * 64 + wcol + j * 16 + fm) * 8];
    }
#pragma unroll
    for (int i = 0; i < 4; ++i)
#pragma unroll
      for (int j = 0; j < 2; ++j) {
        acc[i][j] = __builtin_amdgcn_mfma_f32_16x16x32_bf16(afh[i], bfh[j], acc[i][j], 0, 0, 0);
        acc[i][j] = __builtin_amdgcn_mfma_f32_16x16x32_bf16(afl[i], bfh[j], acc[i][j], 0, 0, 0);
        acc[i][j] = __builtin_amdgcn_mfma_f32_16x16x32_bf16(afh[i], bfl[j], acc[i][j], 0, 0, 0);
      }
  }

  const int rbase = l0 + wrow + (lane >> 4) * 4;
#pragma unroll
  for (int j = 0; j < 2; ++j) {
    int col = h * 64 + wcol + j * 16 + fm;
#pragma unroll
    for (int i = 0; i < 4; ++i)
#pragma unroll
      for (int r = 0; r < 4; ++r)
        oh[(long)(b * L_ + rbase + i * 16 + r) * 1024 + col] = f2bf(acc[i][j][r]);
  }
}

// ---------------- blocked Cholesky factor (NB=16) + invD --------------------
__global__ __launch_bounds__(512) void chol_factor_kernel(
    const float* __restrict__ G, float* __restrict__ Lg)
{
  extern __shared__ float Lb[];  // 136*272
  const int bh = blockIdx.x;
  const int tid = threadIdx.x;
  const float* Gb = G + (long)bh * 65536;

  for (int f = tid; f < 136 * 256; f += 512) {
    int bi = f >> 8, e = f & 255;
    int i = e >> 4, j = e & 15;
    int I = 0; while ((I + 1) * (I + 2) / 2 <= bi) ++I;
    int J = bi - I * (I + 1) / 2;
    float v = Gb[(I * 16 + i) * 256 + J * 16 + j];
    if (I == J && i == j) v += RIDGE_;
    Lb[bi * 272 + i * 17 + j] = v;
  }
  __syncthreads();

  for (int p = 0; p < 16; ++p) {
    const int diagbase = (p * (p + 1) / 2 + p) * 272;
    if (tid < 64) {
      const int i = tid & 15;
      float r[16];
#pragma unroll
      for (int k = 0; k < 16; ++k) r[k] = Lb[diagbase + i * 17 + k];
#pragma unroll
      for (int j = 0; j < 16; ++j) {
        float dj = __shfl(r[j], j);
        float dinv = 1.0f / sqrtf(dj);
        r[j] *= dinv;
        float Lij = r[j];
#pragma unroll
        for (int k = j + 1; k < 16; ++k) {
          float Lkj = __shfl(r[j], k);
          r[k] = fmaf(-Lij, Lkj, r[k]);
        }
      }
      float x[16];
#pragma unroll
      for (int j = 0; j < 16; ++j) {
        float s = (i == j) ? 1.0f : 0.0f;
#pragma unroll
        for (int k = 0; k < j; ++k) {
          float Ljk = __shfl(r[k], j);
          s = fmaf(-Ljk, x[k], s);
        }
        float Ljj = __shfl(r[j], j);
        x[j] = s / Ljj;
      }
      if (tid < 16) {
#pragma unroll
        for (int j = 0; j < 16; ++j) Lb[diagbase + j * 17 + tid] = x[j];
      }
    }
    __syncthreads();

    const int nIb = 15 - p;
    const int tot = nIb * 256;
    float outv[8];
#pragma unroll
    for (int s = 0; s < 8; ++s) {
      int f = tid + s * 512;
      if (f < tot) {
        int Ib = f >> 8;
        int I = p + 1 + Ib;
        int e = f & 255;
        int i = e >> 4, j = e & 15;
        const float* Ablk = &Lb[(I * (I + 1) / 2 + p) * 272 + i * 17];
        const float* invD = &Lb[diagbase + j * 17];
        float s2 = 0.f;
#pragma unroll
        for (int k = 0; k < 16; ++k) s2 = fmaf(Ablk[k], invD[k], s2);
        outv[s] = s2;
      }
    }
    __syncthreads();
#pragma unroll
    for (int s = 0; s < 8; ++s) {
      int f = tid + s * 512;
      if (f < tot) {
        int Ib = f >> 8;
        int I = p + 1 + Ib;
        int e = f & 255;
        int i = e >> 4, j = e & 15;
        Lb[(I * (I + 1) / 2 + p) * 272 + i * 17 + j] = outv[s];
      }
    }
    __syncthreads();

    const int npairs = nIb * (nIb + 1) / 2;
    const int g = tid >> 4, t = tid & 15;
    const int tx = t & 3, ty = t >> 2;
    for (int pi0 = 0; pi0 < npairs; pi0 += 32) {
      int pi = pi0 + g;
      if (pi < npairs) {
        int a = 0; while ((a + 1) * (a + 2) / 2 <= pi) ++a;
        int b2 = pi - a * (a + 1) / 2;
        int I = p + 1 + a, J = p + 1 + b2;
        float* Cblk = &Lb[(I * (I + 1) / 2 + J) * 272];
        const float* Ablk = &Lb[(I * (I + 1) / 2 + p) * 272];
        const float* Bblk = &Lb[(J * (J + 1) / 2 + p) * 272];
        float c4[4][4];
#pragma unroll
        for (int ii = 0; ii < 4; ++ii)
#pragma unroll
          for (int jj = 0; jj < 4; ++jj)
            c4[ii][jj] = Cblk[(4 * ty + ii) * 17 + 4 * tx + jj];
#pragma unroll
        for (int kk = 0; kk < 16; ++kk) {
          float av[4], bv[4];
#pragma unroll
          for (int ii = 0; ii < 4; ++ii) av[ii] = Ablk[(4 * ty + ii) * 17 + kk];
#pragma unroll
          for (int jj = 0; jj < 4; ++jj) bv[jj] = Bblk[(4 * tx + jj) * 17 + kk];
#pragma unroll
          for (int ii = 0; ii < 4; ++ii)
#pragma unroll
            for (int jj = 0; jj < 4; ++jj)
              c4[ii][jj] = fmaf(-av[ii], bv[jj], c4[ii][jj]);
        }
#pragma unroll
        for (int ii = 0; ii < 4; ++ii)
#pragma unroll
          for (int jj = 0; jj < 4; ++jj)
            Cblk[(4 * ty + ii) * 17 + 4 * tx + jj] = c4[ii][jj];
      }
    }
    __syncthreads();
  }

  float* Lgb = Lg + (long)bh * 34816;
  for (int f = tid * 4; f < 136 * 256; f += 2048) {
    int bi = f >> 8, e = f & 255;
    int i = e >> 4, j = e & 15;
    float4 v;
    v.x = Lb[bi * 272 + i * 17 + j];
    v.y = Lb[bi * 272 + i * 17 + j + 1];
    v.z = Lb[bi * 272 + i * 17 + j + 2];
    v.w = Lb[bi * 272 + i * 17 + j + 3];
    *(float4*)&Lgb[f] = v;
  }
}

// ---------------- blocked triangular solves ---------------------------------
__global__ __launch_bounds__(256) void tri_solve_kernel(
    const float* __restrict__ Lg, const float* __restrict__ T,
    float* __restrict__ Wt)
{
  __shared__ float Y[256 * 17];
  __shared__ float tmp[16 * 17];
  const int bh = blockIdx.y;
  const int d0 = blockIdx.x * 16;
  const int tid = threadIdx.x;
  const int i = tid >> 4, d = tid & 15;
  const float* Lb = Lg + (long)bh * 34816;
  const float* Tb = T + (long)bh * 16384;

  for (int r = i; r < 256; r += 16) Y[r * 17 + d] = Tb[r * 64 + d0 + d];
  __syncthreads();

  for (int J = 0; J < 16; ++J) {
    float acc = Y[(J * 16 + i) * 17 + d];
    for (int c = 0; c < J; ++c) {
      const float* Lblk = &Lb[(J * (J + 1) / 2 + c) * 256 + i * 16];
#pragma unroll
      for (int k = 0; k < 16; k += 4) {
        float4 l4 = *(const float4*)&Lblk[k];
        acc = fmaf(-l4.x, Y[(c * 16 + k + 0) * 17 + d], acc);
        acc = fmaf(-l4.y, Y[(c * 16 + k + 1) * 17 + d], acc);
        acc = fmaf(-l4.z, Y[(c * 16 + k + 2) * 17 + d], acc);
        acc = fmaf(-l4.w, Y[(c * 16 + k + 3) * 17 + d], acc);
      }
    }
    tmp[i * 17 + d] = acc;
    __syncthreads();
    const float* invD = &Lb[(J * (J + 1) / 2 + J) * 256 + i * 16];
    float y = 0.f;
#pragma unroll
    for (int k = 0; k < 16; ++k) y = fmaf(invD[k], tmp[k * 17 + d], y);
    Y[(J * 16 + i) * 17 + d] = y;
    __syncthreads();
  }

  for (int J = 15; J >= 0; --J) {
    float acc = Y[(J * 16 + i) * 17 + d];
    for (int I = J + 1; I < 16; ++I) {
      const float* Lblk = &Lb[(I * (I + 1) / 2 + J) * 256];
#pragma unroll
      for (int k = 0; k < 16; ++k)
        acc = fmaf(-Lblk[k * 16 + i], Y[(I * 16 + k) * 17 + d], acc);
    }
    tmp[i * 17 + d] = acc;
    __syncthreads();
    const float* invD = &Lb[(J * (J + 1) / 2 + J) * 256];
    float w = 0.f;
#pragma unroll
    for (int k = 0; k < 16; ++k) w = fmaf(invD[k * 16 + i], tmp[k * 17 + d], w);
    Y[(J * 16 + i) * 17 + d] = w;
    __syncthreads();
  }

  for (int f = tid; f < 16 * 256; f += 256) {
    int dc = f >> 8, m = f & 255;
    Wt[(long)bh * 16384 + (long)(d0 + dc) * 256 + m] = Y[m * 17 + dc];
  }
}

__global__ void ws_too_small_kernel(float* out) { out[0] = 12345.0f; }

extern "C" void kernel_launch(void* const* d_in, const int* in_sizes, int n_in,
                              void* d_out, int out_size, void* d_ws, size_t ws_size,
                              hipStream_t stream) {
  const float* x    = (const float*)d_in[0];
  const float* mask = (const float*)d_in[2];
  const float* Wq   = (const float*)d_in[3];
  const float* Wk   = (const float*)d_in[4];
  const float* Wv   = (const float*)d_in[5];
  const float* Wo   = (const float*)d_in[6];
  const float* bo   = (const float*)d_in[7];
  const float* rffW = (const float*)d_in[8];
  const float* rffb = (const float*)d_in[9];
  float* out = (float*)d_out;
  float* ws  = (float*)d_ws;

  const size_t needed = 58720256UL * 4UL;  // 234.9 MB
  if (ws_size < needed) {
    ws_too_small_kernel<<<1, 1, 0, stream>>>(out);
    return;
  }
  // region A [0, 8.4M): q fp32 -> oh bf16 after rff(q)
  float* q = ws;
  u16* oh_bf = (u16*)ws;
  // region B [8.4M, 16.7M): k fp32 -> T(1M)+G(4.2M)+Lg(2.2M)
  //   (GT half-1 writes T[0..0.5M), G[1M..3.1M) -- only overlaps k rows b=0,1,
  //    which are dead after rff_k half-1; k rows b=2,3 at offset [4.2M,8.4M).)
  float* kbuf = ws + 8388608;
  float* T    = ws + 8388608;
  float* G    = ws + 9437184;
  float* Lg   = ws + 13631488;
  // region big [16.7M, 50.3M) as u16 [0, 67.1M):
  u16* big16 = (u16*)(ws + 16777216);
  u16* x_hi = big16;                 // staging (phase 1)
  u16* x_lo = big16 + 8388608;
  u16* w_hi = big16 + 16777216;
  u16* w_lo = big16 + 19922944;
  u16* pk_hi = big16;                // pkT half (phase 2): 32bh x 320 x 2048
  u16* pk_lo = big16 + 20971520;
  u16* phiq_hi = big16;              // phiq (phase 3): 64bh x 2048 x 256
  u16* phiq_lo = big16 + 33554432;
  // region D [50.3M, 58.7M): v fp32 -> wt_f/wt_hi/lo/wo_hi
  float* v = ws + 50331648;
  float* wt_f = ws + 50331648;
  u16* wt_hi = (u16*)(ws + 51380224);
  u16* wt_lo = wt_hi + 1048576;
  u16* wo_hi = wt_hi + 2097152;

  hipFuncSetAttribute((const void*)chol_factor_kernel,
                      hipFuncAttributeMaxDynamicSharedMemorySize, 147968);

  dim3 blk(256);

  // 1-2: convert x and fused W to bf16 hi/lo
  cvt_split_kernel<<<8192, blk, 0, stream>>>(x, x_hi, x_lo, 2097152);
  cvt_split_kernel<<<1024, blk, 0, stream>>>(Wq, w_hi,           w_lo,           262144);
  cvt_split_kernel<<<1024, blk, 0, stream>>>(Wk, w_hi + 1048576, w_lo + 1048576, 262144);
  cvt_split_kernel<<<1024, blk, 0, stream>>>(Wv, w_hi + 2097152, w_lo + 2097152, 262144);

  // 3: QKV fused bf16x3
  mfma_nt3<<<dim3(24, 64), blk, 0, stream>>>(x_hi, x_lo, w_hi, w_lo, q, kbuf, v);

  // 4-9: two bh-halves: rff(k)->pkT, vT->pkT, [G|T] MFMA
  for (int half = 0; half < 2; ++half) {
    int b0 = half * 2, bh0 = half * 32;
    rff_k_t<<<dim3(32, 16, 2), blk, 0, stream>>>(kbuf, mask, rffW, rffb, pk_hi, pk_lo, b0);
    vt_kernel<<<dim3(16, 32), blk, 0, stream>>>(v, mask, pk_hi, pk_lo, b0);
    mfma_gt<<<dim3(5, 2, 32), blk, 0, stream>>>(pk_hi, pk_lo, G, T, bh0);
  }

  // 10-12: Cholesky, solves, Wt split
  chol_factor_kernel<<<dim3(64), dim3(512), 147968, stream>>>(G, Lg);
  tri_solve_kernel<<<dim3(4, 64), dim3(256), 0, stream>>>(Lg, T, wt_f);
  cvt_split_kernel<<<1024, blk, 0, stream>>>(wt_f, wt_hi, wt_lo, 262144);

  // 13-14: PhiQ bf16 + out-heads MFMA (bf16 output)
  rff_q_n<<<dim3(32, 16, 4), blk, 0, stream>>>(q, rffW, rffb, phiq_hi, phiq_lo);
  mfma_out_k<<<dim3(16, 64), blk, 0, stream>>>(phiq_hi, phiq_lo, wt_hi, wt_lo, oh_bf);

  // 15-16: Wo projection (bf16 MFMA) with bias+mask epilogue
  cvt_bf16_kernel<<<1024, blk, 0, stream>>>(Wo, wo_hi, 262144);
  mfma_nt<<<dim3(8, 64), blk, 0, stream>>>(oh_bf, wo_hi, out, 1024, 1024, 1024, 1024, bo, mask);
}

// Round 7
// 969.460 us; speedup vs baseline: 4.9406x; 1.0622x over previous
//
#include <hip/hip_runtime.h>
#include <math.h>

#define B_ 4
#define L_ 2048
#define HD_ 1024
#define H_ 16
#define VD_ 64
#define M_ 128
#define M2_ 256
#define RIDGE_ 0.01f
#define SCALE_ 0.08838834764831845f   // 1/sqrt(128)

typedef unsigned short u16;
typedef __attribute__((ext_vector_type(8))) short short8;
typedef __attribute__((ext_vector_type(4))) float floatx4;

__device__ __forceinline__ u16 f2bf(float x) {
  unsigned u = __float_as_uint(x);
  unsigned r = u + 0x7fff + ((u >> 16) & 1);
  return (u16)(r >> 16);
}
__device__ __forceinline__ float bf2f(u16 h) {
  return __uint_as_float(((unsigned)h) << 16);
}
__device__ __forceinline__ void gload_lds16(const u16* g, u16* l) {
  __builtin_amdgcn_global_load_lds(
      (const __attribute__((address_space(1))) unsigned int*)g,
      (__attribute__((address_space(3))) unsigned int*)l, 16, 0, 0);
}
__device__ __forceinline__ void split4(float4 f, ushort4* h, float4* r) {
  h->x = f2bf(f.x); h->y = f2bf(f.y); h->z = f2bf(f.z); h->w = f2bf(f.w);
  r->x = f.x - bf2f(h->x); r->y = f.y - bf2f(h->y);
  r->z = f.z - bf2f(h->z); r->w = f.w - bf2f(h->w);
}

// ---------------- fp32 -> bf16 hi/lo split ---------------------------------
__global__ __launch_bounds__(256) void cvt_split_kernel(
    const float* __restrict__ src, u16* __restrict__ hi, u16* __restrict__ lo, int n4)
{
  int i = blockIdx.x * 256 + threadIdx.x;
  if (i < n4) {
    float4 f = ((const float4*)src)[i];
    ushort4 hv; float4 r;
    split4(f, &hv, &r);
    ushort4 lv = {f2bf(r.x), f2bf(r.y), f2bf(r.z), f2bf(r.w)};
    ((ushort4*)hi)[i] = hv;
    ((ushort4*)lo)[i] = lv;
  }
}

// ---------------- bf16 MFMA GEMM (single-pass), C = A * B^T ----------------
__global__ __launch_bounds__(256) void mfma_nt(
    const u16* __restrict__ A0, const u16* __restrict__ B0,
    float* __restrict__ C, int Ndim, int Kdim, int ldA, int ldB,
    const float* __restrict__ bias, const float* __restrict__ mask)
{
  __shared__ __align__(16) u16 a_sm[4096];
  __shared__ __align__(16) u16 b_sm[4096];
  const int tid = threadIdx.x;
  const int wave = tid >> 6, lane = tid & 63;
  const int m0 = blockIdx.y * 128, n0 = blockIdx.x * 128;
  const int wrow = (wave >> 1) * 64, wcol = (wave & 1) * 64;
  const int fm = lane & 15, q = lane >> 4;

  floatx4 acc[4][4];
#pragma unroll
  for (int i = 0; i < 4; ++i)
#pragma unroll
    for (int j = 0; j < 4; ++j) acc[i][j] = (floatx4){0.f, 0.f, 0.f, 0.f};

  const u16* Ag0 = A0 + (long)(m0 + lane) * ldA + wave * 8;
  const u16* Ag1 = A0 + (long)(m0 + 64 + lane) * ldA + wave * 8;
  const u16* Bg0 = B0 + (long)(n0 + lane) * ldB + wave * 8;
  const u16* Bg1 = B0 + (long)(n0 + 64 + lane) * ldB + wave * 8;
  u16* la0 = &a_sm[(wave * 128 + 0) * 8];
  u16* la1 = &a_sm[(wave * 128 + 64) * 8];
  u16* lb0 = &b_sm[(wave * 128 + 0) * 8];
  u16* lb1 = &b_sm[(wave * 128 + 64) * 8];

  for (int k0 = 0; k0 < Kdim; k0 += 32) {
    __syncthreads();
    gload_lds16(Ag0 + k0, la0);
    gload_lds16(Ag1 + k0, la1);
    gload_lds16(Bg0 + k0, lb0);
    gload_lds16(Bg1 + k0, lb1);
    __syncthreads();
    short8 af[4], bf[4];
#pragma unroll
    for (int i = 0; i < 4; ++i)
      af[i] = *(const short8*)&a_sm[(q * 128 + wrow + i * 16 + fm) * 8];
#pragma unroll
    for (int j = 0; j < 4; ++j)
      bf[j] = *(const short8*)&b_sm[(q * 128 + wcol + j * 16 + fm) * 8];
#pragma unroll
    for (int i = 0; i < 4; ++i)
#pragma unroll
      for (int j = 0; j < 4; ++j)
        acc[i][j] = __builtin_amdgcn_mfma_f32_16x16x32_bf16(af[i], bf[j], acc[i][j], 0, 0, 0);
  }

  const int colb = n0 + wcol + fm;
  const int rbase = m0 + wrow + (lane >> 4) * 4;
#pragma unroll
  for (int j = 0; j < 4; ++j) {
    int cg = colb + j * 16;
    float bb = bias ? bias[cg] : 0.f;
#pragma unroll
    for (int i = 0; i < 4; ++i) {
#pragma unroll
      for (int r = 0; r < 4; ++r) {
        int row = rbase + i * 16 + r;
        float val = acc[i][j][r];
        if (bias) val = (val + bb) * mask[row];
        C[(long)row * Ndim + cg] = val;
      }
    }
  }
}

// ---------------- fused bf16x3 MFMA GEMM (QKV) ------------------------------
// q,k columns: 3-pass (hi*hi + lo*hi + hi*lo); v columns (n0>=2048): hi*hi only.
__global__ __launch_bounds__(256) void mfma_nt3(
    const u16* __restrict__ Ah, const u16* __restrict__ Al,
    const u16* __restrict__ Bh, const u16* __restrict__ Bl,
    float* __restrict__ Cq, float* __restrict__ Ck, float* __restrict__ Cv)
{
  __shared__ __align__(16) u16 ah_sm[4096], al_sm[4096];
  __shared__ __align__(16) u16 bh_sm[4096], bl_sm[4096];
  const int tid = threadIdx.x;
  const int wave = tid >> 6, lane = tid & 63;
  const int m0 = blockIdx.y * 128, n0 = blockIdx.x * 128;
  const int wrow = (wave >> 1) * 64, wcol = (wave & 1) * 64;
  const int fm = lane & 15, q = lane >> 4;
  const bool vblk = (n0 >= 2048);   // block-uniform

  floatx4 acc[4][4];
#pragma unroll
  for (int i = 0; i < 4; ++i)
#pragma unroll
    for (int j = 0; j < 4; ++j) acc[i][j] = (floatx4){0.f, 0.f, 0.f, 0.f};

  const long a0o = (long)(m0 + lane) * 1024 + wave * 8;
  const long a1o = (long)(m0 + 64 + lane) * 1024 + wave * 8;
  const long b0o = (long)(n0 + lane) * 1024 + wave * 8;
  const long b1o = (long)(n0 + 64 + lane) * 1024 + wave * 8;
  u16* lah0 = &ah_sm[(wave * 128 + 0) * 8];
  u16* lah1 = &ah_sm[(wave * 128 + 64) * 8];
  u16* lal0 = &al_sm[(wave * 128 + 0) * 8];
  u16* lal1 = &al_sm[(wave * 128 + 64) * 8];
  u16* lbh0 = &bh_sm[(wave * 128 + 0) * 8];
  u16* lbh1 = &bh_sm[(wave * 128 + 64) * 8];
  u16* lbl0 = &bl_sm[(wave * 128 + 0) * 8];
  u16* lbl1 = &bl_sm[(wave * 128 + 64) * 8];

  for (int k0 = 0; k0 < 1024; k0 += 32) {
    __syncthreads();
    gload_lds16(Ah + a0o + k0, lah0);
    gload_lds16(Ah + a1o + k0, lah1);
    gload_lds16(Bh + b0o + k0, lbh0);
    gload_lds16(Bh + b1o + k0, lbh1);
    if (!vblk) {
      gload_lds16(Al + a0o + k0, lal0);
      gload_lds16(Al + a1o + k0, lal1);
      gload_lds16(Bl + b0o + k0, lbl0);
      gload_lds16(Bl + b1o + k0, lbl1);
    }
    __syncthreads();
    short8 afh[4], bfh[4];
#pragma unroll
    for (int i = 0; i < 4; ++i)
      afh[i] = *(const short8*)&ah_sm[(q * 128 + wrow + i * 16 + fm) * 8];
#pragma unroll
    for (int j = 0; j < 4; ++j)
      bfh[j] = *(const short8*)&bh_sm[(q * 128 + wcol + j * 16 + fm) * 8];
    if (vblk) {
#pragma unroll
      for (int i = 0; i < 4; ++i)
#pragma unroll
        for (int j = 0; j < 4; ++j)
          acc[i][j] = __builtin_amdgcn_mfma_f32_16x16x32_bf16(afh[i], bfh[j], acc[i][j], 0, 0, 0);
    } else {
      short8 afl[4], bfl[4];
#pragma unroll
      for (int i = 0; i < 4; ++i)
        afl[i] = *(const short8*)&al_sm[(q * 128 + wrow + i * 16 + fm) * 8];
#pragma unroll
      for (int j = 0; j < 4; ++j)
        bfl[j] = *(const short8*)&bl_sm[(q * 128 + wcol + j * 16 + fm) * 8];
#pragma unroll
      for (int i = 0; i < 4; ++i)
#pragma unroll
        for (int j = 0; j < 4; ++j) {
          acc[i][j] = __builtin_amdgcn_mfma_f32_16x16x32_bf16(afh[i], bfh[j], acc[i][j], 0, 0, 0);
          acc[i][j] = __builtin_amdgcn_mfma_f32_16x16x32_bf16(afl[i], bfh[j], acc[i][j], 0, 0, 0);
          acc[i][j] = __builtin_amdgcn_mfma_f32_16x16x32_bf16(afh[i], bfl[j], acc[i][j], 0, 0, 0);
        }
    }
  }

  float* Cp; int cb;
  if (n0 < 1024)      { Cp = Cq; cb = n0; }
  else if (n0 < 2048) { Cp = Ck; cb = n0 - 1024; }
  else                { Cp = Cv; cb = n0 - 2048; }
  const int colb = cb + wcol + fm;
  const int rbase = m0 + wrow + (lane >> 4) * 4;
#pragma unroll
  for (int j = 0; j < 4; ++j) {
    int cg = colb + j * 16;
#pragma unroll
    for (int i = 0; i < 4; ++i)
#pragma unroll
      for (int r = 0; r < 4; ++r)
        Cp[(long)(rbase + i * 16 + r) * 1024 + cg] = acc[i][j][r];
  }
}

// ---------------- RFF(k): transposed bf16 hi/lo into pkT --------------------
__global__ __launch_bounds__(256) void rff_k_t(
    const float* __restrict__ src, const float* __restrict__ mask,
    const float* __restrict__ rffW, const float* __restrict__ rffb,
    u16* __restrict__ pkh, u16* __restrict__ pkl, int b0)
{
  __shared__ __align__(16) float w_lds[64][132];
  __shared__ __align__(16) float x_lds[64][68];
  __shared__ float b_lds[128];
  const int l0 = blockIdx.x * 64;
  const int h = blockIdx.y, b = b0 + blockIdx.z;
  const int zloc = blockIdx.z * 16 + h;
  const int tid = threadIdx.x;

  const float* wsrc = rffW + h * 8192;
  for (int f = tid * 4; f < 8192; f += 1024) {
    int d = f >> 7, m = f & 127;
    *(float4*)&w_lds[d][m] = *(const float4*)&wsrc[f];
  }
  if (tid < 128) b_lds[tid] = rffb[h * 128 + tid];
  {
    int r = tid >> 2, c0 = (tid & 3) * 16;
    const float* srow = src + (long)(b * L_ + l0 + r) * 1024 + h * VD_ + c0;
    *(float4*)&x_lds[r][c0 + 0]  = *(const float4*)(srow + 0);
    *(float4*)&x_lds[r][c0 + 4]  = *(const float4*)(srow + 4);
    *(float4*)&x_lds[r][c0 + 8]  = *(const float4*)(srow + 8);
    *(float4*)&x_lds[r][c0 + 12] = *(const float4*)(srow + 12);
  }
  __syncthreads();

  const int ty = tid >> 4, tx = tid & 15;
  float acc[4][8];
  {
    float4 bb0 = *(const float4*)&b_lds[4 * tx];
    float4 bb1 = *(const float4*)&b_lds[4 * tx + 64];
#pragma unroll
    for (int i = 0; i < 4; ++i) {
      acc[i][0] = bb0.x; acc[i][1] = bb0.y; acc[i][2] = bb0.z; acc[i][3] = bb0.w;
      acc[i][4] = bb1.x; acc[i][5] = bb1.y; acc[i][6] = bb1.z; acc[i][7] = bb1.w;
    }
  }
#pragma unroll 8
  for (int kk = 0; kk < 64; ++kk) {
    float4 w0 = *(const float4*)&w_lds[kk][4 * tx];
    float4 w1 = *(const float4*)&w_lds[kk][4 * tx + 64];
    float xv[4];
#pragma unroll
    for (int i = 0; i < 4; ++i) xv[i] = x_lds[4 * ty + i][kk];
#pragma unroll
    for (int i = 0; i < 4; ++i) {
      acc[i][0] = fmaf(xv[i], w0.x, acc[i][0]);
      acc[i][1] = fmaf(xv[i], w0.y, acc[i][1]);
      acc[i][2] = fmaf(xv[i], w0.z, acc[i][2]);
      acc[i][3] = fmaf(xv[i], w0.w, acc[i][3]);
      acc[i][4] = fmaf(xv[i], w1.x, acc[i][4]);
      acc[i][5] = fmaf(xv[i], w1.y, acc[i][5]);
      acc[i][6] = fmaf(xv[i], w1.z, acc[i][6]);
      acc[i][7] = fmaf(xv[i], w1.w, acc[i][7]);
    }
  }
  float fi[4];
#pragma unroll
  for (int i = 0; i < 4; ++i) fi[i] = SCALE_ * mask[b * L_ + l0 + 4 * ty + i];
  float cvv[4][8], svv[4][8];
#pragma unroll
  for (int i = 0; i < 4; ++i)
#pragma unroll
    for (int jj = 0; jj < 8; ++jj) {
      float sv, cv;
      sincosf(acc[i][jj], &sv, &cv);
      cvv[i][jj] = cv * fi[i];
      svv[i][jj] = sv * fi[i];
    }
  const long lbase = l0 + 4 * ty;
  const long zbase = (long)zloc * 655360;
#pragma unroll
  for (int jj = 0; jj < 8; ++jj) {
    int mcol = (jj < 4) ? (4 * tx + jj) : (64 + 4 * tx + (jj - 4));
    ushort4 h4, l4;
    h4.x = f2bf(cvv[0][jj]); l4.x = f2bf(cvv[0][jj] - bf2f(h4.x));
    h4.y = f2bf(cvv[1][jj]); l4.y = f2bf(cvv[1][jj] - bf2f(h4.y));
    h4.z = f2bf(cvv[2][jj]); l4.z = f2bf(cvv[2][jj] - bf2f(h4.z));
    h4.w = f2bf(cvv[3][jj]); l4.w = f2bf(cvv[3][jj] - bf2f(h4.w));
    long base = zbase + (long)mcol * 2048 + lbase;
    *(ushort4*)&pkh[base] = h4;
    *(ushort4*)&pkl[base] = l4;
    ushort4 hs, ls;
    hs.x = f2bf(svv[0][jj]); ls.x = f2bf(svv[0][jj] - bf2f(hs.x));
    hs.y = f2bf(svv[1][jj]); ls.y = f2bf(svv[1][jj] - bf2f(hs.y));
    hs.z = f2bf(svv[2][jj]); ls.z = f2bf(svv[2][jj] - bf2f(hs.z));
    hs.w = f2bf(svv[3][jj]); ls.w = f2bf(svv[3][jj] - bf2f(hs.w));
    long base2 = zbase + (long)(mcol + 128) * 2048 + lbase;
    *(ushort4*)&pkh[base2] = hs;
    *(ushort4*)&pkl[base2] = ls;
  }
}

// ---------------- masked V transpose into pkT rows 256..319 -----------------
__global__ __launch_bounds__(256) void vt_kernel(
    const float* __restrict__ v, const float* __restrict__ mask,
    u16* __restrict__ pkh, u16* __restrict__ pkl, int b0)
{
  __shared__ float t[128][65];
  const int z = blockIdx.y;
  const int b = b0 + (z >> 4), h = z & 15;
  const int l0 = blockIdx.x * 128;
  const int tid = threadIdx.x;
  const int d = tid & 63, lg = tid >> 6;
  for (int i = 0; i < 128; i += 4) {
    int ll = i + lg;
    float mv = mask[b * L_ + l0 + ll];
    t[ll][d] = v[(long)(b * L_ + l0 + ll) * 1024 + h * 64 + d] * mv;
  }
  __syncthreads();
  const int d2 = tid >> 2, lofs = (tid & 3) * 32;
  long base = (long)z * 655360 + (long)(256 + d2) * 2048 + l0 + lofs;
  for (int j = 0; j < 32; j += 4) {
    float f0 = t[lofs + j + 0][d2], f1 = t[lofs + j + 1][d2];
    float f2 = t[lofs + j + 2][d2], f3 = t[lofs + j + 3][d2];
    ushort4 hv, lv;
    hv.x = f2bf(f0); lv.x = f2bf(f0 - bf2f(hv.x));
    hv.y = f2bf(f1); lv.y = f2bf(f1 - bf2f(hv.y));
    hv.z = f2bf(f2); lv.z = f2bf(f2 - bf2f(hv.z));
    hv.w = f2bf(f3); lv.w = f2bf(f3 - bf2f(hv.w));
    *(ushort4*)&pkh[base + j] = hv;
    *(ushort4*)&pkl[base + j] = lv;
  }
}

// ---------------- batched bf16x3 MFMA: [G|T] = Phi^T * [Phi|V] --------------
__global__ __launch_bounds__(256) void mfma_gt(
    const u16* __restrict__ pkh, const u16* __restrict__ pkl,
    float* __restrict__ G, float* __restrict__ T, int bh0)
{
  __shared__ __align__(16) u16 ah_sm[4096], al_sm[4096];
  __shared__ __align__(16) u16 bh_sm[2048], bl_sm[2048];
  const int tid = threadIdx.x;
  const int wave = tid >> 6, lane = tid & 63;
  const int z = blockIdx.z;
  const int m0 = blockIdx.y * 128, n0 = blockIdx.x * 64;
  const int wrow = (wave >> 1) * 64, wcol = (wave & 1) * 32;
  const int fm = lane & 15, q = lane >> 4;
  const long batch = (long)z * 655360;
  const u16* Ah = pkh + batch;
  const u16* Al = pkl + batch;

  floatx4 acc[4][2];
#pragma unroll
  for (int i = 0; i < 4; ++i)
#pragma unroll
    for (int j = 0; j < 2; ++j) acc[i][j] = (floatx4){0.f, 0.f, 0.f, 0.f};

  const long a0o = (long)(m0 + lane) * 2048 + wave * 8;
  const long a1o = (long)(m0 + 64 + lane) * 2048 + wave * 8;
  const long b0o = (long)(n0 + lane) * 2048 + wave * 8;
  u16* lah0 = &ah_sm[(wave * 128 + 0) * 8];
  u16* lah1 = &ah_sm[(wave * 128 + 64) * 8];
  u16* lal0 = &al_sm[(wave * 128 + 0) * 8];
  u16* lal1 = &al_sm[(wave * 128 + 64) * 8];
  u16* lbh = &bh_sm[(wave * 64) * 8];
  u16* lbl = &bl_sm[(wave * 64) * 8];

  for (int k0 = 0; k0 < 2048; k0 += 32) {
    __syncthreads();
    gload_lds16(Ah + a0o + k0, lah0);
    gload_lds16(Ah + a1o + k0, lah1);
    gload_lds16(Al + a0o + k0, lal0);
    gload_lds16(Al + a1o + k0, lal1);
    gload_lds16(Ah + b0o + k0, lbh);
    gload_lds16(Al + b0o + k0, lbl);
    __syncthreads();
    short8 afh[4], afl[4], bfh[2], bfl[2];
#pragma unroll
    for (int i = 0; i < 4; ++i) {
      afh[i] = *(const short8*)&ah_sm[(q * 128 + wrow + i * 16 + fm) * 8];
      afl[i] = *(const short8*)&al_sm[(q * 128 + wrow + i * 16 + fm) * 8];
    }
#pragma unroll
    for (int j = 0; j < 2; ++j) {
      bfh[j] = *(const short8*)&bh_sm[(q * 64 + wcol + j * 16 + fm) * 8];
      bfl[j] = *(const short8*)&bl_sm[(q * 64 + wcol + j * 16 + fm) * 8];
    }
#pragma unroll
    for (int i = 0; i < 4; ++i)
#pragma unroll
      for (int j = 0; j < 2; ++j) {
        acc[i][j] = __builtin_amdgcn_mfma_f32_16x16x32_bf16(afh[i], bfh[j], acc[i][j], 0, 0, 0);
        acc[i][j] = __builtin_amdgcn_mfma_f32_16x16x32_bf16(afl[i], bfh[j], acc[i][j], 0, 0, 0);
        acc[i][j] = __builtin_amdgcn_mfma_f32_16x16x32_bf16(afh[i], bfl[j], acc[i][j], 0, 0, 0);
      }
  }

  const int bh = bh0 + z;
  const int rbase = m0 + wrow + (lane >> 4) * 4;
#pragma unroll
  for (int j = 0; j < 2; ++j) {
    int col = n0 + wcol + j * 16 + fm;
#pragma unroll
    for (int i = 0; i < 4; ++i)
#pragma unroll
      for (int r = 0; r < 4; ++r) {
        int row = rbase + i * 16 + r;
        float val = acc[i][j][r];
        if (n0 < 256) G[(long)bh * 65536 + (long)row * 256 + col] = val;
        else T[(long)bh * 16384 + (long)row * 64 + (col - 256)] = val;
      }
  }
}

// ---------------- batched bf16x3 MFMA: oh = PhiQ @ Wt^T (bf16 out) ----------
__global__ __launch_bounds__(256) void mfma_out_k(
    const u16* __restrict__ ph, const u16* __restrict__ pl,
    const u16* __restrict__ wth, const u16* __restrict__ wtl,
    u16* __restrict__ oh)
{
  __shared__ __align__(16) u16 ah_sm[4096], al_sm[4096];
  __shared__ __align__(16) u16 bh_sm[2048], bl_sm[2048];
  const int tid = threadIdx.x;
  const int wave = tid >> 6, lane = tid & 63;
  const int bh = blockIdx.y;
  const int b = bh >> 4, h = bh & 15;
  const int l0 = blockIdx.x * 128;
  const int wrow = (wave >> 1) * 64, wcol = (wave & 1) * 32;
  const int fm = lane & 15, q = lane >> 4;
  const u16* Ah = ph + (long)bh * 524288 + (long)l0 * 256;
  const u16* Al = pl + (long)bh * 524288 + (long)l0 * 256;
  const u16* Bh = wth + (long)bh * 16384;
  const u16* Bl = wtl + (long)bh * 16384;

  floatx4 acc[4][2];
#pragma unroll
  for (int i = 0; i < 4; ++i)
#pragma unroll
    for (int j = 0; j < 2; ++j) acc[i][j] = (floatx4){0.f, 0.f, 0.f, 0.f};

  const long a0o = (long)lane * 256 + wave * 8;
  const long a1o = (long)(64 + lane) * 256 + wave * 8;
  const long b0o = (long)lane * 256 + wave * 8;
  u16* lah0 = &ah_sm[(wave * 128 + 0) * 8];
  u16* lah1 = &ah_sm[(wave * 128 + 64) * 8];
  u16* lal0 = &al_sm[(wave * 128 + 0) * 8];
  u16* lal1 = &al_sm[(wave * 128 + 64) * 8];
  u16* lbh = &bh_sm[(wave * 64) * 8];
  u16* lbl = &bl_sm[(wave * 64) * 8];

  for (int k0 = 0; k0 < 256; k0 += 32) {
    __syncthreads();
    gload_lds16(Ah + a0o + k0, lah0);
    gload_lds16(Ah + a1o + k0, lah1);
    gload_lds16(Al + a0o + k0, lal0);
    gload_lds16(Al + a1o + k0, lal1);
    gload_lds16(Bh + b0o + k0, lbh);
    gload_lds16(Bl + b0o + k0, lbl);
    __syncthreads();
    short8 afh[4], afl[4], bfh[2], bfl[2];
#pragma unroll
    for (int i = 0; i < 4; ++i) {
      afh[i] = *(const short8*)&ah_sm[(q * 128 + wrow + i * 16 + fm) * 8];
      afl[i] = *(const short8*)&al_sm[(q * 128 + wrow + i * 16 + fm) * 8];
    }
#pragma unroll
    for (int j = 0; j < 2; ++j) {
      bfh[j] = *(const short8*)&bh_sm[(q * 64 + wcol + j * 16 + fm) * 8];
      bfl[j] = *(const short8*)&bl_sm[(q * 64 + wcol + j * 16 + fm) * 8];
    }
#pragma unroll
    for (int i = 0; i < 4; ++i)
#pragma unroll
      for (int j = 0; j < 2; ++j) {
        acc[i][j] = __builtin_amdgcn_mfma_f32_16x16x32_bf16(afh[i], bfh[j], acc[i][j], 0, 0, 0);
        acc[i][j] = __builtin_amdgcn_mfma_f32_16x16x32_bf16(afl[i], bfh[j], acc[i][j], 0, 0, 0);
        acc[i][j] = __builtin_amdgcn_mfma_f32_16x16x32_bf16(afh[i], bfl[j], acc[i][j], 0, 0, 0);
      }
  }

  const int rbase = l0 + wrow + (lane >> 4) * 4;
#pragma unroll
  for (int j = 0; j < 2; ++j) {
    int col = h * 64 + wcol + j * 16 + fm;
#pragma unroll
    for (int i = 0; i < 4; ++i)
#pragma unroll
      for (int r = 0; r < 4; ++r)
        oh[(long)(b * L_ + rbase + i * 16 + r) * 1024 + col] = f2bf(acc[i][j][r]);
  }
}

// ---------------- fused: chol (blocks 0-63) + rff(q) (64-1087) + Wo cvt -----
__global__ __launch_bounds__(512) void chol_rffq_wo_kernel(
    const float* __restrict__ G, float* __restrict__ Lg,
    const float* __restrict__ qsrc,
    const float* __restrict__ rffW, const float* __restrict__ rffb,
    u16* __restrict__ ph, u16* __restrict__ pl,
    const float* __restrict__ Wo, u16* __restrict__ wo_hi)
{
  extern __shared__ float sm[];
  const int bx = blockIdx.x;
  const int tid = threadIdx.x;

  if (bx < 64) {
    // ================= Cholesky factor, 1 bh per block =================
    float* Lb = sm;  // 136*272 floats
    const int bh = bx;
    const float* Gb = G + (long)bh * 65536;
    for (int f = tid; f < 136 * 256; f += 512) {
      int bi = f >> 8, e = f & 255;
      int i = e >> 4, j = e & 15;
      int I = 0; while ((I + 1) * (I + 2) / 2 <= bi) ++I;
      int J = bi - I * (I + 1) / 2;
      float v = Gb[(I * 16 + i) * 256 + J * 16 + j];
      if (I == J && i == j) v += RIDGE_;
      Lb[bi * 272 + i * 17 + j] = v;
    }
    __syncthreads();

    for (int p = 0; p < 16; ++p) {
      const int diagbase = (p * (p + 1) / 2 + p) * 272;
      if (tid < 64) {
        const int i = tid & 15;
        float r[16];
#pragma unroll
        for (int k = 0; k < 16; ++k) r[k] = Lb[diagbase + i * 17 + k];
#pragma unroll
        for (int j = 0; j < 16; ++j) {
          float dj = __shfl(r[j], j);
          float dinv = 1.0f / sqrtf(dj);
          r[j] *= dinv;
          float Lij = r[j];
#pragma unroll
          for (int k = j + 1; k < 16; ++k) {
            float Lkj = __shfl(r[j], k);
            r[k] = fmaf(-Lij, Lkj, r[k]);
          }
        }
        float x[16];
#pragma unroll
        for (int j = 0; j < 16; ++j) {
          float s = (i == j) ? 1.0f : 0.0f;
#pragma unroll
          for (int k = 0; k < j; ++k) {
            float Ljk = __shfl(r[k], j);
            s = fmaf(-Ljk, x[k], s);
          }
          float Ljj = __shfl(r[j], j);
          x[j] = s / Ljj;
        }
        if (tid < 16) {
#pragma unroll
          for (int j = 0; j < 16; ++j) Lb[diagbase + j * 17 + tid] = x[j];
        }
      }
      __syncthreads();

      const int nIb = 15 - p;
      const int tot = nIb * 256;
      float outv[8];
#pragma unroll
      for (int s = 0; s < 8; ++s) {
        int f = tid + s * 512;
        if (f < tot) {
          int Ib = f >> 8;
          int I = p + 1 + Ib;
          int e = f & 255;
          int i = e >> 4, j = e & 15;
          const float* Ablk = &Lb[(I * (I + 1) / 2 + p) * 272 + i * 17];
          const float* invD = &Lb[diagbase + j * 17];
          float s2 = 0.f;
#pragma unroll
          for (int k = 0; k < 16; ++k) s2 = fmaf(Ablk[k], invD[k], s2);
          outv[s] = s2;
        }
      }
      __syncthreads();
#pragma unroll
      for (int s = 0; s < 8; ++s) {
        int f = tid + s * 512;
        if (f < tot) {
          int Ib = f >> 8;
          int I = p + 1 + Ib;
          int e = f & 255;
          int i = e >> 4, j = e & 15;
          Lb[(I * (I + 1) / 2 + p) * 272 + i * 17 + j] = outv[s];
        }
      }
      __syncthreads();

      const int npairs = nIb * (nIb + 1) / 2;
      const int g = tid >> 4, t = tid & 15;
      const int tx = t & 3, ty = t >> 2;
      for (int pi0 = 0; pi0 < npairs; pi0 += 32) {
        int pi = pi0 + g;
        if (pi < npairs) {
          int a = 0; while ((a + 1) * (a + 2) / 2 <= pi) ++a;
          int b2 = pi - a * (a + 1) / 2;
          int I = p + 1 + a, J = p + 1 + b2;
          float* Cblk = &Lb[(I * (I + 1) / 2 + J) * 272];
          const float* Ablk = &Lb[(I * (I + 1) / 2 + p) * 272];
          const float* Bblk = &Lb[(J * (J + 1) / 2 + p) * 272];
          float c4[4][4];
#pragma unroll
          for (int ii = 0; ii < 4; ++ii)
#pragma unroll
            for (int jj = 0; jj < 4; ++jj)
              c4[ii][jj] = Cblk[(4 * ty + ii) * 17 + 4 * tx + jj];
#pragma unroll
          for (int kk = 0; kk < 16; ++kk) {
            float av[4], bv[4];
#pragma unroll
            for (int ii = 0; ii < 4; ++ii) av[ii] = Ablk[(4 * ty + ii) * 17 + kk];
#pragma unroll
            for (int jj = 0; jj < 4; ++jj) bv[jj] = Bblk[(4 * tx + jj) * 17 + kk];
#pragma unroll
            for (int ii = 0; ii < 4; ++ii)
#pragma unroll
              for (int jj = 0; jj < 4; ++jj)
                c4[ii][jj] = fmaf(-av[ii], bv[jj], c4[ii][jj]);
          }
#pragma unroll
          for (int ii = 0; ii < 4; ++ii)
#pragma unroll
            for (int jj = 0; jj < 4; ++jj)
              Cblk[(4 * ty + ii) * 17 + 4 * tx + jj] = c4[ii][jj];
        }
      }
      __syncthreads();
    }

    float* Lgb = Lg + (long)bh * 34816;
    for (int f = tid * 4; f < 136 * 256; f += 2048) {
      int bi = f >> 8, e = f & 255;
      int i = e >> 4, j = e & 15;
      float4 v;
      v.x = Lb[bi * 272 + i * 17 + j];
      v.y = Lb[bi * 272 + i * 17 + j + 1];
      v.z = Lb[bi * 272 + i * 17 + j + 2];
      v.w = Lb[bi * 272 + i * 17 + j + 3];
      *(float4*)&Lgb[f] = v;
    }
  } else if (bx < 64 + 1024) {
    // ================= RFF(q) -> phiq bf16 hi/lo, 128 rows/block ==========
    const int id = bx - 64;
    const int l0 = (id & 15) * 128;
    const int h = (id >> 4) & 15;
    const int b = id >> 8;
    float* w_lds = sm;                 // [64][132]
    float* x_lds = sm + 8448;          // [128][68]
    float* b_lds = sm + 8448 + 8704;   // [128]

    const float* wsrc = rffW + h * 8192;
    for (int f = tid * 4; f < 8192; f += 2048) {
      int d = f >> 7, m = f & 127;
      *(float4*)&w_lds[d * 132 + m] = *(const float4*)&wsrc[f];
    }
    if (tid < 128) b_lds[tid] = rffb[h * 128 + tid];
    {
      int r = tid >> 2, c0 = (tid & 3) * 16;
      const float* srow = qsrc + (long)(b * L_ + l0 + r) * 1024 + h * VD_ + c0;
      *(float4*)&x_lds[r * 68 + c0 + 0]  = *(const float4*)(srow + 0);
      *(float4*)&x_lds[r * 68 + c0 + 4]  = *(const float4*)(srow + 4);
      *(float4*)&x_lds[r * 68 + c0 + 8]  = *(const float4*)(srow + 8);
      *(float4*)&x_lds[r * 68 + c0 + 12] = *(const float4*)(srow + 12);
    }
    __syncthreads();

    const int sub = tid >> 8;          // 0..1, 64 rows each
    const int t = tid & 255;
    const int ty = t >> 4, tx = t & 15;
    const int rrow = sub * 64 + 4 * ty;
    float acc[4][8];
    {
      float4 bb0 = *(const float4*)&b_lds[4 * tx];
      float4 bb1 = *(const float4*)&b_lds[4 * tx + 64];
#pragma unroll
      for (int i = 0; i < 4; ++i) {
        acc[i][0] = bb0.x; acc[i][1] = bb0.y; acc[i][2] = bb0.z; acc[i][3] = bb0.w;
        acc[i][4] = bb1.x; acc[i][5] = bb1.y; acc[i][6] = bb1.z; acc[i][7] = bb1.w;
      }
    }
#pragma unroll 8
    for (int kk = 0; kk < 64; ++kk) {
      float4 w0 = *(const float4*)&w_lds[kk * 132 + 4 * tx];
      float4 w1 = *(const float4*)&w_lds[kk * 132 + 4 * tx + 64];
      float xv[4];
#pragma unroll
      for (int i = 0; i < 4; ++i) xv[i] = x_lds[(rrow + i) * 68 + kk];
#pragma unroll
      for (int i = 0; i < 4; ++i) {
        acc[i][0] = fmaf(xv[i], w0.x, acc[i][0]);
        acc[i][1] = fmaf(xv[i], w0.y, acc[i][1]);
        acc[i][2] = fmaf(xv[i], w0.z, acc[i][2]);
        acc[i][3] = fmaf(xv[i], w0.w, acc[i][3]);
        acc[i][4] = fmaf(xv[i], w1.x, acc[i][4]);
        acc[i][5] = fmaf(xv[i], w1.y, acc[i][5]);
        acc[i][6] = fmaf(xv[i], w1.z, acc[i][6]);
        acc[i][7] = fmaf(xv[i], w1.w, acc[i][7]);
      }
    }
#pragma unroll
    for (int i = 0; i < 4; ++i) {
      int l = l0 + rrow + i;
      float4 c0, c1, s0, s1;
      float sv, cv;
      sincosf(acc[i][0], &sv, &cv); c0.x = cv * SCALE_; s0.x = sv * SCALE_;
      sincosf(acc[i][1], &sv, &cv); c0.y = cv * SCALE_; s0.y = sv * SCALE_;
      sincosf(acc[i][2], &sv, &cv); c0.z = cv * SCALE_; s0.z = sv * SCALE_;
      sincosf(acc[i][3], &sv, &cv); c0.w = cv * SCALE_; s0.w = sv * SCALE_;
      sincosf(acc[i][4], &sv, &cv); c1.x = cv * SCALE_; s1.x = sv * SCALE_;
      sincosf(acc[i][5], &sv, &cv); c1.y = cv * SCALE_; s1.y = sv * SCALE_;
      sincosf(acc[i][6], &sv, &cv); c1.z = cv * SCALE_; s1.z = sv * SCALE_;
      sincosf(acc[i][7], &sv, &cv); c1.w = cv * SCALE_; s1.w = sv * SCALE_;
      long base = ((long)(b * H_ + h) * L_ + l) * M2_;
      ushort4 hv; float4 r4;
      split4(c0, &hv, &r4);
      *(ushort4*)&ph[base + 4 * tx] = hv;
      *(ushort4*)&pl[base + 4 * tx] = (ushort4){f2bf(r4.x), f2bf(r4.y), f2bf(r4.z), f2bf(r4.w)};
      split4(c1, &hv, &r4);
      *(ushort4*)&ph[base + 64 + 4 * tx] = hv;
      *(ushort4*)&pl[base + 64 + 4 * tx] = (ushort4){f2bf(r4.x), f2bf(r4.y), f2bf(r4.z), f2bf(r4.w)};
      split4(s0, &hv, &r4);
      *(ushort4*)&ph[base + 128 + 4 * tx] = hv;
      *(ushort4*)&pl[base + 128 + 4 * tx] = (ushort4){f2bf(r4.x), f2bf(r4.y), f2bf(r4.z), f2bf(r4.w)};
      split4(s1, &hv, &r4);
      *(ushort4*)&ph[base + 192 + 4 * tx] = hv;
      *(ushort4*)&pl[base + 192 + 4 * tx] = (ushort4){f2bf(r4.x), f2bf(r4.y), f2bf(r4.z), f2bf(r4.w)};
    }
  } else {
    // ================= Wo -> bf16 ==========================================
    const int id2 = bx - (64 + 1024);
    int idx = id2 * 512 + tid;
    for (int i = idx; i < 262144; i += 65536) {
      float4 f = ((const float4*)Wo)[i];
      ushort4 hv = {f2bf(f.x), f2bf(f.y), f2bf(f.z), f2bf(f.w)};
      ((ushort4*)wo_hi)[i] = hv;
    }
  }
}

// ---------------- blocked triangular solves ---------------------------------
__global__ __launch_bounds__(256) void tri_solve_kernel(
    const float* __restrict__ Lg, const float* __restrict__ T,
    float* __restrict__ Wt)
{
  __shared__ float Y[256 * 17];
  __shared__ float tmp[16 * 17];
  const int bh = blockIdx.y;
  const int d0 = blockIdx.x * 16;
  const int tid = threadIdx.x;
  const int i = tid >> 4, d = tid & 15;
  const float* Lb = Lg + (long)bh * 34816;
  const float* Tb = T + (long)bh * 16384;

  for (int r = i; r < 256; r += 16) Y[r * 17 + d] = Tb[r * 64 + d0 + d];
  __syncthreads();

  for (int J = 0; J < 16; ++J) {
    float acc = Y[(J * 16 + i) * 17 + d];
    for (int c = 0; c < J; ++c) {
      const float* Lblk = &Lb[(J * (J + 1) / 2 + c) * 256 + i * 16];
#pragma unroll
      for (int k = 0; k < 16; k += 4) {
        float4 l4 = *(const float4*)&Lblk[k];
        acc = fmaf(-l4.x, Y[(c * 16 + k + 0) * 17 + d], acc);
        acc = fmaf(-l4.y, Y[(c * 16 + k + 1) * 17 + d], acc);
        acc = fmaf(-l4.z, Y[(c * 16 + k + 2) * 17 + d], acc);
        acc = fmaf(-l4.w, Y[(c * 16 + k + 3) * 17 + d], acc);
      }
    }
    tmp[i * 17 + d] = acc;
    __syncthreads();
    const float* invD = &Lb[(J * (J + 1) / 2 + J) * 256 + i * 16];
    float y = 0.f;
#pragma unroll
    for (int k = 0; k < 16; ++k) y = fmaf(invD[k], tmp[k * 17 + d], y);
    Y[(J * 16 + i) * 17 + d] = y;
    __syncthreads();
  }

  for (int J = 15; J >= 0; --J) {
    float acc = Y[(J * 16 + i) * 17 + d];
    for (int I = J + 1; I < 16; ++I) {
      const float* Lblk = &Lb[(I * (I + 1) / 2 + J) * 256];
#pragma unroll
      for (int k = 0; k < 16; ++k)
        acc = fmaf(-Lblk[k * 16 + i], Y[(I * 16 + k) * 17 + d], acc);
    }
    tmp[i * 17 + d] = acc;
    __syncthreads();
    const float* invD = &Lb[(J * (J + 1) / 2 + J) * 256];
    float w = 0.f;
#pragma unroll
    for (int k = 0; k < 16; ++k) w = fmaf(invD[k * 16 + i], tmp[k * 17 + d], w);
    Y[(J * 16 + i) * 17 + d] = w;
    __syncthreads();
  }

  for (int f = tid; f < 16 * 256; f += 256) {
    int dc = f >> 8, m = f & 255;
    Wt[(long)bh * 16384 + (long)(d0 + dc) * 256 + m] = Y[m * 17 + dc];
  }
}

__global__ void ws_too_small_kernel(float* out) { out[0] = 12345.0f; }

extern "C" void kernel_launch(void* const* d_in, const int* in_sizes, int n_in,
                              void* d_out, int out_size, void* d_ws, size_t ws_size,
                              hipStream_t stream) {
  const float* x    = (const float*)d_in[0];
  const float* mask = (const float*)d_in[2];
  const float* Wq   = (const float*)d_in[3];
  const float* Wk   = (const float*)d_in[4];
  const float* Wv   = (const float*)d_in[5];
  const float* Wo   = (const float*)d_in[6];
  const float* bo   = (const float*)d_in[7];
  const float* rffW = (const float*)d_in[8];
  const float* rffb = (const float*)d_in[9];
  float* out = (float*)d_out;
  float* ws  = (float*)d_ws;

  const size_t needed = 58720256UL * 4UL;  // 234.9 MB
  if (ws_size < needed) {
    ws_too_small_kernel<<<1, 1, 0, stream>>>(out);
    return;
  }
  // region A [0, 8.4M): q fp32 -> oh bf16 after rff(q)
  float* q = ws;
  u16* oh_bf = (u16*)ws;
  // region B [8.4M, 16.7M): k fp32 -> T(1M)+G(4.2M)+Lg(2.2M)
  float* kbuf = ws + 8388608;
  float* T    = ws + 8388608;
  float* G    = ws + 9437184;
  float* Lg   = ws + 13631488;
  // region big [16.7M, 50.3M) as u16:
  u16* big16 = (u16*)(ws + 16777216);
  u16* x_hi = big16;
  u16* x_lo = big16 + 8388608;
  u16* w_hi = big16 + 16777216;
  u16* w_lo = big16 + 19922944;
  u16* pk_hi = big16;
  u16* pk_lo = big16 + 20971520;
  u16* phiq_hi = big16;
  u16* phiq_lo = big16 + 33554432;
  // region D [50.3M, 58.7M): v fp32 -> wt_f/wt_hi/lo/wo_hi
  float* v = ws + 50331648;
  float* wt_f = ws + 50331648;
  u16* wt_hi = (u16*)(ws + 51380224);
  u16* wt_lo = wt_hi + 1048576;
  u16* wo_hi = wt_hi + 2097152;

  hipFuncSetAttribute((const void*)chol_rffq_wo_kernel,
                      hipFuncAttributeMaxDynamicSharedMemorySize, 147968);

  dim3 blk(256);

  // 1-2: convert x and fused W to bf16 hi/lo
  cvt_split_kernel<<<8192, blk, 0, stream>>>(x, x_hi, x_lo, 2097152);
  cvt_split_kernel<<<1024, blk, 0, stream>>>(Wq, w_hi,           w_lo,           262144);
  cvt_split_kernel<<<1024, blk, 0, stream>>>(Wk, w_hi + 1048576, w_lo + 1048576, 262144);
  cvt_split_kernel<<<1024, blk, 0, stream>>>(Wv, w_hi + 2097152, w_lo + 2097152, 262144);

  // 3: QKV fused bf16x3 (v columns: hi*hi only)
  mfma_nt3<<<dim3(24, 64), blk, 0, stream>>>(x_hi, x_lo, w_hi, w_lo, q, kbuf, v);

  // 4-9: two bh-halves: rff(k)->pkT, vT->pkT, [G|T] MFMA
  for (int half = 0; half < 2; ++half) {
    int b0 = half * 2, bh0 = half * 32;
    rff_k_t<<<dim3(32, 16, 2), blk, 0, stream>>>(kbuf, mask, rffW, rffb, pk_hi, pk_lo, b0);
    vt_kernel<<<dim3(16, 32), blk, 0, stream>>>(v, mask, pk_hi, pk_lo, b0);
    mfma_gt<<<dim3(5, 2, 32), blk, 0, stream>>>(pk_hi, pk_lo, G, T, bh0);
  }

  // 10: fused chol (serial pole) + rff(q)->phiq + Wo cvt (fills idle CUs)
  chol_rffq_wo_kernel<<<dim3(64 + 1024 + 128), dim3(512), 147968, stream>>>(
      G, Lg, q, rffW, rffb, phiq_hi, phiq_lo, Wo, wo_hi);

  // 11-12: tri solves + Wt split
  tri_solve_kernel<<<dim3(4, 64), dim3(256), 0, stream>>>(Lg, T, wt_f);
  cvt_split_kernel<<<1024, blk, 0, stream>>>(wt_f, wt_hi, wt_lo, 262144);

  // 13: out-heads MFMA (bf16 output)
  mfma_out_k<<<dim3(16, 64), blk, 0, stream>>>(phiq_hi, phiq_lo, wt_hi, wt_lo, oh_bf);

  // 14: Wo projection (bf16 MFMA) with bias+mask epilogue
  mfma_nt<<<dim3(8, 64), blk, 0, stream>>>(oh_bf, wo_hi, out, 1024, 1024, 1024, 1024, bo, mask);
}

// Round 8
// 958.550 us; speedup vs baseline: 4.9968x; 1.0114x over previous
//
#include <hip/hip_runtime.h>
#include <math.h>

#define B_ 4
#define L_ 2048
#define HD_ 1024
#define H_ 16
#define VD_ 64
#define M_ 128
#define M2_ 256
#define RIDGE_ 0.01f
#define SCALE_ 0.08838834764831845f   // 1/sqrt(128)

typedef unsigned short u16;
typedef __attribute__((ext_vector_type(8))) short short8;
typedef __attribute__((ext_vector_type(4))) float floatx4;

__device__ __forceinline__ u16 f2bf(float x) {
  unsigned u = __float_as_uint(x);
  unsigned r = u + 0x7fff + ((u >> 16) & 1);
  return (u16)(r >> 16);
}
__device__ __forceinline__ float bf2f(u16 h) {
  return __uint_as_float(((unsigned)h) << 16);
}
__device__ __forceinline__ void gload_lds16(const u16* g, u16* l) {
  __builtin_amdgcn_global_load_lds(
      (const __attribute__((address_space(1))) unsigned int*)g,
      (__attribute__((address_space(3))) unsigned int*)l, 16, 0, 0);
}
__device__ __forceinline__ void split4(float4 f, ushort4* h, float4* r) {
  h->x = f2bf(f.x); h->y = f2bf(f.y); h->z = f2bf(f.z); h->w = f2bf(f.w);
  r->x = f.x - bf2f(h->x); r->y = f.y - bf2f(h->y);
  r->z = f.z - bf2f(h->z); r->w = f.w - bf2f(h->w);
}

// ---------------- fp32 -> bf16 hi/lo split ---------------------------------
__global__ __launch_bounds__(256) void cvt_split_kernel(
    const float* __restrict__ src, u16* __restrict__ hi, u16* __restrict__ lo, int n4)
{
  int i = blockIdx.x * 256 + threadIdx.x;
  if (i < n4) {
    float4 f = ((const float4*)src)[i];
    ushort4 hv; float4 r;
    split4(f, &hv, &r);
    ushort4 lv = {f2bf(r.x), f2bf(r.y), f2bf(r.z), f2bf(r.w)};
    ((ushort4*)hi)[i] = hv;
    ((ushort4*)lo)[i] = lv;
  }
}

// ---------------- bf16 MFMA GEMM (single-pass), C = A * B^T ----------------
__global__ __launch_bounds__(256) void mfma_nt(
    const u16* __restrict__ A0, const u16* __restrict__ B0,
    float* __restrict__ C, int Ndim, int Kdim, int ldA, int ldB,
    const float* __restrict__ bias, const float* __restrict__ mask)
{
  __shared__ __align__(16) u16 a_sm[4096];
  __shared__ __align__(16) u16 b_sm[4096];
  const int tid = threadIdx.x;
  const int wave = tid >> 6, lane = tid & 63;
  const int m0 = blockIdx.y * 128, n0 = blockIdx.x * 128;
  const int wrow = (wave >> 1) * 64, wcol = (wave & 1) * 64;
  const int fm = lane & 15, q = lane >> 4;

  floatx4 acc[4][4];
#pragma unroll
  for (int i = 0; i < 4; ++i)
#pragma unroll
    for (int j = 0; j < 4; ++j) acc[i][j] = (floatx4){0.f, 0.f, 0.f, 0.f};

  const u16* Ag0 = A0 + (long)(m0 + lane) * ldA + wave * 8;
  const u16* Ag1 = A0 + (long)(m0 + 64 + lane) * ldA + wave * 8;
  const u16* Bg0 = B0 + (long)(n0 + lane) * ldB + wave * 8;
  const u16* Bg1 = B0 + (long)(n0 + 64 + lane) * ldB + wave * 8;
  u16* la0 = &a_sm[(wave * 128 + 0) * 8];
  u16* la1 = &a_sm[(wave * 128 + 64) * 8];
  u16* lb0 = &b_sm[(wave * 128 + 0) * 8];
  u16* lb1 = &b_sm[(wave * 128 + 64) * 8];

  for (int k0 = 0; k0 < Kdim; k0 += 32) {
    __syncthreads();
    gload_lds16(Ag0 + k0, la0);
    gload_lds16(Ag1 + k0, la1);
    gload_lds16(Bg0 + k0, lb0);
    gload_lds16(Bg1 + k0, lb1);
    __syncthreads();
    short8 af[4], bf[4];
#pragma unroll
    for (int i = 0; i < 4; ++i)
      af[i] = *(const short8*)&a_sm[(q * 128 + wrow + i * 16 + fm) * 8];
#pragma unroll
    for (int j = 0; j < 4; ++j)
      bf[j] = *(const short8*)&b_sm[(q * 128 + wcol + j * 16 + fm) * 8];
#pragma unroll
    for (int i = 0; i < 4; ++i)
#pragma unroll
      for (int j = 0; j < 4; ++j)
        acc[i][j] = __builtin_amdgcn_mfma_f32_16x16x32_bf16(af[i], bf[j], acc[i][j], 0, 0, 0);
  }

  const int colb = n0 + wcol + fm;
  const int rbase = m0 + wrow + (lane >> 4) * 4;
#pragma unroll
  for (int j = 0; j < 4; ++j) {
    int cg = colb + j * 16;
    float bb = bias ? bias[cg] : 0.f;
#pragma unroll
    for (int i = 0; i < 4; ++i) {
#pragma unroll
      for (int r = 0; r < 4; ++r) {
        int row = rbase + i * 16 + r;
        float val = acc[i][j][r];
        if (bias) val = (val + bb) * mask[row];
        C[(long)row * Ndim + cg] = val;
      }
    }
  }
}

// ---------------- uniform bf16x3 MFMA GEMM (q,k columns only) ---------------
__global__ __launch_bounds__(256) void mfma_qk3(
    const u16* __restrict__ Ah, const u16* __restrict__ Al,
    const u16* __restrict__ Bh, const u16* __restrict__ Bl,
    float* __restrict__ Cq, float* __restrict__ Ck)
{
  __shared__ __align__(16) u16 ah_sm[4096], al_sm[4096];
  __shared__ __align__(16) u16 bh_sm[4096], bl_sm[4096];
  const int tid = threadIdx.x;
  const int wave = tid >> 6, lane = tid & 63;
  const int m0 = blockIdx.y * 128, n0 = blockIdx.x * 128;
  const int wrow = (wave >> 1) * 64, wcol = (wave & 1) * 64;
  const int fm = lane & 15, q = lane >> 4;

  floatx4 acc[4][4];
#pragma unroll
  for (int i = 0; i < 4; ++i)
#pragma unroll
    for (int j = 0; j < 4; ++j) acc[i][j] = (floatx4){0.f, 0.f, 0.f, 0.f};

  const long a0o = (long)(m0 + lane) * 1024 + wave * 8;
  const long a1o = (long)(m0 + 64 + lane) * 1024 + wave * 8;
  const long b0o = (long)(n0 + lane) * 1024 + wave * 8;
  const long b1o = (long)(n0 + 64 + lane) * 1024 + wave * 8;
  u16* lah0 = &ah_sm[(wave * 128 + 0) * 8];
  u16* lah1 = &ah_sm[(wave * 128 + 64) * 8];
  u16* lal0 = &al_sm[(wave * 128 + 0) * 8];
  u16* lal1 = &al_sm[(wave * 128 + 64) * 8];
  u16* lbh0 = &bh_sm[(wave * 128 + 0) * 8];
  u16* lbh1 = &bh_sm[(wave * 128 + 64) * 8];
  u16* lbl0 = &bl_sm[(wave * 128 + 0) * 8];
  u16* lbl1 = &bl_sm[(wave * 128 + 64) * 8];

  for (int k0 = 0; k0 < 1024; k0 += 32) {
    __syncthreads();
    gload_lds16(Ah + a0o + k0, lah0);
    gload_lds16(Ah + a1o + k0, lah1);
    gload_lds16(Al + a0o + k0, lal0);
    gload_lds16(Al + a1o + k0, lal1);
    gload_lds16(Bh + b0o + k0, lbh0);
    gload_lds16(Bh + b1o + k0, lbh1);
    gload_lds16(Bl + b0o + k0, lbl0);
    gload_lds16(Bl + b1o + k0, lbl1);
    __syncthreads();
    short8 afh[4], afl[4], bfh[4], bfl[4];
#pragma unroll
    for (int i = 0; i < 4; ++i) {
      afh[i] = *(const short8*)&ah_sm[(q * 128 + wrow + i * 16 + fm) * 8];
      afl[i] = *(const short8*)&al_sm[(q * 128 + wrow + i * 16 + fm) * 8];
    }
#pragma unroll
    for (int j = 0; j < 4; ++j) {
      bfh[j] = *(const short8*)&bh_sm[(q * 128 + wcol + j * 16 + fm) * 8];
      bfl[j] = *(const short8*)&bl_sm[(q * 128 + wcol + j * 16 + fm) * 8];
    }
#pragma unroll
    for (int i = 0; i < 4; ++i)
#pragma unroll
      for (int j = 0; j < 4; ++j) {
        acc[i][j] = __builtin_amdgcn_mfma_f32_16x16x32_bf16(afh[i], bfh[j], acc[i][j], 0, 0, 0);
        acc[i][j] = __builtin_amdgcn_mfma_f32_16x16x32_bf16(afl[i], bfh[j], acc[i][j], 0, 0, 0);
        acc[i][j] = __builtin_amdgcn_mfma_f32_16x16x32_bf16(afh[i], bfl[j], acc[i][j], 0, 0, 0);
      }
  }

  float* Cp; int cb;
  if (n0 < 1024) { Cp = Cq; cb = n0; }
  else           { Cp = Ck; cb = n0 - 1024; }
  const int colb = cb + wcol + fm;
  const int rbase = m0 + wrow + (lane >> 4) * 4;
#pragma unroll
  for (int j = 0; j < 4; ++j) {
    int cg = colb + j * 16;
#pragma unroll
    for (int i = 0; i < 4; ++i)
#pragma unroll
      for (int r = 0; r < 4; ++r)
        Cp[(long)(rbase + i * 16 + r) * 1024 + cg] = acc[i][j][r];
  }
}

// ---------------- RFF(k): transposed bf16 hi/lo into pkT --------------------
__global__ __launch_bounds__(256) void rff_k_t(
    const float* __restrict__ src, const float* __restrict__ mask,
    const float* __restrict__ rffW, const float* __restrict__ rffb,
    u16* __restrict__ pkh, u16* __restrict__ pkl, int b0)
{
  __shared__ __align__(16) float w_lds[64][132];
  __shared__ __align__(16) float x_lds[64][68];
  __shared__ float b_lds[128];
  const int l0 = blockIdx.x * 64;
  const int h = blockIdx.y, b = b0 + blockIdx.z;
  const int zloc = blockIdx.z * 16 + h;
  const int tid = threadIdx.x;

  const float* wsrc = rffW + h * 8192;
  for (int f = tid * 4; f < 8192; f += 1024) {
    int d = f >> 7, m = f & 127;
    *(float4*)&w_lds[d][m] = *(const float4*)&wsrc[f];
  }
  if (tid < 128) b_lds[tid] = rffb[h * 128 + tid];
  {
    int r = tid >> 2, c0 = (tid & 3) * 16;
    const float* srow = src + (long)(b * L_ + l0 + r) * 1024 + h * VD_ + c0;
    *(float4*)&x_lds[r][c0 + 0]  = *(const float4*)(srow + 0);
    *(float4*)&x_lds[r][c0 + 4]  = *(const float4*)(srow + 4);
    *(float4*)&x_lds[r][c0 + 8]  = *(const float4*)(srow + 8);
    *(float4*)&x_lds[r][c0 + 12] = *(const float4*)(srow + 12);
  }
  __syncthreads();

  const int ty = tid >> 4, tx = tid & 15;
  float acc[4][8];
  {
    float4 bb0 = *(const float4*)&b_lds[4 * tx];
    float4 bb1 = *(const float4*)&b_lds[4 * tx + 64];
#pragma unroll
    for (int i = 0; i < 4; ++i) {
      acc[i][0] = bb0.x; acc[i][1] = bb0.y; acc[i][2] = bb0.z; acc[i][3] = bb0.w;
      acc[i][4] = bb1.x; acc[i][5] = bb1.y; acc[i][6] = bb1.z; acc[i][7] = bb1.w;
    }
  }
#pragma unroll 8
  for (int kk = 0; kk < 64; ++kk) {
    float4 w0 = *(const float4*)&w_lds[kk][4 * tx];
    float4 w1 = *(const float4*)&w_lds[kk][4 * tx + 64];
    float xv[4];
#pragma unroll
    for (int i = 0; i < 4; ++i) xv[i] = x_lds[4 * ty + i][kk];
#pragma unroll
    for (int i = 0; i < 4; ++i) {
      acc[i][0] = fmaf(xv[i], w0.x, acc[i][0]);
      acc[i][1] = fmaf(xv[i], w0.y, acc[i][1]);
      acc[i][2] = fmaf(xv[i], w0.z, acc[i][2]);
      acc[i][3] = fmaf(xv[i], w0.w, acc[i][3]);
      acc[i][4] = fmaf(xv[i], w1.x, acc[i][4]);
      acc[i][5] = fmaf(xv[i], w1.y, acc[i][5]);
      acc[i][6] = fmaf(xv[i], w1.z, acc[i][6]);
      acc[i][7] = fmaf(xv[i], w1.w, acc[i][7]);
    }
  }
  float fi[4];
#pragma unroll
  for (int i = 0; i < 4; ++i) fi[i] = SCALE_ * mask[b * L_ + l0 + 4 * ty + i];
  float cvv[4][8], svv[4][8];
#pragma unroll
  for (int i = 0; i < 4; ++i)
#pragma unroll
    for (int jj = 0; jj < 8; ++jj) {
      float sv, cv;
      sincosf(acc[i][jj], &sv, &cv);
      cvv[i][jj] = cv * fi[i];
      svv[i][jj] = sv * fi[i];
    }
  const long lbase = l0 + 4 * ty;
  const long zbase = (long)zloc * 655360;
#pragma unroll
  for (int jj = 0; jj < 8; ++jj) {
    int mcol = (jj < 4) ? (4 * tx + jj) : (64 + 4 * tx + (jj - 4));
    ushort4 h4, l4;
    h4.x = f2bf(cvv[0][jj]); l4.x = f2bf(cvv[0][jj] - bf2f(h4.x));
    h4.y = f2bf(cvv[1][jj]); l4.y = f2bf(cvv[1][jj] - bf2f(h4.y));
    h4.z = f2bf(cvv[2][jj]); l4.z = f2bf(cvv[2][jj] - bf2f(h4.z));
    h4.w = f2bf(cvv[3][jj]); l4.w = f2bf(cvv[3][jj] - bf2f(h4.w));
    long base = zbase + (long)mcol * 2048 + lbase;
    *(ushort4*)&pkh[base] = h4;
    *(ushort4*)&pkl[base] = l4;
    ushort4 hs, ls;
    hs.x = f2bf(svv[0][jj]); ls.x = f2bf(svv[0][jj] - bf2f(hs.x));
    hs.y = f2bf(svv[1][jj]); ls.y = f2bf(svv[1][jj] - bf2f(hs.y));
    hs.z = f2bf(svv[2][jj]); ls.z = f2bf(svv[2][jj] - bf2f(hs.z));
    hs.w = f2bf(svv[3][jj]); ls.w = f2bf(svv[3][jj] - bf2f(hs.w));
    long base2 = zbase + (long)(mcol + 128) * 2048 + lbase;
    *(ushort4*)&pkh[base2] = hs;
    *(ushort4*)&pkl[base2] = ls;
  }
}

// ---------------- masked V transpose into pkT rows 256..319 -----------------
__global__ __launch_bounds__(256) void vt_kernel(
    const float* __restrict__ v, const float* __restrict__ mask,
    u16* __restrict__ pkh, u16* __restrict__ pkl, int b0)
{
  __shared__ float t[128][65];
  const int z = blockIdx.y;
  const int b = b0 + (z >> 4), h = z & 15;
  const int l0 = blockIdx.x * 128;
  const int tid = threadIdx.x;
  const int d = tid & 63, lg = tid >> 6;
  for (int i = 0; i < 128; i += 4) {
    int ll = i + lg;
    float mv = mask[b * L_ + l0 + ll];
    t[ll][d] = v[(long)(b * L_ + l0 + ll) * 1024 + h * 64 + d] * mv;
  }
  __syncthreads();
  const int d2 = tid >> 2, lofs = (tid & 3) * 32;
  long base = (long)z * 655360 + (long)(256 + d2) * 2048 + l0 + lofs;
  for (int j = 0; j < 32; j += 4) {
    float f0 = t[lofs + j + 0][d2], f1 = t[lofs + j + 1][d2];
    float f2 = t[lofs + j + 2][d2], f3 = t[lofs + j + 3][d2];
    ushort4 hv, lv;
    hv.x = f2bf(f0); lv.x = f2bf(f0 - bf2f(hv.x));
    hv.y = f2bf(f1); lv.y = f2bf(f1 - bf2f(hv.y));
    hv.z = f2bf(f2); lv.z = f2bf(f2 - bf2f(hv.z));
    hv.w = f2bf(f3); lv.w = f2bf(f3 - bf2f(hv.w));
    *(ushort4*)&pkh[base + j] = hv;
    *(ushort4*)&pkl[base + j] = lv;
  }
}

// ---------------- batched bf16x3 MFMA: [G|T] partials, K-split x2 -----------
// grid (5, 4, 32): x = n-tile (64), y = (kc<<1)|mt, z = local bh.
__global__ __launch_bounds__(256) void mfma_gt(
    const u16* __restrict__ pkh, const u16* __restrict__ pkl,
    float* __restrict__ Gp, float* __restrict__ Tp, int bh0)
{
  __shared__ __align__(16) u16 ah_sm[4096], al_sm[4096];
  __shared__ __align__(16) u16 bh_sm[2048], bl_sm[2048];
  const int tid = threadIdx.x;
  const int wave = tid >> 6, lane = tid & 63;
  const int z = blockIdx.z;
  const int mt = blockIdx.y & 1, kc = blockIdx.y >> 1;
  const int m0 = mt * 128, n0 = blockIdx.x * 64;
  const int wrow = (wave >> 1) * 64, wcol = (wave & 1) * 32;
  const int fm = lane & 15, q = lane >> 4;
  const long batch = (long)z * 655360;
  const u16* Ah = pkh + batch;
  const u16* Al = pkl + batch;

  floatx4 acc[4][2];
#pragma unroll
  for (int i = 0; i < 4; ++i)
#pragma unroll
    for (int j = 0; j < 2; ++j) acc[i][j] = (floatx4){0.f, 0.f, 0.f, 0.f};

  const long a0o = (long)(m0 + lane) * 2048 + wave * 8;
  const long a1o = (long)(m0 + 64 + lane) * 2048 + wave * 8;
  const long b0o = (long)(n0 + lane) * 2048 + wave * 8;
  u16* lah0 = &ah_sm[(wave * 128 + 0) * 8];
  u16* lah1 = &ah_sm[(wave * 128 + 64) * 8];
  u16* lal0 = &al_sm[(wave * 128 + 0) * 8];
  u16* lal1 = &al_sm[(wave * 128 + 64) * 8];
  u16* lbh = &bh_sm[(wave * 64) * 8];
  u16* lbl = &bl_sm[(wave * 64) * 8];

  const int kbeg = kc * 1024, kend = kbeg + 1024;
  for (int k0 = kbeg; k0 < kend; k0 += 32) {
    __syncthreads();
    gload_lds16(Ah + a0o + k0, lah0);
    gload_lds16(Ah + a1o + k0, lah1);
    gload_lds16(Al + a0o + k0, lal0);
    gload_lds16(Al + a1o + k0, lal1);
    gload_lds16(Ah + b0o + k0, lbh);
    gload_lds16(Al + b0o + k0, lbl);
    __syncthreads();
    short8 afh[4], afl[4], bfh[2], bfl[2];
#pragma unroll
    for (int i = 0; i < 4; ++i) {
      afh[i] = *(const short8*)&ah_sm[(q * 128 + wrow + i * 16 + fm) * 8];
      afl[i] = *(const short8*)&al_sm[(q * 128 + wrow + i * 16 + fm) * 8];
    }
#pragma unroll
    for (int j = 0; j < 2; ++j) {
      bfh[j] = *(const short8*)&bh_sm[(q * 64 + wcol + j * 16 + fm) * 8];
      bfl[j] = *(const short8*)&bl_sm[(q * 64 + wcol + j * 16 + fm) * 8];
    }
#pragma unroll
    for (int i = 0; i < 4; ++i)
#pragma unroll
      for (int j = 0; j < 2; ++j) {
        acc[i][j] = __builtin_amdgcn_mfma_f32_16x16x32_bf16(afh[i], bfh[j], acc[i][j], 0, 0, 0);
        acc[i][j] = __builtin_amdgcn_mfma_f32_16x16x32_bf16(afl[i], bfh[j], acc[i][j], 0, 0, 0);
        acc[i][j] = __builtin_amdgcn_mfma_f32_16x16x32_bf16(afh[i], bfl[j], acc[i][j], 0, 0, 0);
      }
  }

  const int bh = bh0 + z;
  float* Gb = Gp + (long)kc * 4194304;
  float* Tb = Tp + (long)kc * 1048576;
  const int rbase = m0 + wrow + (lane >> 4) * 4;
#pragma unroll
  for (int j = 0; j < 2; ++j) {
    int col = n0 + wcol + j * 16 + fm;
#pragma unroll
    for (int i = 0; i < 4; ++i)
#pragma unroll
      for (int r = 0; r < 4; ++r) {
        int row = rbase + i * 16 + r;
        float val = acc[i][j][r];
        if (n0 < 256) Gb[(long)bh * 65536 + (long)row * 256 + col] = val;
        else Tb[(long)bh * 16384 + (long)row * 64 + (col - 256)] = val;
      }
  }
}

// ---------------- reduce K-split partials into final G, T -------------------
__global__ __launch_bounds__(256) void reduce_gt_kernel(
    const float* __restrict__ Gp, float* __restrict__ G,
    const float* __restrict__ Tp, float* __restrict__ T)
{
  long i = (long)blockIdx.x * 256 + threadIdx.x;  // float4 index
  if (i < 1048576) {
    float4 a = ((const float4*)Gp)[i];
    float4 b = ((const float4*)(Gp + 4194304))[i];
    float4 o = {a.x + b.x, a.y + b.y, a.z + b.z, a.w + b.w};
    ((float4*)G)[i] = o;
  } else {
    long j = i - 1048576;
    float4 a = ((const float4*)Tp)[j];
    float4 b = ((const float4*)(Tp + 1048576))[j];
    float4 o = {a.x + b.x, a.y + b.y, a.z + b.z, a.w + b.w};
    ((float4*)T)[j] = o;
  }
}

// ---------------- batched bf16x3 MFMA: oh = PhiQ @ Wt^T (bf16 out) ----------
__global__ __launch_bounds__(256) void mfma_out_k(
    const u16* __restrict__ ph, const u16* __restrict__ pl,
    const u16* __restrict__ wth, const u16* __restrict__ wtl,
    u16* __restrict__ oh)
{
  __shared__ __align__(16) u16 ah_sm[4096], al_sm[4096];
  __shared__ __align__(16) u16 bh_sm[2048], bl_sm[2048];
  const int tid = threadIdx.x;
  const int wave = tid >> 6, lane = tid & 63;
  const int bh = blockIdx.y;
  const int b = bh >> 4, h = bh & 15;
  const int l0 = blockIdx.x * 128;
  const int wrow = (wave >> 1) * 64, wcol = (wave & 1) * 32;
  const int fm = lane & 15, q = lane >> 4;
  const u16* Ah = ph + (long)bh * 524288 + (long)l0 * 256;
  const u16* Al = pl + (long)bh * 524288 + (long)l0 * 256;
  const u16* Bh = wth + (long)bh * 16384;
  const u16* Bl = wtl + (long)bh * 16384;

  floatx4 acc[4][2];
#pragma unroll
  for (int i = 0; i < 4; ++i)
#pragma unroll
    for (int j = 0; j < 2; ++j) acc[i][j] = (floatx4){0.f, 0.f, 0.f, 0.f};

  const long a0o = (long)lane * 256 + wave * 8;
  const long a1o = (long)(64 + lane) * 256 + wave * 8;
  const long b0o = (long)lane * 256 + wave * 8;
  u16* lah0 = &ah_sm[(wave * 128 + 0) * 8];
  u16* lah1 = &ah_sm[(wave * 128 + 64) * 8];
  u16* lal0 = &al_sm[(wave * 128 + 0) * 8];
  u16* lal1 = &al_sm[(wave * 128 + 64) * 8];
  u16* lbh = &bh_sm[(wave * 64) * 8];
  u16* lbl = &bl_sm[(wave * 64) * 8];

  for (int k0 = 0; k0 < 256; k0 += 32) {
    __syncthreads();
    gload_lds16(Ah + a0o + k0, lah0);
    gload_lds16(Ah + a1o + k0, lah1);
    gload_lds16(Al + a0o + k0, lal0);
    gload_lds16(Al + a1o + k0, lal1);
    gload_lds16(Bh + b0o + k0, lbh);
    gload_lds16(Bl + b0o + k0, lbl);
    __syncthreads();
    short8 afh[4], afl[4], bfh[2], bfl[2];
#pragma unroll
    for (int i = 0; i < 4; ++i) {
      afh[i] = *(const short8*)&ah_sm[(q * 128 + wrow + i * 16 + fm) * 8];
      afl[i] = *(const short8*)&al_sm[(q * 128 + wrow + i * 16 + fm) * 8];
    }
#pragma unroll
    for (int j = 0; j < 2; ++j) {
      bfh[j] = *(const short8*)&bh_sm[(q * 64 + wcol + j * 16 + fm) * 8];
      bfl[j] = *(const short8*)&bl_sm[(q * 64 + wcol + j * 16 + fm) * 8];
    }
#pragma unroll
    for (int i = 0; i < 4; ++i)
#pragma unroll
      for (int j = 0; j < 2; ++j) {
        acc[i][j] = __builtin_amdgcn_mfma_f32_16x16x32_bf16(afh[i], bfh[j], acc[i][j], 0, 0, 0);
        acc[i][j] = __builtin_amdgcn_mfma_f32_16x16x32_bf16(afl[i], bfh[j], acc[i][j], 0, 0, 0);
        acc[i][j] = __builtin_amdgcn_mfma_f32_16x16x32_bf16(afh[i], bfl[j], acc[i][j], 0, 0, 0);
      }
  }

  const int rbase = l0 + wrow + (lane >> 4) * 4;
#pragma unroll
  for (int j = 0; j < 2; ++j) {
    int col = h * 64 + wcol + j * 16 + fm;
#pragma unroll
    for (int i = 0; i < 4; ++i)
#pragma unroll
      for (int r = 0; r < 4; ++r)
        oh[(long)(b * L_ + rbase + i * 16 + r) * 1024 + col] = f2bf(acc[i][j][r]);
  }
}

// ---------------- fused: chol (blocks 0-63) + rff(q) (64-1087) + Wo cvt -----
__global__ __launch_bounds__(512) void chol_rffq_wo_kernel(
    const float* __restrict__ G, float* __restrict__ Lg,
    const float* __restrict__ qsrc,
    const float* __restrict__ rffW, const float* __restrict__ rffb,
    u16* __restrict__ ph, u16* __restrict__ pl,
    const float* __restrict__ Wo, u16* __restrict__ wo_hi)
{
  extern __shared__ float sm[];
  const int bx = blockIdx.x;
  const int tid = threadIdx.x;

  if (bx < 64) {
    float* Lb = sm;  // 136*272 floats
    const int bh = bx;
    const float* Gb = G + (long)bh * 65536;
    for (int f = tid; f < 136 * 256; f += 512) {
      int bi = f >> 8, e = f & 255;
      int i = e >> 4, j = e & 15;
      int I = 0; while ((I + 1) * (I + 2) / 2 <= bi) ++I;
      int J = bi - I * (I + 1) / 2;
      float v = Gb[(I * 16 + i) * 256 + J * 16 + j];
      if (I == J && i == j) v += RIDGE_;
      Lb[bi * 272 + i * 17 + j] = v;
    }
    __syncthreads();

    for (int p = 0; p < 16; ++p) {
      const int diagbase = (p * (p + 1) / 2 + p) * 272;
      if (tid < 64) {
        const int i = tid & 15;
        float r[16];
#pragma unroll
        for (int k = 0; k < 16; ++k) r[k] = Lb[diagbase + i * 17 + k];
#pragma unroll
        for (int j = 0; j < 16; ++j) {
          float dj = __shfl(r[j], j);
          float dinv = 1.0f / sqrtf(dj);
          r[j] *= dinv;
          float Lij = r[j];
#pragma unroll
          for (int k = j + 1; k < 16; ++k) {
            float Lkj = __shfl(r[j], k);
            r[k] = fmaf(-Lij, Lkj, r[k]);
          }
        }
        float x[16];
#pragma unroll
        for (int j = 0; j < 16; ++j) {
          float s = (i == j) ? 1.0f : 0.0f;
#pragma unroll
          for (int k = 0; k < j; ++k) {
            float Ljk = __shfl(r[k], j);
            s = fmaf(-Ljk, x[k], s);
          }
          float Ljj = __shfl(r[j], j);
          x[j] = s / Ljj;
        }
        if (tid < 16) {
#pragma unroll
          for (int j = 0; j < 16; ++j) Lb[diagbase + j * 17 + tid] = x[j];
        }
      }
      __syncthreads();

      const int nIb = 15 - p;
      const int tot = nIb * 256;
      float outv[8];
#pragma unroll
      for (int s = 0; s < 8; ++s) {
        int f = tid + s * 512;
        if (f < tot) {
          int Ib = f >> 8;
          int I = p + 1 + Ib;
          int e = f & 255;
          int i = e >> 4, j = e & 15;
          const float* Ablk = &Lb[(I * (I + 1) / 2 + p) * 272 + i * 17];
          const float* invD = &Lb[diagbase + j * 17];
          float s2 = 0.f;
#pragma unroll
          for (int k = 0; k < 16; ++k) s2 = fmaf(Ablk[k], invD[k], s2);
          outv[s] = s2;
        }
      }
      __syncthreads();
#pragma unroll
      for (int s = 0; s < 8; ++s) {
        int f = tid + s * 512;
        if (f < tot) {
          int Ib = f >> 8;
          int I = p + 1 + Ib;
          int e = f & 255;
          int i = e >> 4, j = e & 15;
          Lb[(I * (I + 1) / 2 + p) * 272 + i * 17 + j] = outv[s];
        }
      }
      __syncthreads();

      const int npairs = nIb * (nIb + 1) / 2;
      const int g = tid >> 4, t = tid & 15;
      const int tx = t & 3, ty = t >> 2;
      for (int pi0 = 0; pi0 < npairs; pi0 += 32) {
        int pi = pi0 + g;
        if (pi < npairs) {
          int a = 0; while ((a + 1) * (a + 2) / 2 <= pi) ++a;
          int b2 = pi - a * (a + 1) / 2;
          int I = p + 1 + a, J = p + 1 + b2;
          float* Cblk = &Lb[(I * (I + 1) / 2 + J) * 272];
          const float* Ablk = &Lb[(I * (I + 1) / 2 + p) * 272];
          const float* Bblk = &Lb[(J * (J + 1) / 2 + p) * 272];
          float c4[4][4];
#pragma unroll
          for (int ii = 0; ii < 4; ++ii)
#pragma unroll
            for (int jj = 0; jj < 4; ++jj)
              c4[ii][jj] = Cblk[(4 * ty + ii) * 17 + 4 * tx + jj];
#pragma unroll
          for (int kk = 0; kk < 16; ++kk) {
            float av[4], bv[4];
#pragma unroll
            for (int ii = 0; ii < 4; ++ii) av[ii] = Ablk[(4 * ty + ii) * 17 + kk];
#pragma unroll
            for (int jj = 0; jj < 4; ++jj) bv[jj] = Bblk[(4 * tx + jj) * 17 + kk];
#pragma unroll
            for (int ii = 0; ii < 4; ++ii)
#pragma unroll
              for (int jj = 0; jj < 4; ++jj)
                c4[ii][jj] = fmaf(-av[ii], bv[jj], c4[ii][jj]);
          }
#pragma unroll
          for (int ii = 0; ii < 4; ++ii)
#pragma unroll
            for (int jj = 0; jj < 4; ++jj)
              Cblk[(4 * ty + ii) * 17 + 4 * tx + jj] = c4[ii][jj];
        }
      }
      __syncthreads();
    }

    float* Lgb = Lg + (long)bh * 34816;
    for (int f = tid * 4; f < 136 * 256; f += 2048) {
      int bi = f >> 8, e = f & 255;
      int i = e >> 4, j = e & 15;
      float4 v;
      v.x = Lb[bi * 272 + i * 17 + j];
      v.y = Lb[bi * 272 + i * 17 + j + 1];
      v.z = Lb[bi * 272 + i * 17 + j + 2];
      v.w = Lb[bi * 272 + i * 17 + j + 3];
      *(float4*)&Lgb[f] = v;
    }
  } else if (bx < 64 + 1024) {
    const int id = bx - 64;
    const int l0 = (id & 15) * 128;
    const int h = (id >> 4) & 15;
    const int b = id >> 8;
    float* w_lds = sm;                 // [64][132]
    float* x_lds = sm + 8448;          // [128][68]
    float* b_lds = sm + 8448 + 8704;   // [128]

    const float* wsrc = rffW + h * 8192;
    for (int f = tid * 4; f < 8192; f += 2048) {
      int d = f >> 7, m = f & 127;
      *(float4*)&w_lds[d * 132 + m] = *(const float4*)&wsrc[f];
    }
    if (tid < 128) b_lds[tid] = rffb[h * 128 + tid];
    {
      int r = tid >> 2, c0 = (tid & 3) * 16;
      const float* srow = qsrc + (long)(b * L_ + l0 + r) * 1024 + h * VD_ + c0;
      *(float4*)&x_lds[r * 68 + c0 + 0]  = *(const float4*)(srow + 0);
      *(float4*)&x_lds[r * 68 + c0 + 4]  = *(const float4*)(srow + 4);
      *(float4*)&x_lds[r * 68 + c0 + 8]  = *(const float4*)(srow + 8);
      *(float4*)&x_lds[r * 68 + c0 + 12] = *(const float4*)(srow + 12);
    }
    __syncthreads();

    const int sub = tid >> 8;
    const int t = tid & 255;
    const int ty = t >> 4, tx = t & 15;
    const int rrow = sub * 64 + 4 * ty;
    float acc[4][8];
    {
      float4 bb0 = *(const float4*)&b_lds[4 * tx];
      float4 bb1 = *(const float4*)&b_lds[4 * tx + 64];
#pragma unroll
      for (int i = 0; i < 4; ++i) {
        acc[i][0] = bb0.x; acc[i][1] = bb0.y; acc[i][2] = bb0.z; acc[i][3] = bb0.w;
        acc[i][4] = bb1.x; acc[i][5] = bb1.y; acc[i][6] = bb1.z; acc[i][7] = bb1.w;
      }
    }
#pragma unroll 8
    for (int kk = 0; kk < 64; ++kk) {
      float4 w0 = *(const float4*)&w_lds[kk * 132 + 4 * tx];
      float4 w1 = *(const float4*)&w_lds[kk * 132 + 4 * tx + 64];
      float xv[4];
#pragma unroll
      for (int i = 0; i < 4; ++i) xv[i] = x_lds[(rrow + i) * 68 + kk];
#pragma unroll
      for (int i = 0; i < 4; ++i) {
        acc[i][0] = fmaf(xv[i], w0.x, acc[i][0]);
        acc[i][1] = fmaf(xv[i], w0.y, acc[i][1]);
        acc[i][2] = fmaf(xv[i], w0.z, acc[i][2]);
        acc[i][3] = fmaf(xv[i], w0.w, acc[i][3]);
        acc[i][4] = fmaf(xv[i], w1.x, acc[i][4]);
        acc[i][5] = fmaf(xv[i], w1.y, acc[i][5]);
        acc[i][6] = fmaf(xv[i], w1.z, acc[i][6]);
        acc[i][7] = fmaf(xv[i], w1.w, acc[i][7]);
      }
    }
#pragma unroll
    for (int i = 0; i < 4; ++i) {
      int l = l0 + rrow + i;
      float4 c0, c1, s0, s1;
      float sv, cv;
      sincosf(acc[i][0], &sv, &cv); c0.x = cv * SCALE_; s0.x = sv * SCALE_;
      sincosf(acc[i][1], &sv, &cv); c0.y = cv * SCALE_; s0.y = sv * SCALE_;
      sincosf(acc[i][2], &sv, &cv); c0.z = cv * SCALE_; s0.z = sv * SCALE_;
      sincosf(acc[i][3], &sv, &cv); c0.w = cv * SCALE_; s0.w = sv * SCALE_;
      sincosf(acc[i][4], &sv, &cv); c1.x = cv * SCALE_; s1.x = sv * SCALE_;
      sincosf(acc[i][5], &sv, &cv); c1.y = cv * SCALE_; s1.y = sv * SCALE_;
      sincosf(acc[i][6], &sv, &cv); c1.z = cv * SCALE_; s1.z = sv * SCALE_;
      sincosf(acc[i][7], &sv, &cv); c1.w = cv * SCALE_; s1.w = sv * SCALE_;
      long base = ((long)(b * H_ + h) * L_ + l) * M2_;
      ushort4 hv; float4 r4;
      split4(c0, &hv, &r4);
      *(ushort4*)&ph[base + 4 * tx] = hv;
      *(ushort4*)&pl[base + 4 * tx] = (ushort4){f2bf(r4.x), f2bf(r4.y), f2bf(r4.z), f2bf(r4.w)};
      split4(c1, &hv, &r4);
      *(ushort4*)&ph[base + 64 + 4 * tx] = hv;
      *(ushort4*)&pl[base + 64 + 4 * tx] = (ushort4){f2bf(r4.x), f2bf(r4.y), f2bf(r4.z), f2bf(r4.w)};
      split4(s0, &hv, &r4);
      *(ushort4*)&ph[base + 128 + 4 * tx] = hv;
      *(ushort4*)&pl[base + 128 + 4 * tx] = (ushort4){f2bf(r4.x), f2bf(r4.y), f2bf(r4.z), f2bf(r4.w)};
      split4(s1, &hv, &r4);
      *(ushort4*)&ph[base + 192 + 4 * tx] = hv;
      *(ushort4*)&pl[base + 192 + 4 * tx] = (ushort4){f2bf(r4.x), f2bf(r4.y), f2bf(r4.z), f2bf(r4.w)};
    }
  } else {
    const int id2 = bx - (64 + 1024);
    int idx = id2 * 512 + tid;
    for (int i = idx; i < 262144; i += 65536) {
      float4 f = ((const float4*)Wo)[i];
      ushort4 hv = {f2bf(f.x), f2bf(f.y), f2bf(f.z), f2bf(f.w)};
      ((ushort4*)wo_hi)[i] = hv;
    }
  }
}

// ---------------- blocked triangular solves (emit Wt bf16 hi/lo) ------------
__global__ __launch_bounds__(256) void tri_solve_kernel(
    const float* __restrict__ Lg, const float* __restrict__ T,
    u16* __restrict__ wth, u16* __restrict__ wtl)
{
  __shared__ float Y[256 * 17];
  __shared__ float tmp[16 * 17];
  const int bh = blockIdx.y;
  const int d0 = blockIdx.x * 16;
  const int tid = threadIdx.x;
  const int i = tid >> 4, d = tid & 15;
  const float* Lb = Lg + (long)bh * 34816;
  const float* Tb = T + (long)bh * 16384;

  for (int r = i; r < 256; r += 16) Y[r * 17 + d] = Tb[r * 64 + d0 + d];
  __syncthreads();

  for (int J = 0; J < 16; ++J) {
    float acc = Y[(J * 16 + i) * 17 + d];
    for (int c = 0; c < J; ++c) {
      const float* Lblk = &Lb[(J * (J + 1) / 2 + c) * 256 + i * 16];
#pragma unroll
      for (int k = 0; k < 16; k += 4) {
        float4 l4 = *(const float4*)&Lblk[k];
        acc = fmaf(-l4.x, Y[(c * 16 + k + 0) * 17 + d], acc);
        acc = fmaf(-l4.y, Y[(c * 16 + k + 1) * 17 + d], acc);
        acc = fmaf(-l4.z, Y[(c * 16 + k + 2) * 17 + d], acc);
        acc = fmaf(-l4.w, Y[(c * 16 + k + 3) * 17 + d], acc);
      }
    }
    tmp[i * 17 + d] = acc;
    __syncthreads();
    const float* invD = &Lb[(J * (J + 1) / 2 + J) * 256 + i * 16];
    float y = 0.f;
#pragma unroll
    for (int k = 0; k < 16; ++k) y = fmaf(invD[k], tmp[k * 17 + d], y);
    Y[(J * 16 + i) * 17 + d] = y;
    __syncthreads();
  }

  for (int J = 15; J >= 0; --J) {
    float acc = Y[(J * 16 + i) * 17 + d];
    for (int I = J + 1; I < 16; ++I) {
      const float* Lblk = &Lb[(I * (I + 1) / 2 + J) * 256];
#pragma unroll
      for (int k = 0; k < 16; ++k)
        acc = fmaf(-Lblk[k * 16 + i], Y[(I * 16 + k) * 17 + d], acc);
    }
    tmp[i * 17 + d] = acc;
    __syncthreads();
    const float* invD = &Lb[(J * (J + 1) / 2 + J) * 256];
    float w = 0.f;
#pragma unroll
    for (int k = 0; k < 16; ++k) w = fmaf(invD[k * 16 + i], tmp[k * 17 + d], w);
    Y[(J * 16 + i) * 17 + d] = w;
    __syncthreads();
  }

  for (int f = tid; f < 16 * 256; f += 256) {
    int dc = f >> 8, m = f & 255;
    float val = Y[m * 17 + dc];
    u16 h = f2bf(val);
    long o = (long)bh * 16384 + (long)(d0 + dc) * 256 + m;
    wth[o] = h;
    wtl[o] = f2bf(val - bf2f(h));
  }
}

__global__ void ws_too_small_kernel(float* out) { out[0] = 12345.0f; }

extern "C" void kernel_launch(void* const* d_in, const int* in_sizes, int n_in,
                              void* d_out, int out_size, void* d_ws, size_t ws_size,
                              hipStream_t stream) {
  const float* x    = (const float*)d_in[0];
  const float* mask = (const float*)d_in[2];
  const float* Wq   = (const float*)d_in[3];
  const float* Wk   = (const float*)d_in[4];
  const float* Wv   = (const float*)d_in[5];
  const float* Wo   = (const float*)d_in[6];
  const float* bo   = (const float*)d_in[7];
  const float* rffW = (const float*)d_in[8];
  const float* rffb = (const float*)d_in[9];
  float* out = (float*)d_out;
  float* ws  = (float*)d_ws;

  const size_t needed = 58720256UL * 4UL;  // 234.9 MB
  if (ws_size < needed) {
    ws_too_small_kernel<<<1, 1, 0, stream>>>(out);
    return;
  }
  // region A [0, 8.4M): q fp32 -> oh bf16 after rff(q)
  float* q = ws;
  u16* oh_bf = (u16*)ws;
  // region B [8.4M, 16.7M): k fp32 -> T(1M)+G(4.2M)+Lg(2.2M) after reduce
  float* kbuf = ws + 8388608;
  float* T    = ws + 8388608;
  float* G    = ws + 9437184;
  float* Lg   = ws + 13631488;
  // region big [16.7M, 50.3M):
  u16* big16 = (u16*)(ws + 16777216);
  u16* x_hi = big16;
  u16* x_lo = big16 + 8388608;
  u16* w_hi = big16 + 16777216;
  u16* w_lo = big16 + 19922944;
  u16* pk_hi = big16;                      // [0, 20971520) u16
  u16* pk_lo = big16 + 20971520;           // [20971520, 41943040) u16
  float* Gp = ws + 37748736;               // 2 x 4194304 floats (K-split partials)
  float* Tp = ws + 46137344;               // 2 x 1048576 floats
  u16* phiq_hi = big16;                    // after reduce, whole big region
  u16* phiq_lo = big16 + 33554432;
  // region D [50.3M, 58.7M): v fp32 -> wt/wo bf16
  float* v = ws + 50331648;
  u16* wt_hi = (u16*)(ws + 50331648);
  u16* wt_lo = wt_hi + 1048576;
  u16* wo_hi = wt_hi + 2097152;

  hipFuncSetAttribute((const void*)chol_rffq_wo_kernel,
                      hipFuncAttributeMaxDynamicSharedMemorySize, 147968);

  dim3 blk(256);

  // 1: convert x and W to bf16 hi/lo
  cvt_split_kernel<<<8192, blk, 0, stream>>>(x, x_hi, x_lo, 2097152);
  cvt_split_kernel<<<1024, blk, 0, stream>>>(Wq, w_hi,           w_lo,           262144);
  cvt_split_kernel<<<1024, blk, 0, stream>>>(Wk, w_hi + 1048576, w_lo + 1048576, 262144);
  cvt_split_kernel<<<1024, blk, 0, stream>>>(Wv, w_hi + 2097152, w_lo + 2097152, 262144);

  // 2: QKV — qk 3-pass (uniform) + v hi-only
  mfma_qk3<<<dim3(16, 64), blk, 0, stream>>>(x_hi, x_lo, w_hi, w_lo, q, kbuf);
  mfma_nt<<<dim3(8, 64), blk, 0, stream>>>(x_hi, w_hi + 2097152, v,
                                           1024, 1024, 1024, 1024, nullptr, nullptr);

  // 3: two bh-halves: rff(k)->pkT, vT->pkT, [G|T] MFMA (K-split x2 partials)
  for (int half = 0; half < 2; ++half) {
    int b0 = half * 2, bh0 = half * 32;
    rff_k_t<<<dim3(32, 16, 2), blk, 0, stream>>>(kbuf, mask, rffW, rffb, pk_hi, pk_lo, b0);
    vt_kernel<<<dim3(16, 32), blk, 0, stream>>>(v, mask, pk_hi, pk_lo, b0);
    mfma_gt<<<dim3(5, 4, 32), blk, 0, stream>>>(pk_hi, pk_lo, Gp, Tp, bh0);
  }

  // 4: reduce partials -> final G, T (frees the big region for phiq)
  reduce_gt_kernel<<<5120, blk, 0, stream>>>(Gp, G, Tp, T);

  // 5: fused chol + rff(q)->phiq + Wo cvt
  chol_rffq_wo_kernel<<<dim3(64 + 1024 + 128), dim3(512), 147968, stream>>>(
      G, Lg, q, rffW, rffb, phiq_hi, phiq_lo, Wo, wo_hi);

  // 6: tri solves -> wt bf16 hi/lo directly
  tri_solve_kernel<<<dim3(4, 64), dim3(256), 0, stream>>>(Lg, T, wt_hi, wt_lo);

  // 7: out-heads MFMA (bf16 output)
  mfma_out_k<<<dim3(16, 64), blk, 0, stream>>>(phiq_hi, phiq_lo, wt_hi, wt_lo, oh_bf);

  // 8: Wo projection (bf16 MFMA) with bias+mask epilogue
  mfma_nt<<<dim3(8, 64), blk, 0, stream>>>(oh_bf, wo_hi, out, 1024, 1024, 1024, 1024, bo, mask);
}

// Round 9
// 893.234 us; speedup vs baseline: 5.3622x; 1.0731x over previous
//
#include <hip/hip_runtime.h>
#include <math.h>

#define B_ 4
#define L_ 2048
#define HD_ 1024
#define H_ 16
#define VD_ 64
#define M_ 128
#define M2_ 256
#define RIDGE_ 0.01f
#define SCALE_ 0.08838834764831845f   // 1/sqrt(128)

typedef unsigned short u16;
typedef __attribute__((ext_vector_type(8))) short short8;
typedef __attribute__((ext_vector_type(4))) float floatx4;

__device__ __forceinline__ u16 f2bf(float x) {
  unsigned u = __float_as_uint(x);
  unsigned r = u + 0x7fff + ((u >> 16) & 1);
  return (u16)(r >> 16);
}
__device__ __forceinline__ float bf2f(u16 h) {
  return __uint_as_float(((unsigned)h) << 16);
}
__device__ __forceinline__ void gload_lds16(const u16* g, u16* l) {
  __builtin_amdgcn_global_load_lds(
      (const __attribute__((address_space(1))) unsigned int*)g,
      (__attribute__((address_space(3))) unsigned int*)l, 16, 0, 0);
}
__device__ __forceinline__ void split4(float4 f, ushort4* h, float4* r) {
  h->x = f2bf(f.x); h->y = f2bf(f.y); h->z = f2bf(f.z); h->w = f2bf(f.w);
  r->x = f.x - bf2f(h->x); r->y = f.y - bf2f(h->y);
  r->z = f.z - bf2f(h->z); r->w = f.w - bf2f(h->w);
}

// ---------------- fp32 -> bf16 hi/lo split ---------------------------------
__global__ __launch_bounds__(256) void cvt_split_kernel(
    const float* __restrict__ src, u16* __restrict__ hi, u16* __restrict__ lo, int n4)
{
  int i = blockIdx.x * 256 + threadIdx.x;
  if (i < n4) {
    float4 f = ((const float4*)src)[i];
    ushort4 hv; float4 r;
    split4(f, &hv, &r);
    ushort4 lv = {f2bf(r.x), f2bf(r.y), f2bf(r.z), f2bf(r.w)};
    ((ushort4*)hi)[i] = hv;
    ((ushort4*)lo)[i] = lv;
  }
}

// ---------------- bf16 MFMA GEMM (single-pass), C = A * B^T ----------------
__global__ __launch_bounds__(256) void mfma_nt(
    const u16* __restrict__ A0, const u16* __restrict__ B0,
    float* __restrict__ C, int Ndim, int Kdim, int ldA, int ldB,
    const float* __restrict__ bias, const float* __restrict__ mask)
{
  __shared__ __align__(16) u16 a_sm[4096];
  __shared__ __align__(16) u16 b_sm[4096];
  const int tid = threadIdx.x;
  const int wave = tid >> 6, lane = tid & 63;
  const int m0 = blockIdx.y * 128, n0 = blockIdx.x * 128;
  const int wrow = (wave >> 1) * 64, wcol = (wave & 1) * 64;
  const int fm = lane & 15, q = lane >> 4;

  floatx4 acc[4][4];
#pragma unroll
  for (int i = 0; i < 4; ++i)
#pragma unroll
    for (int j = 0; j < 4; ++j) acc[i][j] = (floatx4){0.f, 0.f, 0.f, 0.f};

  const u16* Ag0 = A0 + (long)(m0 + lane) * ldA + wave * 8;
  const u16* Ag1 = A0 + (long)(m0 + 64 + lane) * ldA + wave * 8;
  const u16* Bg0 = B0 + (long)(n0 + lane) * ldB + wave * 8;
  const u16* Bg1 = B0 + (long)(n0 + 64 + lane) * ldB + wave * 8;
  u16* la0 = &a_sm[(wave * 128 + 0) * 8];
  u16* la1 = &a_sm[(wave * 128 + 64) * 8];
  u16* lb0 = &b_sm[(wave * 128 + 0) * 8];
  u16* lb1 = &b_sm[(wave * 128 + 64) * 8];

  for (int k0 = 0; k0 < Kdim; k0 += 32) {
    __syncthreads();
    gload_lds16(Ag0 + k0, la0);
    gload_lds16(Ag1 + k0, la1);
    gload_lds16(Bg0 + k0, lb0);
    gload_lds16(Bg1 + k0, lb1);
    __syncthreads();
    short8 af[4], bf[4];
#pragma unroll
    for (int i = 0; i < 4; ++i)
      af[i] = *(const short8*)&a_sm[(q * 128 + wrow + i * 16 + fm) * 8];
#pragma unroll
    for (int j = 0; j < 4; ++j)
      bf[j] = *(const short8*)&b_sm[(q * 128 + wcol + j * 16 + fm) * 8];
#pragma unroll
    for (int i = 0; i < 4; ++i)
#pragma unroll
      for (int j = 0; j < 4; ++j)
        acc[i][j] = __builtin_amdgcn_mfma_f32_16x16x32_bf16(af[i], bf[j], acc[i][j], 0, 0, 0);
  }

  const int colb = n0 + wcol + fm;
  const int rbase = m0 + wrow + (lane >> 4) * 4;
#pragma unroll
  for (int j = 0; j < 4; ++j) {
    int cg = colb + j * 16;
    float bb = bias ? bias[cg] : 0.f;
#pragma unroll
    for (int i = 0; i < 4; ++i) {
#pragma unroll
      for (int r = 0; r < 4; ++r) {
        int row = rbase + i * 16 + r;
        float val = acc[i][j][r];
        if (bias) val = (val + bb) * mask[row];
        C[(long)row * Ndim + cg] = val;
      }
    }
  }
}

// ---------------- uniform bf16x3 MFMA GEMM (q,k columns only) ---------------
__global__ __launch_bounds__(256) void mfma_qk3(
    const u16* __restrict__ Ah, const u16* __restrict__ Al,
    const u16* __restrict__ Bh, const u16* __restrict__ Bl,
    float* __restrict__ Cq, float* __restrict__ Ck)
{
  __shared__ __align__(16) u16 ah_sm[4096], al_sm[4096];
  __shared__ __align__(16) u16 bh_sm[4096], bl_sm[4096];
  const int tid = threadIdx.x;
  const int wave = tid >> 6, lane = tid & 63;
  const int m0 = blockIdx.y * 128, n0 = blockIdx.x * 128;
  const int wrow = (wave >> 1) * 64, wcol = (wave & 1) * 64;
  const int fm = lane & 15, q = lane >> 4;

  floatx4 acc[4][4];
#pragma unroll
  for (int i = 0; i < 4; ++i)
#pragma unroll
    for (int j = 0; j < 4; ++j) acc[i][j] = (floatx4){0.f, 0.f, 0.f, 0.f};

  const long a0o = (long)(m0 + lane) * 1024 + wave * 8;
  const long a1o = (long)(m0 + 64 + lane) * 1024 + wave * 8;
  const long b0o = (long)(n0 + lane) * 1024 + wave * 8;
  const long b1o = (long)(n0 + 64 + lane) * 1024 + wave * 8;
  u16* lah0 = &ah_sm[(wave * 128 + 0) * 8];
  u16* lah1 = &ah_sm[(wave * 128 + 64) * 8];
  u16* lal0 = &al_sm[(wave * 128 + 0) * 8];
  u16* lal1 = &al_sm[(wave * 128 + 64) * 8];
  u16* lbh0 = &bh_sm[(wave * 128 + 0) * 8];
  u16* lbh1 = &bh_sm[(wave * 128 + 64) * 8];
  u16* lbl0 = &bl_sm[(wave * 128 + 0) * 8];
  u16* lbl1 = &bl_sm[(wave * 128 + 64) * 8];

  for (int k0 = 0; k0 < 1024; k0 += 32) {
    __syncthreads();
    gload_lds16(Ah + a0o + k0, lah0);
    gload_lds16(Ah + a1o + k0, lah1);
    gload_lds16(Al + a0o + k0, lal0);
    gload_lds16(Al + a1o + k0, lal1);
    gload_lds16(Bh + b0o + k0, lbh0);
    gload_lds16(Bh + b1o + k0, lbh1);
    gload_lds16(Bl + b0o + k0, lbl0);
    gload_lds16(Bl + b1o + k0, lbl1);
    __syncthreads();
    short8 afh[4], afl[4], bfh[4], bfl[4];
#pragma unroll
    for (int i = 0; i < 4; ++i) {
      afh[i] = *(const short8*)&ah_sm[(q * 128 + wrow + i * 16 + fm) * 8];
      afl[i] = *(const short8*)&al_sm[(q * 128 + wrow + i * 16 + fm) * 8];
    }
#pragma unroll
    for (int j = 0; j < 4; ++j) {
      bfh[j] = *(const short8*)&bh_sm[(q * 128 + wcol + j * 16 + fm) * 8];
      bfl[j] = *(const short8*)&bl_sm[(q * 128 + wcol + j * 16 + fm) * 8];
    }
#pragma unroll
    for (int i = 0; i < 4; ++i)
#pragma unroll
      for (int j = 0; j < 4; ++j) {
        acc[i][j] = __builtin_amdgcn_mfma_f32_16x16x32_bf16(afh[i], bfh[j], acc[i][j], 0, 0, 0);
        acc[i][j] = __builtin_amdgcn_mfma_f32_16x16x32_bf16(afl[i], bfh[j], acc[i][j], 0, 0, 0);
        acc[i][j] = __builtin_amdgcn_mfma_f32_16x16x32_bf16(afh[i], bfl[j], acc[i][j], 0, 0, 0);
      }
  }

  float* Cp; int cb;
  if (n0 < 1024) { Cp = Cq; cb = n0; }
  else           { Cp = Ck; cb = n0 - 1024; }
  const int colb = cb + wcol + fm;
  const int rbase = m0 + wrow + (lane >> 4) * 4;
#pragma unroll
  for (int j = 0; j < 4; ++j) {
    int cg = colb + j * 16;
#pragma unroll
    for (int i = 0; i < 4; ++i)
#pragma unroll
      for (int r = 0; r < 4; ++r)
        Cp[(long)(rbase + i * 16 + r) * 1024 + cg] = acc[i][j][r];
  }
}

// ---------------- RFF(k): transposed bf16 hi/lo into pkT --------------------
__global__ __launch_bounds__(256) void rff_k_t(
    const float* __restrict__ src, const float* __restrict__ mask,
    const float* __restrict__ rffW, const float* __restrict__ rffb,
    u16* __restrict__ pkh, u16* __restrict__ pkl, int b0)
{
  __shared__ __align__(16) float w_lds[64][132];
  __shared__ __align__(16) float x_lds[64][68];
  __shared__ float b_lds[128];
  const int l0 = blockIdx.x * 64;
  const int h = blockIdx.y, b = b0 + blockIdx.z;
  const int zloc = blockIdx.z * 16 + h;
  const int tid = threadIdx.x;

  const float* wsrc = rffW + h * 8192;
  for (int f = tid * 4; f < 8192; f += 1024) {
    int d = f >> 7, m = f & 127;
    *(float4*)&w_lds[d][m] = *(const float4*)&wsrc[f];
  }
  if (tid < 128) b_lds[tid] = rffb[h * 128 + tid];
  {
    int r = tid >> 2, c0 = (tid & 3) * 16;
    const float* srow = src + (long)(b * L_ + l0 + r) * 1024 + h * VD_ + c0;
    *(float4*)&x_lds[r][c0 + 0]  = *(const float4*)(srow + 0);
    *(float4*)&x_lds[r][c0 + 4]  = *(const float4*)(srow + 4);
    *(float4*)&x_lds[r][c0 + 8]  = *(const float4*)(srow + 8);
    *(float4*)&x_lds[r][c0 + 12] = *(const float4*)(srow + 12);
  }
  __syncthreads();

  const int ty = tid >> 4, tx = tid & 15;
  float acc[4][8];
  {
    float4 bb0 = *(const float4*)&b_lds[4 * tx];
    float4 bb1 = *(const float4*)&b_lds[4 * tx + 64];
#pragma unroll
    for (int i = 0; i < 4; ++i) {
      acc[i][0] = bb0.x; acc[i][1] = bb0.y; acc[i][2] = bb0.z; acc[i][3] = bb0.w;
      acc[i][4] = bb1.x; acc[i][5] = bb1.y; acc[i][6] = bb1.z; acc[i][7] = bb1.w;
    }
  }
#pragma unroll 8
  for (int kk = 0; kk < 64; ++kk) {
    float4 w0 = *(const float4*)&w_lds[kk][4 * tx];
    float4 w1 = *(const float4*)&w_lds[kk][4 * tx + 64];
    float xv[4];
#pragma unroll
    for (int i = 0; i < 4; ++i) xv[i] = x_lds[4 * ty + i][kk];
#pragma unroll
    for (int i = 0; i < 4; ++i) {
      acc[i][0] = fmaf(xv[i], w0.x, acc[i][0]);
      acc[i][1] = fmaf(xv[i], w0.y, acc[i][1]);
      acc[i][2] = fmaf(xv[i], w0.z, acc[i][2]);
      acc[i][3] = fmaf(xv[i], w0.w, acc[i][3]);
      acc[i][4] = fmaf(xv[i], w1.x, acc[i][4]);
      acc[i][5] = fmaf(xv[i], w1.y, acc[i][5]);
      acc[i][6] = fmaf(xv[i], w1.z, acc[i][6]);
      acc[i][7] = fmaf(xv[i], w1.w, acc[i][7]);
    }
  }
  float fi[4];
#pragma unroll
  for (int i = 0; i < 4; ++i) fi[i] = SCALE_ * mask[b * L_ + l0 + 4 * ty + i];
  float cvv[4][8], svv[4][8];
#pragma unroll
  for (int i = 0; i < 4; ++i)
#pragma unroll
    for (int jj = 0; jj < 8; ++jj) {
      float sv, cv;
      sincosf(acc[i][jj], &sv, &cv);
      cvv[i][jj] = cv * fi[i];
      svv[i][jj] = sv * fi[i];
    }
  const long lbase = l0 + 4 * ty;
  const long zbase = (long)zloc * 655360;
#pragma unroll
  for (int jj = 0; jj < 8; ++jj) {
    int mcol = (jj < 4) ? (4 * tx + jj) : (64 + 4 * tx + (jj - 4));
    ushort4 h4, l4;
    h4.x = f2bf(cvv[0][jj]); l4.x = f2bf(cvv[0][jj] - bf2f(h4.x));
    h4.y = f2bf(cvv[1][jj]); l4.y = f2bf(cvv[1][jj] - bf2f(h4.y));
    h4.z = f2bf(cvv[2][jj]); l4.z = f2bf(cvv[2][jj] - bf2f(h4.z));
    h4.w = f2bf(cvv[3][jj]); l4.w = f2bf(cvv[3][jj] - bf2f(h4.w));
    long base = zbase + (long)mcol * 2048 + lbase;
    *(ushort4*)&pkh[base] = h4;
    *(ushort4*)&pkl[base] = l4;
    ushort4 hs, ls;
    hs.x = f2bf(svv[0][jj]); ls.x = f2bf(svv[0][jj] - bf2f(hs.x));
    hs.y = f2bf(svv[1][jj]); ls.y = f2bf(svv[1][jj] - bf2f(hs.y));
    hs.z = f2bf(svv[2][jj]); ls.z = f2bf(svv[2][jj] - bf2f(hs.z));
    hs.w = f2bf(svv[3][jj]); ls.w = f2bf(svv[3][jj] - bf2f(hs.w));
    long base2 = zbase + (long)(mcol + 128) * 2048 + lbase;
    *(ushort4*)&pkh[base2] = hs;
    *(ushort4*)&pkl[base2] = ls;
  }
}

// ---------------- masked V transpose into pkT rows 256..319 -----------------
__global__ __launch_bounds__(256) void vt_kernel(
    const float* __restrict__ v, const float* __restrict__ mask,
    u16* __restrict__ pkh, u16* __restrict__ pkl, int b0)
{
  __shared__ float t[128][65];
  const int z = blockIdx.y;
  const int b = b0 + (z >> 4), h = z & 15;
  const int l0 = blockIdx.x * 128;
  const int tid = threadIdx.x;
  const int d = tid & 63, lg = tid >> 6;
  for (int i = 0; i < 128; i += 4) {
    int ll = i + lg;
    float mv = mask[b * L_ + l0 + ll];
    t[ll][d] = v[(long)(b * L_ + l0 + ll) * 1024 + h * 64 + d] * mv;
  }
  __syncthreads();
  const int d2 = tid >> 2, lofs = (tid & 3) * 32;
  long base = (long)z * 655360 + (long)(256 + d2) * 2048 + l0 + lofs;
  for (int j = 0; j < 32; j += 4) {
    float f0 = t[lofs + j + 0][d2], f1 = t[lofs + j + 1][d2];
    float f2 = t[lofs + j + 2][d2], f3 = t[lofs + j + 3][d2];
    ushort4 hv, lv;
    hv.x = f2bf(f0); lv.x = f2bf(f0 - bf2f(hv.x));
    hv.y = f2bf(f1); lv.y = f2bf(f1 - bf2f(hv.y));
    hv.z = f2bf(f2); lv.z = f2bf(f2 - bf2f(hv.z));
    hv.w = f2bf(f3); lv.w = f2bf(f3 - bf2f(hv.w));
    *(ushort4*)&pkh[base + j] = hv;
    *(ushort4*)&pkl[base + j] = lv;
  }
}

// ---------------- batched bf16x3 MFMA: [G|T] partials, K-split x2 -----------
__global__ __launch_bounds__(256) void mfma_gt(
    const u16* __restrict__ pkh, const u16* __restrict__ pkl,
    float* __restrict__ Gp, float* __restrict__ Tp, int bh0)
{
  __shared__ __align__(16) u16 ah_sm[4096], al_sm[4096];
  __shared__ __align__(16) u16 bh_sm[2048], bl_sm[2048];
  const int tid = threadIdx.x;
  const int wave = tid >> 6, lane = tid & 63;
  const int z = blockIdx.z;
  const int mt = blockIdx.y & 1, kc = blockIdx.y >> 1;
  const int m0 = mt * 128, n0 = blockIdx.x * 64;
  const int wrow = (wave >> 1) * 64, wcol = (wave & 1) * 32;
  const int fm = lane & 15, q = lane >> 4;
  const long batch = (long)z * 655360;
  const u16* Ah = pkh + batch;
  const u16* Al = pkl + batch;

  floatx4 acc[4][2];
#pragma unroll
  for (int i = 0; i < 4; ++i)
#pragma unroll
    for (int j = 0; j < 2; ++j) acc[i][j] = (floatx4){0.f, 0.f, 0.f, 0.f};

  const long a0o = (long)(m0 + lane) * 2048 + wave * 8;
  const long a1o = (long)(m0 + 64 + lane) * 2048 + wave * 8;
  const long b0o = (long)(n0 + lane) * 2048 + wave * 8;
  u16* lah0 = &ah_sm[(wave * 128 + 0) * 8];
  u16* lah1 = &ah_sm[(wave * 128 + 64) * 8];
  u16* lal0 = &al_sm[(wave * 128 + 0) * 8];
  u16* lal1 = &al_sm[(wave * 128 + 64) * 8];
  u16* lbh = &bh_sm[(wave * 64) * 8];
  u16* lbl = &bl_sm[(wave * 64) * 8];

  const int kbeg = kc * 1024, kend = kbeg + 1024;
  for (int k0 = kbeg; k0 < kend; k0 += 32) {
    __syncthreads();
    gload_lds16(Ah + a0o + k0, lah0);
    gload_lds16(Ah + a1o + k0, lah1);
    gload_lds16(Al + a0o + k0, lal0);
    gload_lds16(Al + a1o + k0, lal1);
    gload_lds16(Ah + b0o + k0, lbh);
    gload_lds16(Al + b0o + k0, lbl);
    __syncthreads();
    short8 afh[4], afl[4], bfh[2], bfl[2];
#pragma unroll
    for (int i = 0; i < 4; ++i) {
      afh[i] = *(const short8*)&ah_sm[(q * 128 + wrow + i * 16 + fm) * 8];
      afl[i] = *(const short8*)&al_sm[(q * 128 + wrow + i * 16 + fm) * 8];
    }
#pragma unroll
    for (int j = 0; j < 2; ++j) {
      bfh[j] = *(const short8*)&bh_sm[(q * 64 + wcol + j * 16 + fm) * 8];
      bfl[j] = *(const short8*)&bl_sm[(q * 64 + wcol + j * 16 + fm) * 8];
    }
#pragma unroll
    for (int i = 0; i < 4; ++i)
#pragma unroll
      for (int j = 0; j < 2; ++j) {
        acc[i][j] = __builtin_amdgcn_mfma_f32_16x16x32_bf16(afh[i], bfh[j], acc[i][j], 0, 0, 0);
        acc[i][j] = __builtin_amdgcn_mfma_f32_16x16x32_bf16(afl[i], bfh[j], acc[i][j], 0, 0, 0);
        acc[i][j] = __builtin_amdgcn_mfma_f32_16x16x32_bf16(afh[i], bfl[j], acc[i][j], 0, 0, 0);
      }
  }

  const int bh = bh0 + z;
  float* Gb = Gp + (long)kc * 4194304;
  float* Tb = Tp + (long)kc * 1048576;
  const int rbase = m0 + wrow + (lane >> 4) * 4;
#pragma unroll
  for (int j = 0; j < 2; ++j) {
    int col = n0 + wcol + j * 16 + fm;
#pragma unroll
    for (int i = 0; i < 4; ++i)
#pragma unroll
      for (int r = 0; r < 4; ++r) {
        int row = rbase + i * 16 + r;
        float val = acc[i][j][r];
        if (n0 < 256) Gb[(long)bh * 65536 + (long)row * 256 + col] = val;
        else Tb[(long)bh * 16384 + (long)row * 64 + (col - 256)] = val;
      }
  }
}

// ---------------- reduce K-split partials into final G, T -------------------
__global__ __launch_bounds__(256) void reduce_gt_kernel(
    const float* __restrict__ Gp, float* __restrict__ G,
    const float* __restrict__ Tp, float* __restrict__ T)
{
  long i = (long)blockIdx.x * 256 + threadIdx.x;  // float4 index
  if (i < 1048576) {
    float4 a = ((const float4*)Gp)[i];
    float4 b = ((const float4*)(Gp + 4194304))[i];
    float4 o = {a.x + b.x, a.y + b.y, a.z + b.z, a.w + b.w};
    ((float4*)G)[i] = o;
  } else {
    long j = i - 1048576;
    float4 a = ((const float4*)Tp)[j];
    float4 b = ((const float4*)(Tp + 1048576))[j];
    float4 o = {a.x + b.x, a.y + b.y, a.z + b.z, a.w + b.w};
    ((float4*)T)[j] = o;
  }
}

// ---------------- batched bf16x3 MFMA: oh = PhiQ @ Wt^T (bf16 out) ----------
__global__ __launch_bounds__(256) void mfma_out_k(
    const u16* __restrict__ ph, const u16* __restrict__ pl,
    const u16* __restrict__ wth, const u16* __restrict__ wtl,
    u16* __restrict__ oh)
{
  __shared__ __align__(16) u16 ah_sm[4096], al_sm[4096];
  __shared__ __align__(16) u16 bh_sm[2048], bl_sm[2048];
  const int tid = threadIdx.x;
  const int wave = tid >> 6, lane = tid & 63;
  const int bh = blockIdx.y;
  const int b = bh >> 4, h = bh & 15;
  const int l0 = blockIdx.x * 128;
  const int wrow = (wave >> 1) * 64, wcol = (wave & 1) * 32;
  const int fm = lane & 15, q = lane >> 4;
  const u16* Ah = ph + (long)bh * 524288 + (long)l0 * 256;
  const u16* Al = pl + (long)bh * 524288 + (long)l0 * 256;
  const u16* Bh = wth + (long)bh * 16384;
  const u16* Bl = wtl + (long)bh * 16384;

  floatx4 acc[4][2];
#pragma unroll
  for (int i = 0; i < 4; ++i)
#pragma unroll
    for (int j = 0; j < 2; ++j) acc[i][j] = (floatx4){0.f, 0.f, 0.f, 0.f};

  const long a0o = (long)lane * 256 + wave * 8;
  const long a1o = (long)(64 + lane) * 256 + wave * 8;
  const long b0o = (long)lane * 256 + wave * 8;
  u16* lah0 = &ah_sm[(wave * 128 + 0) * 8];
  u16* lah1 = &ah_sm[(wave * 128 + 64) * 8];
  u16* lal0 = &al_sm[(wave * 128 + 0) * 8];
  u16* lal1 = &al_sm[(wave * 128 + 64) * 8];
  u16* lbh = &bh_sm[(wave * 64) * 8];
  u16* lbl = &bl_sm[(wave * 64) * 8];

  for (int k0 = 0; k0 < 256; k0 += 32) {
    __syncthreads();
    gload_lds16(Ah + a0o + k0, lah0);
    gload_lds16(Ah + a1o + k0, lah1);
    gload_lds16(Al + a0o + k0, lal0);
    gload_lds16(Al + a1o + k0, lal1);
    gload_lds16(Bh + b0o + k0, lbh);
    gload_lds16(Bl + b0o + k0, lbl);
    __syncthreads();
    short8 afh[4], afl[4], bfh[2], bfl[2];
#pragma unroll
    for (int i = 0; i < 4; ++i) {
      afh[i] = *(const short8*)&ah_sm[(q * 128 + wrow + i * 16 + fm) * 8];
      afl[i] = *(const short8*)&al_sm[(q * 128 + wrow + i * 16 + fm) * 8];
    }
#pragma unroll
    for (int j = 0; j < 2; ++j) {
      bfh[j] = *(const short8*)&bh_sm[(q * 64 + wcol + j * 16 + fm) * 8];
      bfl[j] = *(const short8*)&bl_sm[(q * 64 + wcol + j * 16 + fm) * 8];
    }
#pragma unroll
    for (int i = 0; i < 4; ++i)
#pragma unroll
      for (int j = 0; j < 2; ++j) {
        acc[i][j] = __builtin_amdgcn_mfma_f32_16x16x32_bf16(afh[i], bfh[j], acc[i][j], 0, 0, 0);
        acc[i][j] = __builtin_amdgcn_mfma_f32_16x16x32_bf16(afl[i], bfh[j], acc[i][j], 0, 0, 0);
        acc[i][j] = __builtin_amdgcn_mfma_f32_16x16x32_bf16(afh[i], bfl[j], acc[i][j], 0, 0, 0);
      }
  }

  const int rbase = l0 + wrow + (lane >> 4) * 4;
#pragma unroll
  for (int j = 0; j < 2; ++j) {
    int col = h * 64 + wcol + j * 16 + fm;
#pragma unroll
    for (int i = 0; i < 4; ++i)
#pragma unroll
      for (int r = 0; r < 4; ++r)
        oh[(long)(b * L_ + rbase + i * 16 + r) * 1024 + col] = f2bf(acc[i][j][r]);
  }
}

// ---------------- fused: out-of-core chol (0-63) + rff(q) (64-2111) + Wo cvt
// Small uniform LDS (51712 B) -> 3 blocks/CU for all segments.
// chol: in-place on dense G; panel cached in LDS; diag slots <- invD,
// strict lower <- L. Trailing matrix lives in global (L2-resident).
__global__ __launch_bounds__(512) void chol_rffq_wo_kernel(
    float* __restrict__ Gw,
    const float* __restrict__ qsrc,
    const float* __restrict__ rffW, const float* __restrict__ rffb,
    u16* __restrict__ ph, u16* __restrict__ pl,
    const float* __restrict__ Wo, u16* __restrict__ wo_hi)
{
  extern __shared__ float sm[];
  const int bx = blockIdx.x;
  const int tid = threadIdx.x;

  if (bx < 64) {
    // ---------- out-of-core blocked Cholesky, 1 bh per block ----------
    float* panel = sm;           // [256][17] = 4352 floats
    float* invD  = sm + 4352;    // [16][17]  = 272 floats
    float* Gb = Gw + (long)bx * 65536;

    for (int p = 0; p < 16; ++p) {
      // A: wave 0 factors diag block (global -> regs), computes invD
      if (tid < 64) {
        const int i = tid & 15;
        float r[16];
#pragma unroll
        for (int k = 0; k < 16; ++k) r[k] = Gb[(16 * p + i) * 256 + 16 * p + k];
        r[i] += RIDGE_;
#pragma unroll
        for (int j = 0; j < 16; ++j) {
          float dj = __shfl(r[j], j);
          float dinv = 1.0f / sqrtf(dj);
          r[j] *= dinv;
          float Lij = r[j];
#pragma unroll
          for (int k = j + 1; k < 16; ++k) {
            float Lkj = __shfl(r[j], k);
            r[k] = fmaf(-Lij, Lkj, r[k]);
          }
        }
        float x[16];
#pragma unroll
        for (int j = 0; j < 16; ++j) {
          float s = (i == j) ? 1.0f : 0.0f;
#pragma unroll
          for (int k = 0; k < j; ++k) {
            float Ljk = __shfl(r[k], j);
            s = fmaf(-Ljk, x[k], s);
          }
          float Ljj = __shfl(r[j], j);
          x[j] = s / Ljj;
        }
        if (tid < 16) {
#pragma unroll
          for (int j = 0; j < 16; ++j) {
            invD[j * 17 + tid] = x[j];
            Gb[(16 * p + j) * 256 + 16 * p + tid] = x[j];  // diag slot <- invD
          }
        }
      }
      __syncthreads();

      const int nIb = 15 - p;
      if (nIb == 0) break;
      const int nrows = nIb * 16;
      const int r0 = 16 * (p + 1);

      // B1: stage A(trailing rows, panel col p) into LDS (coalesced)
      for (int f = tid; f < nrows * 16; f += 512) {
        int rr = f >> 4, cc = f & 15;
        panel[(r0 + rr) * 17 + cc] = Gb[(long)(r0 + rr) * 256 + 16 * p + cc];
      }
      __syncthreads();

      // B2: L(I,p) = A(I,p) * invD^T  (compute to regs, then store)
      float outv[8];
#pragma unroll
      for (int s = 0; s < 8; ++s) {
        int f = tid + s * 512;
        if (f < nrows * 16) {
          int rr = f >> 4, j = f & 15;
          const float* arow = &panel[(r0 + rr) * 17];
          const float* dcol = &invD[j * 17];
          float s2 = 0.f;
#pragma unroll
          for (int k = 0; k < 16; ++k) s2 = fmaf(arow[k], dcol[k], s2);
          outv[s] = s2;
        }
      }
      __syncthreads();
#pragma unroll
      for (int s = 0; s < 8; ++s) {
        int f = tid + s * 512;
        if (f < nrows * 16) {
          int rr = f >> 4, j = f & 15;
          panel[(r0 + rr) * 17 + j] = outv[s];
          Gb[(long)(r0 + rr) * 256 + 16 * p + j] = outv[s];
        }
      }
      __syncthreads();

      // C: trailing update in global, panels from LDS
      const int npairs = nIb * (nIb + 1) / 2;
      const int g = tid >> 4, t = tid & 15;
      const int tx = t & 3, ty = t >> 2;
      for (int pi0 = 0; pi0 < npairs; pi0 += 32) {
        int pi = pi0 + g;
        if (pi < npairs) {
          int a = 0; while ((a + 1) * (a + 2) / 2 <= pi) ++a;
          int b2 = pi - a * (a + 1) / 2;
          int I = p + 1 + a, J = p + 1 + b2;
          float c4[4][4];
#pragma unroll
          for (int ii = 0; ii < 4; ++ii) {
            float4 cv = *(const float4*)&Gb[(long)(16 * I + 4 * ty + ii) * 256 + 16 * J + 4 * tx];
            c4[ii][0] = cv.x; c4[ii][1] = cv.y; c4[ii][2] = cv.z; c4[ii][3] = cv.w;
          }
#pragma unroll
          for (int kk = 0; kk < 16; ++kk) {
            float av[4], bv[4];
#pragma unroll
            for (int ii = 0; ii < 4; ++ii) av[ii] = panel[(16 * I + 4 * ty + ii) * 17 + kk];
#pragma unroll
            for (int jj = 0; jj < 4; ++jj) bv[jj] = panel[(16 * J + 4 * tx + jj) * 17 + kk];
#pragma unroll
            for (int ii = 0; ii < 4; ++ii)
#pragma unroll
              for (int jj = 0; jj < 4; ++jj)
                c4[ii][jj] = fmaf(-av[ii], bv[jj], c4[ii][jj]);
          }
#pragma unroll
          for (int ii = 0; ii < 4; ++ii) {
            float4 cv = {c4[ii][0], c4[ii][1], c4[ii][2], c4[ii][3]};
            *(float4*)&Gb[(long)(16 * I + 4 * ty + ii) * 256 + 16 * J + 4 * tx] = cv;
          }
        }
      }
      __syncthreads();
    }
  } else if (bx < 64 + 2048) {
    // ---------- RFF(q) -> phiq bf16 hi/lo, 64 rows/block ----------
    const int id = bx - 64;
    const int l0 = (id & 31) * 64;
    const int h = (id >> 5) & 15;
    const int b = id >> 9;
    float* w_lds = sm;                // [64][132] = 8448
    float* x_lds = sm + 8448;         // [64][68]  = 4352
    float* b_lds = sm + 12800;        // [128]

    const float* wsrc = rffW + h * 8192;
    for (int f = tid * 4; f < 8192; f += 2048) {
      int d = f >> 7, m = f & 127;
      *(float4*)&w_lds[d * 132 + m] = *(const float4*)&wsrc[f];
    }
    if (tid < 128) b_lds[tid] = rffb[h * 128 + tid];
    {
      int r = tid >> 3, c0 = (tid & 7) * 8;
      const float* srow = qsrc + (long)(b * L_ + l0 + r) * 1024 + h * VD_ + c0;
      *(float4*)&x_lds[r * 68 + c0 + 0] = *(const float4*)(srow + 0);
      *(float4*)&x_lds[r * 68 + c0 + 4] = *(const float4*)(srow + 4);
    }
    __syncthreads();

    const int sub = tid >> 8;          // 0..1 -> row half
    const int t = tid & 255;
    const int ty = t >> 4, tx = t & 15;
    const int rrow = sub * 32 + 2 * ty;  // 2 rows per thread
    float acc[2][8];
    {
      float4 bb0 = *(const float4*)&b_lds[4 * tx];
      float4 bb1 = *(const float4*)&b_lds[4 * tx + 64];
#pragma unroll
      for (int i = 0; i < 2; ++i) {
        acc[i][0] = bb0.x; acc[i][1] = bb0.y; acc[i][2] = bb0.z; acc[i][3] = bb0.w;
        acc[i][4] = bb1.x; acc[i][5] = bb1.y; acc[i][6] = bb1.z; acc[i][7] = bb1.w;
      }
    }
#pragma unroll 8
    for (int kk = 0; kk < 64; ++kk) {
      float4 w0 = *(const float4*)&w_lds[kk * 132 + 4 * tx];
      float4 w1 = *(const float4*)&w_lds[kk * 132 + 4 * tx + 64];
      float xv[2];
#pragma unroll
      for (int i = 0; i < 2; ++i) xv[i] = x_lds[(rrow + i) * 68 + kk];
#pragma unroll
      for (int i = 0; i < 2; ++i) {
        acc[i][0] = fmaf(xv[i], w0.x, acc[i][0]);
        acc[i][1] = fmaf(xv[i], w0.y, acc[i][1]);
        acc[i][2] = fmaf(xv[i], w0.z, acc[i][2]);
        acc[i][3] = fmaf(xv[i], w0.w, acc[i][3]);
        acc[i][4] = fmaf(xv[i], w1.x, acc[i][4]);
        acc[i][5] = fmaf(xv[i], w1.y, acc[i][5]);
        acc[i][6] = fmaf(xv[i], w1.z, acc[i][6]);
        acc[i][7] = fmaf(xv[i], w1.w, acc[i][7]);
      }
    }
#pragma unroll
    for (int i = 0; i < 2; ++i) {
      int l = l0 + rrow + i;
      float4 c0, c1, s0, s1;
      float sv, cv;
      sincosf(acc[i][0], &sv, &cv); c0.x = cv * SCALE_; s0.x = sv * SCALE_;
      sincosf(acc[i][1], &sv, &cv); c0.y = cv * SCALE_; s0.y = sv * SCALE_;
      sincosf(acc[i][2], &sv, &cv); c0.z = cv * SCALE_; s0.z = sv * SCALE_;
      sincosf(acc[i][3], &sv, &cv); c0.w = cv * SCALE_; s0.w = sv * SCALE_;
      sincosf(acc[i][4], &sv, &cv); c1.x = cv * SCALE_; s1.x = sv * SCALE_;
      sincosf(acc[i][5], &sv, &cv); c1.y = cv * SCALE_; s1.y = sv * SCALE_;
      sincosf(acc[i][6], &sv, &cv); c1.z = cv * SCALE_; s1.z = sv * SCALE_;
      sincosf(acc[i][7], &sv, &cv); c1.w = cv * SCALE_; s1.w = sv * SCALE_;
      long base = ((long)(b * H_ + h) * L_ + l) * M2_;
      ushort4 hv; float4 r4;
      split4(c0, &hv, &r4);
      *(ushort4*)&ph[base + 4 * tx] = hv;
      *(ushort4*)&pl[base + 4 * tx] = (ushort4){f2bf(r4.x), f2bf(r4.y), f2bf(r4.z), f2bf(r4.w)};
      split4(c1, &hv, &r4);
      *(ushort4*)&ph[base + 64 + 4 * tx] = hv;
      *(ushort4*)&pl[base + 64 + 4 * tx] = (ushort4){f2bf(r4.x), f2bf(r4.y), f2bf(r4.z), f2bf(r4.w)};
      split4(s0, &hv, &r4);
      *(ushort4*)&ph[base + 128 + 4 * tx] = hv;
      *(ushort4*)&pl[base + 128 + 4 * tx] = (ushort4){f2bf(r4.x), f2bf(r4.y), f2bf(r4.z), f2bf(r4.w)};
      split4(s1, &hv, &r4);
      *(ushort4*)&ph[base + 192 + 4 * tx] = hv;
      *(ushort4*)&pl[base + 192 + 4 * tx] = (ushort4){f2bf(r4.x), f2bf(r4.y), f2bf(r4.z), f2bf(r4.w)};
    }
  } else {
    // ---------- Wo -> bf16 ----------
    const int id2 = bx - (64 + 2048);
    int idx = id2 * 512 + tid;
    for (int i = idx; i < 262144; i += 65536) {
      float4 f = ((const float4*)Wo)[i];
      ushort4 hv = {f2bf(f.x), f2bf(f.y), f2bf(f.z), f2bf(f.w)};
      ((ushort4*)wo_hi)[i] = hv;
    }
  }
}

// ---------------- blocked triangular solves (dense L/invD in G) -------------
__global__ __launch_bounds__(256) void tri_solve_kernel(
    const float* __restrict__ Gw, const float* __restrict__ T,
    u16* __restrict__ wth, u16* __restrict__ wtl)
{
  __shared__ float Y[256 * 17];
  __shared__ float tmp[16 * 17];
  const int bh = blockIdx.y;
  const int d0 = blockIdx.x * 16;
  const int tid = threadIdx.x;
  const int i = tid >> 4, d = tid & 15;
  const float* Gb = Gw + (long)bh * 65536;
  const float* Tb = T + (long)bh * 16384;

  for (int r = i; r < 256; r += 16) Y[r * 17 + d] = Tb[r * 64 + d0 + d];
  __syncthreads();

  for (int J = 0; J < 16; ++J) {
    float acc = Y[(J * 16 + i) * 17 + d];
    for (int c = 0; c < J; ++c) {
      const float* Lblk = &Gb[(long)(16 * J + i) * 256 + 16 * c];
#pragma unroll
      for (int k = 0; k < 16; k += 4) {
        float4 l4 = *(const float4*)&Lblk[k];
        acc = fmaf(-l4.x, Y[(c * 16 + k + 0) * 17 + d], acc);
        acc = fmaf(-l4.y, Y[(c * 16 + k + 1) * 17 + d], acc);
        acc = fmaf(-l4.z, Y[(c * 16 + k + 2) * 17 + d], acc);
        acc = fmaf(-l4.w, Y[(c * 16 + k + 3) * 17 + d], acc);
      }
    }
    tmp[i * 17 + d] = acc;
    __syncthreads();
    const float* invD = &Gb[(long)(16 * J + i) * 256 + 16 * J];
    float y = 0.f;
#pragma unroll
    for (int k = 0; k < 16; ++k) y = fmaf(invD[k], tmp[k * 17 + d], y);
    Y[(J * 16 + i) * 17 + d] = y;
    __syncthreads();
  }

  for (int J = 15; J >= 0; --J) {
    float acc = Y[(J * 16 + i) * 17 + d];
    for (int I = J + 1; I < 16; ++I) {
#pragma unroll
      for (int k = 0; k < 16; ++k)
        acc = fmaf(-Gb[(long)(16 * I + k) * 256 + 16 * J + i], Y[(I * 16 + k) * 17 + d], acc);
    }
    tmp[i * 17 + d] = acc;
    __syncthreads();
    float w = 0.f;
#pragma unroll
    for (int k = 0; k < 16; ++k)
      w = fmaf(Gb[(long)(16 * J + k) * 256 + 16 * J + i], tmp[k * 17 + d], w);
    Y[(J * 16 + i) * 17 + d] = w;
    __syncthreads();
  }

  for (int f = tid; f < 16 * 256; f += 256) {
    int dc = f >> 8, m = f & 255;
    float val = Y[m * 17 + dc];
    u16 h = f2bf(val);
    long o = (long)bh * 16384 + (long)(d0 + dc) * 256 + m;
    wth[o] = h;
    wtl[o] = f2bf(val - bf2f(h));
  }
}

__global__ void ws_too_small_kernel(float* out) { out[0] = 12345.0f; }

extern "C" void kernel_launch(void* const* d_in, const int* in_sizes, int n_in,
                              void* d_out, int out_size, void* d_ws, size_t ws_size,
                              hipStream_t stream) {
  const float* x    = (const float*)d_in[0];
  const float* mask = (const float*)d_in[2];
  const float* Wq   = (const float*)d_in[3];
  const float* Wk   = (const float*)d_in[4];
  const float* Wv   = (const float*)d_in[5];
  const float* Wo   = (const float*)d_in[6];
  const float* bo   = (const float*)d_in[7];
  const float* rffW = (const float*)d_in[8];
  const float* rffb = (const float*)d_in[9];
  float* out = (float*)d_out;
  float* ws  = (float*)d_ws;

  const size_t needed = 58720256UL * 4UL;  // 234.9 MB
  if (ws_size < needed) {
    ws_too_small_kernel<<<1, 1, 0, stream>>>(out);
    return;
  }
  // region A [0, 8.4M): q fp32 -> oh bf16 after rff(q)
  float* q = ws;
  u16* oh_bf = (u16*)ws;
  // region B [8.4M, 16.7M): k fp32 -> T(1M)+G(4.2M) after reduce; G becomes L in-place
  float* kbuf = ws + 8388608;
  float* T    = ws + 8388608;
  float* G    = ws + 9437184;
  // region big [16.7M, 50.3M):
  u16* big16 = (u16*)(ws + 16777216);
  u16* x_hi = big16;
  u16* x_lo = big16 + 8388608;
  u16* w_hi = big16 + 16777216;
  u16* w_lo = big16 + 19922944;
  u16* pk_hi = big16;                      // [0, 20971520) u16
  u16* pk_lo = big16 + 20971520;           // [20971520, 41943040) u16
  float* Gp = ws + 37748736;               // 2 x 4194304 floats
  float* Tp = ws + 46137344;               // 2 x 1048576 floats
  u16* phiq_hi = big16;                    // after reduce, whole big region
  u16* phiq_lo = big16 + 33554432;
  // region D [50.3M, 58.7M): v fp32 -> wt/wo bf16
  float* v = ws + 50331648;
  u16* wt_hi = (u16*)(ws + 50331648);
  u16* wt_lo = wt_hi + 1048576;
  u16* wo_hi = wt_hi + 2097152;

  hipFuncSetAttribute((const void*)chol_rffq_wo_kernel,
                      hipFuncAttributeMaxDynamicSharedMemorySize, 51712);

  dim3 blk(256);

  // 1: convert x and W to bf16 hi/lo
  cvt_split_kernel<<<8192, blk, 0, stream>>>(x, x_hi, x_lo, 2097152);
  cvt_split_kernel<<<1024, blk, 0, stream>>>(Wq, w_hi,           w_lo,           262144);
  cvt_split_kernel<<<1024, blk, 0, stream>>>(Wk, w_hi + 1048576, w_lo + 1048576, 262144);
  cvt_split_kernel<<<1024, blk, 0, stream>>>(Wv, w_hi + 2097152, w_lo + 2097152, 262144);

  // 2: QKV — qk 3-pass (uniform) + v hi-only
  mfma_qk3<<<dim3(16, 64), blk, 0, stream>>>(x_hi, x_lo, w_hi, w_lo, q, kbuf);
  mfma_nt<<<dim3(8, 64), blk, 0, stream>>>(x_hi, w_hi + 2097152, v,
                                           1024, 1024, 1024, 1024, nullptr, nullptr);

  // 3: two bh-halves: rff(k)->pkT, vT->pkT, [G|T] MFMA (K-split x2 partials)
  for (int half = 0; half < 2; ++half) {
    int b0 = half * 2, bh0 = half * 32;
    rff_k_t<<<dim3(32, 16, 2), blk, 0, stream>>>(kbuf, mask, rffW, rffb, pk_hi, pk_lo, b0);
    vt_kernel<<<dim3(16, 32), blk, 0, stream>>>(v, mask, pk_hi, pk_lo, b0);
    mfma_gt<<<dim3(5, 4, 32), blk, 0, stream>>>(pk_hi, pk_lo, Gp, Tp, bh0);
  }

  // 4: reduce partials -> final G, T
  reduce_gt_kernel<<<5120, blk, 0, stream>>>(Gp, G, Tp, T);

  // 5: fused out-of-core chol (in-place on G) + rff(q)->phiq + Wo cvt
  chol_rffq_wo_kernel<<<dim3(64 + 2048 + 128), dim3(512), 51712, stream>>>(
      G, q, rffW, rffb, phiq_hi, phiq_lo, Wo, wo_hi);

  // 6: tri solves (dense L/invD from G) -> wt bf16 hi/lo
  tri_solve_kernel<<<dim3(4, 64), dim3(256), 0, stream>>>(G, T, wt_hi, wt_lo);

  // 7: out-heads MFMA (bf16 output)
  mfma_out_k<<<dim3(16, 64), blk, 0, stream>>>(phiq_hi, phiq_lo, wt_hi, wt_lo, oh_bf);

  // 8: Wo projection (bf16 MFMA) with bias+mask epilogue
  mfma_nt<<<dim3(8, 64), blk, 0, stream>>>(oh_bf, wo_hi, out, 1024, 1024, 1024, 1024, bo, mask);
}